// Round 1
// baseline (4506.008 us; speedup 1.0000x reference)
//
#include <hip/hip_runtime.h>

#define N_NODES 200000
#define N_EDGES 1250000
#define N_RELS 8

constexpr int TILE = 64;
constexpr int NTILES_E = (N_EDGES + TILE - 1) / TILE + N_RELS;  // 19540
constexpr int EP = NTILES_E * TILE;                              // 1250560

// ---------------- setup kernels ----------------

__global__ void k_zero(int* __restrict__ p, int n) {
  int i = blockIdx.x * 256 + threadIdx.x;
  if (i < n) p[i] = 0;
}

__global__ void k_count(const int* __restrict__ ei, const int* __restrict__ et,
                        int* __restrict__ cnt, int* __restrict__ hist) {
  __shared__ int bins[N_RELS];
  if (threadIdx.x < N_RELS) bins[threadIdx.x] = 0;
  __syncthreads();
  int e = blockIdx.x * 256 + threadIdx.x;
  if (e < N_EDGES) {
    int dst = ei[N_EDGES + e];
    int r = et[e];
    atomicAdd(&cnt[dst * N_RELS + r], 1);
    atomicAdd(&bins[r], 1);
  }
  __syncthreads();
  if (threadIdx.x < N_RELS) atomicAdd(&hist[threadIdx.x], bins[threadIdx.x]);
}

__global__ void k_offsets(const int* __restrict__ hist, int* __restrict__ off,
                          int* __restrict__ cursor, int* __restrict__ es,
                          int* __restrict__ ed) {
  __shared__ int soff[N_RELS + 1];
  if (threadIdx.x == 0) {
    int o = 0;
    soff[0] = 0;
    for (int r = 0; r < N_RELS; ++r) {
      o += ((hist[r] + TILE - 1) / TILE) * TILE;
      soff[r + 1] = o;
    }
    for (int r = 0; r <= N_RELS; ++r) off[r] = soff[r];
  }
  __syncthreads();
  if (threadIdx.x < N_RELS) cursor[threadIdx.x] = soff[threadIdx.x];
  int r = threadIdx.x >> 3, j = threadIdx.x & 7;
  int s = soff[r] + hist[r];
  int e2 = soff[r + 1];
  for (int i = s + j; i < e2; i += 8) { es[i] = 0; ed[i] = -1; }
}

__global__ void k_scatter(const int* __restrict__ ei, const int* __restrict__ et,
                          int* __restrict__ cursor, int* __restrict__ es,
                          int* __restrict__ ed) {
  __shared__ int bins[N_RELS];
  __shared__ int base[N_RELS];
  if (threadIdx.x < N_RELS) bins[threadIdx.x] = 0;
  __syncthreads();
  int e = blockIdx.x * 256 + threadIdx.x;
  int r = -1, rank = 0, src = 0, dst = 0;
  if (e < N_EDGES) {
    src = ei[e];
    dst = ei[N_EDGES + e];
    r = et[e];
    rank = atomicAdd(&bins[r], 1);
  }
  __syncthreads();
  if (threadIdx.x < N_RELS && bins[threadIdx.x] > 0)
    base[threadIdx.x] = atomicAdd(&cursor[threadIdx.x], bins[threadIdx.x]);
  __syncthreads();
  if (r >= 0) {
    int p = base[r] + rank;
    es[p] = src;
    ed[p] = dst;
  }
}

// ---------------- GEMM kernels ----------------
// thread layout: 256 threads; lane l: cg=l&15, rg=l>>4; wave w=t>>6
// thread computes 4 rows (R0..R0+3) x NC cols (C0..C0+NC-1)

template <int NC, bool RELU>
__global__ __launch_bounds__(256) void k_edge(
    const float* __restrict__ X, const float* __restrict__ W,
    const int* __restrict__ cnt, const int* __restrict__ es,
    const int* __restrict__ ed, const int* __restrict__ off,
    float* __restrict__ out) {
  constexpr int HO = NC * 16;
  __shared__ __align__(16) float Ws[64 * HO];
  __shared__ __align__(16) float XsT[64][TILE + 4];
  int tile = blockIdx.x * TILE;
  if (tile >= off[N_RELS]) return;
  int r = 0;
#pragma unroll
  for (int i = 1; i < N_RELS; ++i) r += (tile >= off[i]) ? 1 : 0;

  // stage W[r] into LDS
  const float4* Wr = reinterpret_cast<const float4*>(W + (size_t)r * 64 * HO);
  float4* Wd = reinterpret_cast<float4*>(Ws);
#pragma unroll
  for (int idx = threadIdx.x; idx < 64 * HO / 4; idx += 256) Wd[idx] = Wr[idx];

  // stage X rows (scaled by 1/cnt) transposed into LDS
  int t = threadIdx.x;
  int row = t >> 2, part = t & 3;
  int s = es[tile + row];
  int d = ed[tile + row];
  float alpha = 0.0f;
  if (d >= 0) {
    int c = cnt[d * N_RELS + r];
    alpha = 1.0f / (float)(c < 1 ? 1 : c);
  }
  const float4* xr = reinterpret_cast<const float4*>(X + (size_t)s * 64 + part * 16);
#pragma unroll
  for (int j4 = 0; j4 < 4; ++j4) {
    float4 v = xr[j4];
    if (RELU) {
      v.x = fmaxf(v.x, 0.f); v.y = fmaxf(v.y, 0.f);
      v.z = fmaxf(v.z, 0.f); v.w = fmaxf(v.w, 0.f);
    }
    int k0 = part * 16 + j4 * 4;
    XsT[k0 + 0][row] = v.x * alpha;
    XsT[k0 + 1][row] = v.y * alpha;
    XsT[k0 + 2][row] = v.z * alpha;
    XsT[k0 + 3][row] = v.w * alpha;
  }
  __syncthreads();

  int l = t & 63, w = t >> 6;
  int cg = l & 15, rg = l >> 4;
  int C0 = cg * NC;
  int R0 = w * 16 + rg * 4;
  float acc[4][NC];
#pragma unroll
  for (int i = 0; i < 4; ++i)
#pragma unroll
    for (int j = 0; j < NC; ++j) acc[i][j] = 0.f;

#pragma unroll
  for (int k = 0; k < 64; ++k) {
    float4 a = *reinterpret_cast<const float4*>(&XsT[k][R0]);
    float av[4] = {a.x, a.y, a.z, a.w};
    float b[NC];
    if constexpr (NC == 4) {
      float4 bv = *reinterpret_cast<const float4*>(&Ws[k * HO + C0]);
      b[0] = bv.x; b[1] = bv.y; b[2] = bv.z; b[3] = bv.w;
    } else {
      float2 bv = *reinterpret_cast<const float2*>(&Ws[k * HO + C0]);
      b[0] = bv.x; b[1] = bv.y;
    }
#pragma unroll
    for (int i = 0; i < 4; ++i)
#pragma unroll
      for (int j = 0; j < NC; ++j) acc[i][j] = fmaf(av[i], b[j], acc[i][j]);
  }

#pragma unroll
  for (int i = 0; i < 4; ++i) {
    int dd = ed[tile + R0 + i];
    if (dd < 0) continue;
    float* o = out + (size_t)dd * HO + C0;
#pragma unroll
    for (int j = 0; j < NC; ++j) atomicAdd(o + j, acc[i][j]);
  }
}

template <int NC, bool RELU>
__global__ __launch_bounds__(256) void k_dense(
    const float* __restrict__ X, const float* __restrict__ Wg,
    const float* __restrict__ bias, float* __restrict__ out) {
  constexpr int HO = NC * 16;
  __shared__ __align__(16) float Ws[64 * HO];
  __shared__ __align__(16) float XsT[64][TILE + 4];
  int tile = blockIdx.x * TILE;

  const float4* Wr = reinterpret_cast<const float4*>(Wg);
  float4* Wd = reinterpret_cast<float4*>(Ws);
#pragma unroll
  for (int idx = threadIdx.x; idx < 64 * HO / 4; idx += 256) Wd[idx] = Wr[idx];

  int t = threadIdx.x;
  int row = t >> 2, part = t & 3;
  const float4* xr =
      reinterpret_cast<const float4*>(X + (size_t)(tile + row) * 64 + part * 16);
#pragma unroll
  for (int j4 = 0; j4 < 4; ++j4) {
    float4 v = xr[j4];
    if (RELU) {
      v.x = fmaxf(v.x, 0.f); v.y = fmaxf(v.y, 0.f);
      v.z = fmaxf(v.z, 0.f); v.w = fmaxf(v.w, 0.f);
    }
    int k0 = part * 16 + j4 * 4;
    XsT[k0 + 0][row] = v.x;
    XsT[k0 + 1][row] = v.y;
    XsT[k0 + 2][row] = v.z;
    XsT[k0 + 3][row] = v.w;
  }
  __syncthreads();

  int l = t & 63, w = t >> 6;
  int cg = l & 15, rg = l >> 4;
  int C0 = cg * NC;
  int R0 = w * 16 + rg * 4;
  float acc[4][NC];
#pragma unroll
  for (int i = 0; i < 4; ++i)
#pragma unroll
    for (int j = 0; j < NC; ++j) acc[i][j] = 0.f;

#pragma unroll
  for (int k = 0; k < 64; ++k) {
    float4 a = *reinterpret_cast<const float4*>(&XsT[k][R0]);
    float av[4] = {a.x, a.y, a.z, a.w};
    float b[NC];
    if constexpr (NC == 4) {
      float4 bv = *reinterpret_cast<const float4*>(&Ws[k * HO + C0]);
      b[0] = bv.x; b[1] = bv.y; b[2] = bv.z; b[3] = bv.w;
    } else {
      float2 bv = *reinterpret_cast<const float2*>(&Ws[k * HO + C0]);
      b[0] = bv.x; b[1] = bv.y;
    }
#pragma unroll
    for (int i = 0; i < 4; ++i)
#pragma unroll
      for (int j = 0; j < NC; ++j) acc[i][j] = fmaf(av[i], b[j], acc[i][j]);
  }

#pragma unroll
  for (int i = 0; i < 4; ++i) {
    float* o = out + (size_t)(tile + R0 + i) * HO + C0;
#pragma unroll
    for (int j = 0; j < NC; ++j) o[j] = acc[i][j] + bias[C0 + j];
  }
}

// ---------------- launch ----------------

extern "C" void kernel_launch(void* const* d_in, const int* in_sizes, int n_in,
                              void* d_out, int out_size, void* d_ws, size_t ws_size,
                              hipStream_t stream) {
  const float* x = (const float*)d_in[0];
  const int* ei = (const int*)d_in[1];
  const int* et = (const int*)d_in[2];
  const float* w1 = (const float*)d_in[3];
  const float* r1 = (const float*)d_in[4];
  const float* b1 = (const float*)d_in[5];
  const float* w2 = (const float*)d_in[6];
  const float* r2 = (const float*)d_in[7];
  const float* b2 = (const float*)d_in[8];
  float* out = (float*)d_out;

  // workspace carve (all offsets keep 16B alignment)
  char* p = (char*)d_ws;
  int* cnt = (int*)p;              p += (size_t)N_NODES * N_RELS * 4;  // 6.4 MB
  int* hist = (int*)p;             // 8 ints
  int* cursor = hist + 16;         // 8 ints
  int* off = hist + 32;            // 9 ints
  p += 256;
  int* es = (int*)p;               p += (size_t)EP * 4;
  int* ed = (int*)p;               p += (size_t)EP * 4;
  float* agg1 = (float*)p;         // [N,64] = 51.2 MB

  int nz = N_NODES * N_RELS + 64;  // cnt + hist/cursor/off region
  k_zero<<<(nz + 255) / 256, 256, 0, stream>>>(cnt, nz);
  k_count<<<(N_EDGES + 255) / 256, 256, 0, stream>>>(ei, et, cnt, hist);
  k_offsets<<<1, 64, 0, stream>>>(hist, off, cursor, es, ed);
  k_scatter<<<(N_EDGES + 255) / 256, 256, 0, stream>>>(ei, et, cursor, es, ed);

  // layer 1: agg1 = x@root1 + bias1, then += per-edge messages
  k_dense<4, false><<<N_NODES / TILE, 256, 0, stream>>>(x, r1, b1, agg1);
  k_edge<4, false><<<NTILES_E, 256, 0, stream>>>(x, w1, cnt, es, ed, off, agg1);

  // layer 2 (relu applied on load of agg1 by both consumers)
  k_dense<2, true><<<N_NODES / TILE, 256, 0, stream>>>(agg1, r2, b2, out);
  k_edge<2, true><<<NTILES_E, 256, 0, stream>>>(agg1, w2, cnt, es, ed, off, out);
}

// Round 2
// 1793.977 us; speedup vs baseline: 2.5117x; 2.5117x over previous
//
#include <hip/hip_runtime.h>

#define N_NODES 200000
#define N_EDGES 1250000
#define N_RELS 8
#define NBUCK 3125   // N_NODES / 64

// ---------------- setup kernels ----------------

__global__ void k_zero(int* __restrict__ p, int n) {
  int i = blockIdx.x * 256 + threadIdx.x;
  if (i < n) p[i] = 0;
}

// per-(dst,rel) counts + per-bucket (dst>>6) histogram
__global__ void k_count(const int* __restrict__ ei, const int* __restrict__ et,
                        int* __restrict__ cnt, int* __restrict__ hist) {
  int e = blockIdx.x * 256 + threadIdx.x;
  if (e < N_EDGES) {
    int dst = ei[N_EDGES + e];
    int r = et[e];
    atomicAdd(&cnt[dst * N_RELS + r], 1);
    atomicAdd(&hist[dst >> 6], 1);
  }
}

// exclusive scan over 3125 bucket counts -> boff[0..3125], cursor = boff
__global__ __launch_bounds__(1024) void k_scan(const int* __restrict__ hist,
                                               int* __restrict__ boff,
                                               int* __restrict__ cursor) {
  __shared__ int s[1024];
  int t = threadIdx.x;
  int base = t * 4;
  int v[4];
  int sum = 0;
#pragma unroll
  for (int j = 0; j < 4; ++j) {
    v[j] = (base + j < NBUCK) ? hist[base + j] : 0;
    sum += v[j];
  }
  s[t] = sum;
  __syncthreads();
  for (int off = 1; off < 1024; off <<= 1) {
    int a = (t >= off) ? s[t - off] : 0;
    __syncthreads();
    s[t] += a;
    __syncthreads();
  }
  int run = (t > 0) ? s[t - 1] : 0;
#pragma unroll
  for (int j = 0; j < 4; ++j) {
    int i = base + j;
    if (i < NBUCK) { boff[i] = run; cursor[i] = run; }
    else if (i == NBUCK) boff[i] = run;
    run += v[j];
  }
}

// bucket edges by dst>>6; payload: src and (dstLocal<<3)|rel
__global__ void k_scatter(const int* __restrict__ ei, const int* __restrict__ et,
                          int* __restrict__ cursor, int* __restrict__ es2,
                          int* __restrict__ emeta) {
  int e = blockIdx.x * 256 + threadIdx.x;
  if (e < N_EDGES) {
    int src = ei[e];
    int dst = ei[N_EDGES + e];
    int r = et[e];
    int pos = atomicAdd(&cursor[dst >> 6], 1);
    es2[pos] = src;
    emeta[pos] = ((dst & 63) << 3) | r;
  }
}

// ---------------- fused aggregate + transform ----------------
// Block owns 64 dst nodes. Phase 1: aggregate alpha*x[src] into LDS A[64][512]
// (k = rel*64 + feature), XOR-swizzled 16B blocks to avoid bank conflicts.
// Phase 2: out[64][NCOL] = A @ Wstk[512][NCOL] + x_dst @ Root[64][NCOL] + bias,
// split-K across G groups, 8x4 register tiles, B staged in LDS chunks.

__device__ __forceinline__ int aword(int m, int lane) {
  int d = m >> 3;
  int kb = (m & 7) * 16 + (lane >> 2);
  return d * 512 + (((kb ^ (d >> 3)) << 2) | (lane & 3));
}

template <int NCOL, bool RELU>
__global__ __launch_bounds__(256) void k_rgcn(
    const float* __restrict__ X, const float* __restrict__ Wstk,
    const float* __restrict__ Root, const float* __restrict__ Bias,
    const int* __restrict__ cnt, const int* __restrict__ boff,
    const int* __restrict__ es2, const int* __restrict__ emeta,
    float* __restrict__ Out) {
  constexpr int G = (NCOL == 64) ? 2 : 4;   // split-K groups
  constexpr int GT = 256 / G;               // threads per group
  constexpr int CGS = NCOL / 4;             // col-groups
  constexpr int KG = 512 / G;               // rel-K per group
  constexpr int NCH = KG / 32;              // 32-k chunks per group
  constexpr int KR = 64 / G;                // root-K per group
  constexpr int NF4 = 32 * NCOL / 4;        // float4s per B chunk per group

  __shared__ float agg[64 * 512];           // 128 KB
  __shared__ float Bb[4096];                // 16 KB (G chunk buffers)
  __shared__ float inv_lds[512];            // 2 KB

  int t = threadIdx.x;
  int b = blockIdx.x;
  int d0 = b * 64;

  // zero agg
  float4* agg4 = (float4*)agg;
#pragma unroll
  for (int q = 0; q < 32; ++q) agg4[t + q * 256] = make_float4(0.f, 0.f, 0.f, 0.f);
  // 1/count table for the 64 dsts x 8 rels
  {
    int i0 = t * 2;
    int c0 = cnt[d0 * 8 + i0];
    int c1 = cnt[d0 * 8 + i0 + 1];
    inv_lds[i0] = 1.0f / (float)(c0 < 1 ? 1 : c0);
    inv_lds[i0 + 1] = 1.0f / (float)(c1 < 1 ? 1 : c1);
  }
  __syncthreads();

  // ---- phase 1: aggregation into LDS ----
  int start = boff[b], end = boff[b + 1];
  int lane = t & 63, w = t >> 6;
  for (int eb = start + w * 64; eb < end; eb += 256) {
    int nv = end - eb; if (nv > 64) nv = 64;
    int vs = 0, vm = 0;
    if (lane < nv) { vs = es2[eb + lane]; vm = emeta[eb + lane]; }
    int j = 0;
    for (; j + 4 <= nv; j += 4) {
      int s0 = __shfl(vs, j + 0), m0 = __shfl(vm, j + 0);
      int s1 = __shfl(vs, j + 1), m1 = __shfl(vm, j + 1);
      int s2 = __shfl(vs, j + 2), m2 = __shfl(vm, j + 2);
      int s3 = __shfl(vs, j + 3), m3 = __shfl(vm, j + 3);
      float x0 = X[(size_t)s0 * 64 + lane];
      float x1 = X[(size_t)s1 * 64 + lane];
      float x2 = X[(size_t)s2 * 64 + lane];
      float x3 = X[(size_t)s3 * 64 + lane];
      if (RELU) {
        x0 = fmaxf(x0, 0.f); x1 = fmaxf(x1, 0.f);
        x2 = fmaxf(x2, 0.f); x3 = fmaxf(x3, 0.f);
      }
      atomicAdd(&agg[aword(m0, lane)], x0 * inv_lds[m0]);
      atomicAdd(&agg[aword(m1, lane)], x1 * inv_lds[m1]);
      atomicAdd(&agg[aword(m2, lane)], x2 * inv_lds[m2]);
      atomicAdd(&agg[aword(m3, lane)], x3 * inv_lds[m3]);
    }
    for (; j < nv; ++j) {
      int s0 = __shfl(vs, j), m0 = __shfl(vm, j);
      float x0 = X[(size_t)s0 * 64 + lane];
      if (RELU) x0 = fmaxf(x0, 0.f);
      atomicAdd(&agg[aword(m0, lane)], x0 * inv_lds[m0]);
    }
  }
  __syncthreads();

  // ---- phase 2: GEMM ----
  int g = t / GT, tl = t % GT;
  int rg = tl / CGS, cg = tl % CGS;
  int R0 = rg * 8, C0 = cg * 4;
  float acc[8][4];
#pragma unroll
  for (int i = 0; i < 8; ++i)
#pragma unroll
    for (int j = 0; j < 4; ++j) acc[i][j] = 0.f;

  const float4* W4 = (const float4*)Wstk;
  const float4* R4 = (const float4*)Root;
  float4* Bb4 = (float4*)Bb;

  // rel-K chunks (A from LDS)
  for (int ch = 0; ch < NCH; ++ch) {
    int kbase = g * KG + ch * 32;
    __syncthreads();
#pragma unroll
    for (int q = 0; q < NF4 / GT; ++q)
      Bb4[g * NF4 + tl + q * GT] = W4[(kbase * NCOL) / 4 + tl + q * GT];
    __syncthreads();
    int kb0 = kbase >> 2;
#pragma unroll
    for (int k4 = 0; k4 < 8; ++k4) {
      float4 bq[4];
#pragma unroll
      for (int lo = 0; lo < 4; ++lo)
        bq[lo] = *(const float4*)&Bb[(g * 32 + k4 * 4 + lo) * NCOL + C0];
      const float* br = (const float*)bq;
      int kb = kb0 + k4;
#pragma unroll
      for (int i = 0; i < 8; ++i) {
        int d = R0 + i;
        float4 Av = *(const float4*)&agg[d * 512 + ((kb ^ rg) << 2)];
        float a4[4] = {Av.x, Av.y, Av.z, Av.w};
#pragma unroll
        for (int kk = 0; kk < 4; ++kk)
#pragma unroll
          for (int j = 0; j < 4; ++j)
            acc[i][j] = fmaf(a4[kk], br[kk * 4 + j], acc[i][j]);
      }
    }
  }

  // root-K chunk (A from global = X rows of this block's dsts)
  {
    int krb = g * KR;
    constexpr int NF4R = KR * NCOL / 4;
    __syncthreads();
#pragma unroll
    for (int q = 0; q < NF4R / GT; ++q)
      Bb4[g * NF4 + tl + q * GT] = R4[(krb * NCOL) / 4 + tl + q * GT];
    __syncthreads();
#pragma unroll
    for (int k4 = 0; k4 < KR / 4; ++k4) {
      float4 bq[4];
#pragma unroll
      for (int lo = 0; lo < 4; ++lo)
        bq[lo] = *(const float4*)&Bb[(g * 32 + k4 * 4 + lo) * NCOL + C0];
      const float* br = (const float*)bq;
#pragma unroll
      for (int i = 0; i < 8; ++i) {
        float4 Av = *(const float4*)(X + (size_t)(d0 + R0 + i) * 64 + krb + k4 * 4);
        if (RELU) {
          Av.x = fmaxf(Av.x, 0.f); Av.y = fmaxf(Av.y, 0.f);
          Av.z = fmaxf(Av.z, 0.f); Av.w = fmaxf(Av.w, 0.f);
        }
        float a4[4] = {Av.x, Av.y, Av.z, Av.w};
#pragma unroll
        for (int kk = 0; kk < 4; ++kk)
#pragma unroll
          for (int j = 0; j < 4; ++j)
            acc[i][j] = fmaf(a4[kk], br[kk * 4 + j], acc[i][j]);
      }
    }
  }

  // ---- reduce split-K partials via LDS (reuse agg) and store ----
  __syncthreads();
  float* red = agg;
#pragma unroll
  for (int i = 0; i < 8; ++i) {
    float4 v = make_float4(acc[i][0], acc[i][1], acc[i][2], acc[i][3]);
    *(float4*)&red[g * (64 * NCOL) + (R0 + i) * NCOL + C0] = v;
  }
  __syncthreads();
  constexpr int PER = 64 * NCOL / 256;
  int e0 = t * PER;
#pragma unroll
  for (int jj = 0; jj < PER; jj += 4) {
    int idx = e0 + jj;
    float4 s = *(const float4*)&red[idx];
#pragma unroll
    for (int g2 = 1; g2 < G; ++g2) {
      float4 u = *(const float4*)&red[g2 * (64 * NCOL) + idx];
      s.x += u.x; s.y += u.y; s.z += u.z; s.w += u.w;
    }
    int c = idx % NCOL;
    float4 bv = *(const float4*)&Bias[c];
    s.x += bv.x; s.y += bv.y; s.z += bv.z; s.w += bv.w;
    int d = idx / NCOL;
    *(float4*)&Out[(size_t)(d0 + d) * NCOL + c] = s;
  }
}

// ---------------- launch ----------------

extern "C" void kernel_launch(void* const* d_in, const int* in_sizes, int n_in,
                              void* d_out, int out_size, void* d_ws, size_t ws_size,
                              hipStream_t stream) {
  const float* x = (const float*)d_in[0];
  const int* ei = (const int*)d_in[1];
  const int* et = (const int*)d_in[2];
  const float* w1 = (const float*)d_in[3];
  const float* r1 = (const float*)d_in[4];
  const float* b1 = (const float*)d_in[5];
  const float* w2 = (const float*)d_in[6];
  const float* r2 = (const float*)d_in[7];
  const float* b2 = (const float*)d_in[8];
  float* out = (float*)d_out;

  int* cnt = (int*)d_ws;                 // 1,600,000 ints
  int* hist = cnt + 1600000;             // 3200
  int* cursor = hist + 3200;             // 3200
  int* boff = cursor + 3200;             // 3204 (3126 used)
  int* es2 = boff + 3204;                // 1,250,000
  int* emeta = es2 + N_EDGES;            // 1,250,000
  float* h = (float*)(emeta + N_EDGES);  // 12,800,000 floats (51.2 MB)

  int nz = 1600000 + 3200;  // cnt + hist
  k_zero<<<(nz + 255) / 256, 256, 0, stream>>>(cnt, nz);
  k_count<<<(N_EDGES + 255) / 256, 256, 0, stream>>>(ei, et, cnt, hist);
  k_scan<<<1, 1024, 0, stream>>>(hist, boff, cursor);
  k_scatter<<<(N_EDGES + 255) / 256, 256, 0, stream>>>(ei, et, cursor, es2, emeta);

  k_rgcn<64, false><<<NBUCK, 256, 0, stream>>>(x, w1, r1, b1, cnt, boff, es2, emeta, h);
  k_rgcn<32, true><<<NBUCK, 256, 0, stream>>>(h, w2, r2, b2, cnt, boff, es2, emeta, out);
}

// Round 3
// 1358.179 us; speedup vs baseline: 3.3177x; 1.3209x over previous
//
#include <hip/hip_runtime.h>

#define N_NODES 200000
#define N_EDGES 1250000
#define N_RELS 8
#define NBUCK 6250   // N_NODES / 32

// ---------------- setup kernels ----------------

__global__ void k_zero(int* __restrict__ p, int n) {
  int i = blockIdx.x * 256 + threadIdx.x;
  if (i < n) p[i] = 0;
}

// per-(dst,rel) counts + per-bucket (dst>>5) histogram
__global__ void k_count(const int* __restrict__ ei, const int* __restrict__ et,
                        int* __restrict__ cnt, int* __restrict__ hist) {
  int e = blockIdx.x * 256 + threadIdx.x;
  if (e < N_EDGES) {
    int dst = ei[N_EDGES + e];
    int r = et[e];
    atomicAdd(&cnt[dst * N_RELS + r], 1);
    atomicAdd(&hist[dst >> 5], 1);
  }
}

// exclusive scan over 6250 bucket counts -> boff[0..6250], cursor = boff
__global__ __launch_bounds__(1024) void k_scan(const int* __restrict__ hist,
                                               int* __restrict__ boff,
                                               int* __restrict__ cursor) {
  __shared__ int s[1024];
  int t = threadIdx.x;
  int base = t * 8;
  int v[8];
  int sum = 0;
#pragma unroll
  for (int j = 0; j < 8; ++j) {
    v[j] = (base + j < NBUCK) ? hist[base + j] : 0;
    sum += v[j];
  }
  s[t] = sum;
  __syncthreads();
  for (int off = 1; off < 1024; off <<= 1) {
    int a = (t >= off) ? s[t - off] : 0;
    __syncthreads();
    s[t] += a;
    __syncthreads();
  }
  int run = (t > 0) ? s[t - 1] : 0;
#pragma unroll
  for (int j = 0; j < 8; ++j) {
    int i = base + j;
    if (i < NBUCK) { boff[i] = run; cursor[i] = run; }
    else if (i == NBUCK) boff[i] = run;
    run += v[j];
  }
}

// bucket edges by dst>>5; payload: src and row = (dstLocal<<3)|rel
__global__ void k_scatter(const int* __restrict__ ei, const int* __restrict__ et,
                          int* __restrict__ cursor, int* __restrict__ es2,
                          int* __restrict__ emeta) {
  int e = blockIdx.x * 256 + threadIdx.x;
  if (e < N_EDGES) {
    int src = ei[e];
    int dst = ei[N_EDGES + e];
    int r = et[e];
    int pos = atomicAdd(&cursor[dst >> 5], 1);
    es2[pos] = src;
    emeta[pos] = ((dst & 31) << 3) | r;
  }
}

// ---------------- fused aggregate + transform ----------------
// Block owns 32 dst nodes, 512 threads (8 waves), ~77KB LDS -> 2 blocks/CU.
// agg[256 rows][64 feats], row = dlocal*8+rel, swizzled:
//   word(row,f) = row*64 + ((f + 4*(row>>3)) & 63)
// Phase 1: raw sums of x[src] rows (ds_atomic, conflict-free, 8-deep unroll).
// Scale:   agg row *= 1/cnt  (alpha folded out of the edge loop).
// Phase 2: split-K GEMM  out[32][NCOL] = agg@Wstk + X_dst@Root + bias.

template <int NCOL, bool RELU>
__global__ __launch_bounds__(512, 4) void k_rgcn(
    const float* __restrict__ X, const float* __restrict__ Wstk,
    const float* __restrict__ Root, const float* __restrict__ Bias,
    const int* __restrict__ cnt, const int* __restrict__ boff,
    const int* __restrict__ es2, const int* __restrict__ emeta,
    float* __restrict__ Out) {
  constexpr int G = (NCOL == 64) ? 4 : 8;   // split-K groups
  constexpr int GT = 512 / G;               // threads per group
  constexpr int KG = 512 / G;               // rel-K per group
  constexpr int CK = 8;                     // K-chunk staged in LDS
  constexpr int NCH = KG / CK;
  constexpr int KR = 64 / G;                // root-K per group
  constexpr int RCH = KR / CK;              // root chunks (>=1)
  constexpr int CGN = NCOL / 4;             // col-groups

  __shared__ float agg[32 * 512];           // 64 KB
  __shared__ float Bb[G * CK * NCOL];       // 8 KB
  __shared__ float inv_lds[256];            // 1 KB
  __shared__ int2 ebatch[8][64];            // 4 KB

  int t = threadIdx.x;
  int b = blockIdx.x;
  int d0 = b * 32;

  // zero agg + fill 1/cnt table
  float4* agg4 = (float4*)agg;
#pragma unroll
  for (int q = 0; q < 8; ++q) agg4[t + q * 512] = make_float4(0.f, 0.f, 0.f, 0.f);
  if (t < 256) {
    int c = cnt[d0 * 8 + t];
    inv_lds[t] = 1.0f / (float)(c < 1 ? 1 : c);
  }
  __syncthreads();

  // ---- phase 1: raw-sum aggregation into LDS ----
  int start = boff[b], end = boff[b + 1];
  int lane = t & 63, w = t >> 6;
  for (int eb = start + w * 64; eb < end; eb += 512) {
    int nv = end - eb; if (nv > 64) nv = 64;
    if (lane < nv) ebatch[w][lane] = make_int2(es2[eb + lane], emeta[eb + lane]);
    int j = 0;
    for (; j + 8 <= nv; j += 8) {
      float xv[8]; int rowv[8];
#pragma unroll
      for (int u = 0; u < 8; ++u) {
        int2 sm = ebatch[w][j + u];   // wave-broadcast LDS read
        rowv[u] = sm.y;
        float v = X[(size_t)sm.x * 64 + lane];
        if (RELU) v = fmaxf(v, 0.f);
        xv[u] = v;
      }
#pragma unroll
      for (int u = 0; u < 8; ++u) {
        int row = rowv[u];
        int word = (row << 6) + ((lane + ((row >> 3) << 2)) & 63);
        atomicAdd(&agg[word], xv[u]);
      }
    }
    for (; j < nv; ++j) {
      int2 sm = ebatch[w][j];
      float v = X[(size_t)sm.x * 64 + lane];
      if (RELU) v = fmaxf(v, 0.f);
      int row = sm.y;
      int word = (row << 6) + ((lane + ((row >> 3) << 2)) & 63);
      atomicAdd(&agg[word], v);
    }
  }
  __syncthreads();

  // ---- scale rows by 1/cnt (swizzle is intra-row, so row-uniform scale ok) ----
#pragma unroll
  for (int q = 0; q < 8; ++q) {
    int i4 = t + q * 512;
    float s = inv_lds[i4 >> 4];
    float4 v = agg4[i4];
    v.x *= s; v.y *= s; v.z *= s; v.w *= s;
    agg4[i4] = v;
  }
  __syncthreads();

  // ---- phase 2: split-K GEMM ----
  int g = t / GT, tl = t % GT;
  int rg = tl / CGN, cg = tl % CGN;
  int R0 = rg * 4, C0 = cg * 4;
  float acc[4][4];
#pragma unroll
  for (int i = 0; i < 4; ++i)
#pragma unroll
    for (int j = 0; j < 4; ++j) acc[i][j] = 0.f;

  const float4* W4 = (const float4*)Wstk;
  const float4* R4 = (const float4*)Root;
  float4* Bb4 = (float4*)Bb;

  // rel-K chunks (A from LDS)
  for (int ch = 0; ch < NCH; ++ch) {
    int kbase = g * KG + ch * CK;
    __syncthreads();
    Bb4[g * GT + tl] = W4[(kbase * NCOL) / 4 + tl];   // CK*NCOL/4 == GT
    __syncthreads();
#pragma unroll
    for (int k4 = 0; k4 < CK / 4; ++k4) {
      float4 bq[4];
#pragma unroll
      for (int lo = 0; lo < 4; ++lo)
        bq[lo] = *(const float4*)&Bb[(g * CK + k4 * 4 + lo) * NCOL + C0];
      const float* br = (const float*)bq;
      int kk = kbase + k4 * 4;
      int rr = kk >> 6, f0 = kk & 63;
#pragma unroll
      for (int i = 0; i < 4; ++i) {
        int d = R0 + i;
        int row = (d << 3) + rr;
        float4 Av = *(const float4*)&agg[(row << 6) + ((f0 + (d << 2)) & 63)];
        float a4[4] = {Av.x, Av.y, Av.z, Av.w};
#pragma unroll
        for (int kq = 0; kq < 4; ++kq)
#pragma unroll
          for (int j = 0; j < 4; ++j)
            acc[i][j] = fmaf(a4[kq], br[kq * 4 + j], acc[i][j]);
      }
    }
  }

  // root chunks (A = X rows of this block's dsts, from global)
  for (int rc = 0; rc < RCH; ++rc) {
    int krb = g * KR + rc * CK;
    __syncthreads();
    Bb4[g * GT + tl] = R4[(krb * NCOL) / 4 + tl];
    __syncthreads();
#pragma unroll
    for (int k4 = 0; k4 < CK / 4; ++k4) {
      float4 bq[4];
#pragma unroll
      for (int lo = 0; lo < 4; ++lo)
        bq[lo] = *(const float4*)&Bb[(g * CK + k4 * 4 + lo) * NCOL + C0];
      const float* br = (const float*)bq;
#pragma unroll
      for (int i = 0; i < 4; ++i) {
        float4 Av = *(const float4*)(X + (size_t)(d0 + R0 + i) * 64 + krb + k4 * 4);
        if (RELU) {
          Av.x = fmaxf(Av.x, 0.f); Av.y = fmaxf(Av.y, 0.f);
          Av.z = fmaxf(Av.z, 0.f); Av.w = fmaxf(Av.w, 0.f);
        }
        float a4[4] = {Av.x, Av.y, Av.z, Av.w};
#pragma unroll
        for (int kq = 0; kq < 4; ++kq)
#pragma unroll
          for (int j = 0; j < 4; ++j)
            acc[i][j] = fmaf(a4[kq], br[kq * 4 + j], acc[i][j]);
      }
    }
  }

  // ---- reduce split-K partials via LDS (reuse agg) and store ----
  constexpr int TW = 32 * NCOL;
  __syncthreads();
  float* red = agg;
#pragma unroll
  for (int i = 0; i < 4; ++i)
    *(float4*)&red[g * TW + (R0 + i) * NCOL + C0] =
        make_float4(acc[i][0], acc[i][1], acc[i][2], acc[i][3]);
  __syncthreads();
  if (NCOL == 64) {
    int idx = t * 4;
    float4 s = *(const float4*)&red[idx];
#pragma unroll
    for (int g2 = 1; g2 < G; ++g2) {
      float4 u = *(const float4*)&red[g2 * TW + idx];
      s.x += u.x; s.y += u.y; s.z += u.z; s.w += u.w;
    }
    int c = idx & (NCOL - 1);
    float4 bv = *(const float4*)&Bias[c];
    s.x += bv.x; s.y += bv.y; s.z += bv.z; s.w += bv.w;
    *(float4*)&Out[(size_t)(d0 + (idx / NCOL)) * NCOL + c] = s;
  } else {
    int idx = t * 2;
    float2 s = *(const float2*)&red[idx];
#pragma unroll
    for (int g2 = 1; g2 < G; ++g2) {
      float2 u = *(const float2*)&red[g2 * TW + idx];
      s.x += u.x; s.y += u.y;
    }
    int c = idx & (NCOL - 1);
    float2 bv = *(const float2*)&Bias[c];
    s.x += bv.x; s.y += bv.y;
    *(float2*)&Out[(size_t)(d0 + (idx / NCOL)) * NCOL + c] = s;
  }
}

// ---------------- launch ----------------

extern "C" void kernel_launch(void* const* d_in, const int* in_sizes, int n_in,
                              void* d_out, int out_size, void* d_ws, size_t ws_size,
                              hipStream_t stream) {
  const float* x = (const float*)d_in[0];
  const int* ei = (const int*)d_in[1];
  const int* et = (const int*)d_in[2];
  const float* w1 = (const float*)d_in[3];
  const float* r1 = (const float*)d_in[4];
  const float* b1 = (const float*)d_in[5];
  const float* w2 = (const float*)d_in[6];
  const float* r2 = (const float*)d_in[7];
  const float* b2 = (const float*)d_in[8];
  float* out = (float*)d_out;

  int* cnt = (int*)d_ws;                 // 1,600,000 ints
  int* hist = cnt + 1600000;             // 6400
  int* cursor = hist + 6400;             // 6400
  int* boff = cursor + 6400;             // 6400 (6251 used)
  int* es2 = boff + 6400;                // 1,250,000
  int* emeta = es2 + N_EDGES;            // 1,250,000
  float* h = (float*)(emeta + N_EDGES);  // 12,800,000 floats (51.2 MB)

  int nz = 1600000 + 6400;  // cnt + hist
  k_zero<<<(nz + 255) / 256, 256, 0, stream>>>(cnt, nz);
  k_count<<<(N_EDGES + 255) / 256, 256, 0, stream>>>(ei, et, cnt, hist);
  k_scan<<<1, 1024, 0, stream>>>(hist, boff, cursor);
  k_scatter<<<(N_EDGES + 255) / 256, 256, 0, stream>>>(ei, et, cursor, es2, emeta);

  k_rgcn<64, false><<<NBUCK, 512, 0, stream>>>(x, w1, r1, b1, cnt, boff, es2, emeta, h);
  k_rgcn<32, true><<<NBUCK, 512, 0, stream>>>(h, w2, r2, b2, cnt, boff, es2, emeta, out);
}

// Round 4
// 1169.623 us; speedup vs baseline: 3.8525x; 1.1612x over previous
//
#include <hip/hip_runtime.h>

#define N_NODES 200000
#define N_EDGES 1250000
#define N_RELS 8
#define NBUCK 6250   // N_NODES / 32

typedef __attribute__((ext_vector_type(8))) short short8v;
typedef __attribute__((ext_vector_type(4))) float f32x4;

// ---------------- setup kernels ----------------

__global__ void k_zero(int* __restrict__ p, int n) {
  int i = blockIdx.x * 256 + threadIdx.x;
  if (i < n) p[i] = 0;
}

__global__ void k_count(const int* __restrict__ ei, const int* __restrict__ et,
                        int* __restrict__ cnt, int* __restrict__ hist) {
  int e = blockIdx.x * 256 + threadIdx.x;
  if (e < N_EDGES) {
    int dst = ei[N_EDGES + e];
    int r = et[e];
    atomicAdd(&cnt[dst * N_RELS + r], 1);
    atomicAdd(&hist[dst >> 5], 1);
  }
}

__global__ __launch_bounds__(1024) void k_scan(const int* __restrict__ hist,
                                               int* __restrict__ boff,
                                               int* __restrict__ cursor) {
  __shared__ int s[1024];
  int t = threadIdx.x;
  int base = t * 8;
  int v[8];
  int sum = 0;
#pragma unroll
  for (int j = 0; j < 8; ++j) {
    v[j] = (base + j < NBUCK) ? hist[base + j] : 0;
    sum += v[j];
  }
  s[t] = sum;
  __syncthreads();
  for (int off = 1; off < 1024; off <<= 1) {
    int a = (t >= off) ? s[t - off] : 0;
    __syncthreads();
    s[t] += a;
    __syncthreads();
  }
  int run = (t > 0) ? s[t - 1] : 0;
#pragma unroll
  for (int j = 0; j < 8; ++j) {
    int i = base + j;
    if (i < NBUCK) { boff[i] = run; cursor[i] = run; }
    else if (i == NBUCK) boff[i] = run;
    run += v[j];
  }
}

__global__ void k_scatter(const int* __restrict__ ei, const int* __restrict__ et,
                          int* __restrict__ cursor, int* __restrict__ es2,
                          int* __restrict__ emeta) {
  int e = blockIdx.x * 256 + threadIdx.x;
  if (e < N_EDGES) {
    int src = ei[e];
    int dst = ei[N_EDGES + e];
    int r = et[e];
    int pos = atomicAdd(&cursor[dst >> 5], 1);
    es2[pos] = src;
    emeta[pos] = ((dst & 31) << 3) | r;
  }
}

// Build Bt_hi/Bt_lo [ncol][576] (bf16 as ushort): k<512 from W[512][ncol],
// k>=512 from Root[64][ncol]. hi = trunc-bf16(w), lo = trunc-bf16(w - hi).
__global__ void k_prep(const float* __restrict__ W, const float* __restrict__ Root,
                       ushort* __restrict__ bhi, ushort* __restrict__ blo, int ncol) {
  int i = blockIdx.x * 256 + threadIdx.x;
  if (i >= ncol * 576) return;
  int col = i / 576, k = i - col * 576;
  float w = (k < 512) ? W[k * ncol + col] : Root[(k - 512) * ncol + col];
  unsigned ub = __float_as_uint(w);
  unsigned hb = ub & 0xFFFF0000u;
  float lo = w - __uint_as_float(hb);
  bhi[i] = (ushort)(ub >> 16);
  blo[i] = (ushort)(__float_as_uint(lo) >> 16);
}

// ---------------- fused aggregate + MFMA transform ----------------
// Block: 32 dsts, 512 threads (8 waves). agg[256 rows][64 f] f32 in LDS,
// row = dlocal*8 + rel, swizzled in 4-word blocks:
//   idx(row,f) = row*64 + ((((f>>2)+(row>>3))&15)<<2) + (f&3)
// Phase 1: balanced raw-sum LDS atomics. Phase 2: per-wave 16x16 tiles,
// K=576 (8 rels*64 + 64 root), split-bf16 (hi/lo) 3xMFMA f32 emulation.

__device__ __forceinline__ int aidx(int row, int f) {
  return (row << 6) + (((((f >> 2) + (row >> 3)) & 15) << 2) | (f & 3));
}

__device__ __forceinline__ void split8(const float* v, short8v& ah, short8v& al) {
  union { unsigned u[4]; short8v s; } H, L;
#pragma unroll
  for (int j = 0; j < 4; ++j) {
    unsigned u0 = __float_as_uint(v[2 * j]);
    unsigned u1 = __float_as_uint(v[2 * j + 1]);
    unsigned h0 = u0 & 0xFFFF0000u, h1 = u1 & 0xFFFF0000u;
    H.u[j] = h1 | (h0 >> 16);
    float l0 = v[2 * j] - __uint_as_float(h0);
    float l1 = v[2 * j + 1] - __uint_as_float(h1);
    L.u[j] = (__float_as_uint(l1) & 0xFFFF0000u) | (__float_as_uint(l0) >> 16);
  }
  ah = H.s;
  al = L.s;
}

template <int NCOL, bool RELU>
__global__ __launch_bounds__(512, 4) void k_rgcn(
    const float* __restrict__ X, const ushort* __restrict__ Bhi,
    const ushort* __restrict__ Blo, const float* __restrict__ Bias,
    const int* __restrict__ cnt, const int* __restrict__ boff,
    const int* __restrict__ es2, const int* __restrict__ emeta,
    float* __restrict__ Out) {
  __shared__ float agg[32 * 512];   // 64 KB
  __shared__ float inv_lds[256];    // [rel][dstLocal]
  __shared__ float bias_lds[64];

  int t = threadIdx.x;
  int b = blockIdx.x;
  int d0 = b * 32;
  int lane = t & 63, w = t >> 6;

  // zero agg + tables
  f32x4* agg4 = (f32x4*)agg;
#pragma unroll
  for (int q = 0; q < 8; ++q) agg4[t + q * 512] = (f32x4){0.f, 0.f, 0.f, 0.f};
  if (t < 256) {
    int c = cnt[d0 * 8 + t];                       // t = dl*8 + rel
    inv_lds[(t & 7) * 32 + (t >> 3)] = 1.0f / (float)(c < 1 ? 1 : c);
  }
  if (t < NCOL) bias_lds[t] = Bias[t];
  __syncthreads();

  // ---- phase 1: balanced raw-sum aggregation ----
  int start = boff[b], end = boff[b + 1];
  for (int e8 = start + w * 8; e8 < end; e8 += 64) {
    int n = end - e8; if (n > 8) n = 8;
    int vx = 0, vy = 0;
    if (lane < n) { vx = es2[e8 + lane]; vy = emeta[e8 + lane]; }
    if (n == 8) {
      float xv[8]; int rw[8];
#pragma unroll
      for (int u = 0; u < 8; ++u) {
        int s = __shfl(vx, u);
        rw[u] = __shfl(vy, u);
        float v = X[(size_t)s * 64 + lane];
        if (RELU) v = fmaxf(v, 0.f);
        xv[u] = v;
      }
#pragma unroll
      for (int u = 0; u < 8; ++u) atomicAdd(&agg[aidx(rw[u], lane)], xv[u]);
    } else {
      for (int u = 0; u < n; ++u) {
        int s = __shfl(vx, u);
        int row = __shfl(vy, u);
        float v = X[(size_t)s * 64 + lane];
        if (RELU) v = fmaxf(v, 0.f);
        atomicAdd(&agg[aidx(row, lane)], v);
      }
    }
  }
  __syncthreads();

  // ---- phase 2: split-bf16 MFMA GEMM ----
  constexpr int NKS = (NCOL == 64) ? 18 : 9;
  constexpr int KSTEP = (NCOL == 64) ? 1 : 2;
  int wm, wn, ks0;
  if (NCOL == 64) { wm = w >> 2; wn = w & 3; ks0 = 0; }
  else { wm = (w >> 1) & 1; wn = w & 1; ks0 = w >> 2; }
  int l15 = lane & 15;
  int kg = lane >> 4;
  int d = wm * 16 + l15;            // A row (dst local)
  int col = wn * 16 + l15;          // B col

  f32x4 acc_hh = {0.f, 0.f, 0.f, 0.f};
  f32x4 acc_lh = {0.f, 0.f, 0.f, 0.f};
  f32x4 acc_hl = {0.f, 0.f, 0.f, 0.f};

  const size_t bbase = (size_t)col * 576;

#pragma unroll 3
  for (int ii = 0; ii < NKS; ++ii) {
    int ks = ks0 + ii * KSTEP;
    // B fragments (global, L2-resident)
    union { uint4 q; short8v s; } bh, bl;
    size_t bo = bbase + ks * 32 + kg * 8;
    bh.q = *(const uint4*)(Bhi + bo);
    bl.q = *(const uint4*)(Blo + bo);
    // A fragment: 8 f32
    float v[8];
    if (ii * KSTEP < 16) {                    // relation K-range (from agg)
      int rr = ks >> 1;
      int row = (d << 3) + rr;
      int f = ((ks & 1) << 5) + (kg << 3);
      float4 a0 = *(const float4*)&agg[aidx(row, f)];
      float4 a1 = *(const float4*)&agg[aidx(row, f + 4)];
      float s = inv_lds[rr * 32 + d];
      v[0] = a0.x * s; v[1] = a0.y * s; v[2] = a0.z * s; v[3] = a0.w * s;
      v[4] = a1.x * s; v[5] = a1.y * s; v[6] = a1.z * s; v[7] = a1.w * s;
    } else {                                  // root K-range (from X rows)
      int kb = (ks - 16) * 32 + (kg << 3);
      float4 a0 = *(const float4*)&X[(size_t)(d0 + d) * 64 + kb];
      float4 a1 = *(const float4*)&X[(size_t)(d0 + d) * 64 + kb + 4];
      if (RELU) {
        a0.x = fmaxf(a0.x, 0.f); a0.y = fmaxf(a0.y, 0.f);
        a0.z = fmaxf(a0.z, 0.f); a0.w = fmaxf(a0.w, 0.f);
        a1.x = fmaxf(a1.x, 0.f); a1.y = fmaxf(a1.y, 0.f);
        a1.z = fmaxf(a1.z, 0.f); a1.w = fmaxf(a1.w, 0.f);
      }
      v[0] = a0.x; v[1] = a0.y; v[2] = a0.z; v[3] = a0.w;
      v[4] = a1.x; v[5] = a1.y; v[6] = a1.z; v[7] = a1.w;
    }
    short8v ah, al;
    split8(v, ah, al);
    acc_hh = __builtin_amdgcn_mfma_f32_16x16x32_bf16(ah, bh.s, acc_hh, 0, 0, 0);
    acc_lh = __builtin_amdgcn_mfma_f32_16x16x32_bf16(al, bh.s, acc_lh, 0, 0, 0);
    acc_hl = __builtin_amdgcn_mfma_f32_16x16x32_bf16(ah, bl.s, acc_hl, 0, 0, 0);
  }

  float osum[4];
#pragma unroll
  for (int i = 0; i < 4; ++i) osum[i] = acc_hh[i] + acc_lh[i] + acc_hl[i];

  // ---- epilogue ----
  if (NCOL == 64) {
#pragma unroll
    for (int i = 0; i < 4; ++i) {
      int rrow = wm * 16 + kg * 4 + i;
      Out[(size_t)(d0 + rrow) * 64 + col] = osum[i] + bias_lds[col];
    }
  } else {
    int wk = w >> 2;
    __syncthreads();                 // all agg reads done
    if (wk == 1) {
#pragma unroll
      for (int i = 0; i < 4; ++i)
        agg[(wm * 16 + kg * 4 + i) * 32 + col] = osum[i];
    }
    __syncthreads();
    if (wk == 0) {
#pragma unroll
      for (int i = 0; i < 4; ++i) {
        int rrow = wm * 16 + kg * 4 + i;
        Out[(size_t)(d0 + rrow) * 32 + col] =
            osum[i] + agg[rrow * 32 + col] + bias_lds[col];
      }
    }
  }
}

// ---------------- launch ----------------

extern "C" void kernel_launch(void* const* d_in, const int* in_sizes, int n_in,
                              void* d_out, int out_size, void* d_ws, size_t ws_size,
                              hipStream_t stream) {
  const float* x = (const float*)d_in[0];
  const int* ei = (const int*)d_in[1];
  const int* et = (const int*)d_in[2];
  const float* w1 = (const float*)d_in[3];
  const float* r1 = (const float*)d_in[4];
  const float* b1 = (const float*)d_in[5];
  const float* w2 = (const float*)d_in[6];
  const float* r2 = (const float*)d_in[7];
  const float* b2 = (const float*)d_in[8];
  float* out = (float*)d_out;

  int* cnt = (int*)d_ws;                  // 1,600,000
  int* hist = cnt + 1600000;              // 6400
  int* cursor = hist + 6400;              // 6400
  int* boff = cursor + 6400;              // 6400 (6251 used)
  int* es2 = boff + 6400;                 // 1,250,000
  int* emeta = es2 + N_EDGES;             // 1,250,000
  ushort* bt1h = (ushort*)(emeta + N_EDGES);   // 64*576
  ushort* bt1l = bt1h + 64 * 576;
  ushort* bt2h = bt1l + 64 * 576;              // 32*576
  ushort* bt2l = bt2h + 32 * 576;
  float* h = (float*)(bt2l + 32 * 576);        // [N,64] 51.2 MB

  int nz = 1600000 + 6400;  // cnt + hist
  k_zero<<<(nz + 255) / 256, 256, 0, stream>>>(cnt, nz);
  k_count<<<(N_EDGES + 255) / 256, 256, 0, stream>>>(ei, et, cnt, hist);
  k_scan<<<1, 1024, 0, stream>>>(hist, boff, cursor);
  k_scatter<<<(N_EDGES + 255) / 256, 256, 0, stream>>>(ei, et, cursor, es2, emeta);
  k_prep<<<(64 * 576 + 255) / 256, 256, 0, stream>>>(w1, r1, bt1h, bt1l, 64);
  k_prep<<<(32 * 576 + 255) / 256, 256, 0, stream>>>(w2, r2, bt2h, bt2l, 32);

  k_rgcn<64, false><<<NBUCK, 512, 0, stream>>>(x, bt1h, bt1l, b1, cnt, boff, es2, emeta, h);
  k_rgcn<32, true><<<NBUCK, 512, 0, stream>>>(h, bt2h, bt2l, b2, cnt, boff, es2, emeta, out);
}

// Round 5
// 1107.388 us; speedup vs baseline: 4.0690x; 1.0562x over previous
//
#include <hip/hip_runtime.h>

#define N_NODES 200000
#define N_EDGES 1250000
#define N_RELS 8
#define NBUCK 6250   // N_NODES / 32

typedef __attribute__((ext_vector_type(8))) short short8v;
typedef __attribute__((ext_vector_type(4))) float f32x4;

// ---------------- setup kernels ----------------

__global__ void k_zero(int* __restrict__ p, int n) {
  int i = blockIdx.x * 256 + threadIdx.x;
  if (i < n) p[i] = 0;
}

__global__ void k_count(const int* __restrict__ ei, const int* __restrict__ et,
                        int* __restrict__ cnt) {
  int e = blockIdx.x * 256 + threadIdx.x;
  if (e < N_EDGES) {
    int dst = ei[N_EDGES + e];
    int r = et[e];
    atomicAdd(&cnt[dst * N_RELS + r], 1);
  }
}

// hist[b] = sum of the 256 cnt entries of bucket b (64 threads/bucket, int4)
__global__ __launch_bounds__(64) void k_hist(const int* __restrict__ cnt,
                                             int* __restrict__ hist) {
  int b = blockIdx.x;
  int t = threadIdx.x;
  int4 v = *(const int4*)&cnt[b * 256 + t * 4];
  int s = v.x + v.y + v.z + v.w;
#pragma unroll
  for (int off = 32; off >= 1; off >>= 1) s += __shfl_down(s, off);
  if (t == 0) hist[b] = s;
}

__global__ __launch_bounds__(1024) void k_scan(const int* __restrict__ hist,
                                               int* __restrict__ boff,
                                               int* __restrict__ cursor) {
  __shared__ int s[1024];
  int t = threadIdx.x;
  int base = t * 8;
  int v[8];
  int sum = 0;
#pragma unroll
  for (int j = 0; j < 8; ++j) {
    v[j] = (base + j < NBUCK) ? hist[base + j] : 0;
    sum += v[j];
  }
  s[t] = sum;
  __syncthreads();
  for (int off = 1; off < 1024; off <<= 1) {
    int a = (t >= off) ? s[t - off] : 0;
    __syncthreads();
    s[t] += a;
    __syncthreads();
  }
  int run = (t > 0) ? s[t - 1] : 0;
#pragma unroll
  for (int j = 0; j < 8; ++j) {
    int i = base + j;
    if (i < NBUCK) { boff[i] = run; cursor[i] = run; }
    else if (i == NBUCK) boff[i] = run;
    run += v[j];
  }
}

__global__ void k_scatter(const int* __restrict__ ei, const int* __restrict__ et,
                          int* __restrict__ cursor, int2* __restrict__ e2) {
  int e = blockIdx.x * 256 + threadIdx.x;
  if (e < N_EDGES) {
    int src = ei[e];
    int dst = ei[N_EDGES + e];
    int r = et[e];
    int pos = atomicAdd(&cursor[dst >> 5], 1);
    e2[pos] = make_int2(src, ((dst & 31) << 3) | r);
  }
}

// Build Bf in MFMA fragment order: slab (ks, wn) of 1024 ushorts:
//   [0..511]  hi: lane*8 + j  ->  bf16hi( B[k = ks*32 + (lane>>4)*8 + j][col = wn*16 + (lane&15)] )
//   [512..1023] lo: same for residual.
// B rows: k<512 from W[512][ncol] (k = rel*64+feat), k>=512 from Root[64][ncol].
__global__ void k_prep(const float* __restrict__ W, const float* __restrict__ Root,
                       ushort* __restrict__ Bf, int ncol) {
  int i = blockIdx.x * 256 + threadIdx.x;
  if (i >= ncol * 576) return;
  int col = i / 576, k = i - col * 576;
  float w = (k < 512) ? W[k * ncol + col] : Root[(k - 512) * ncol + col];
  unsigned ub = __float_as_uint(w);
  unsigned hb = ub & 0xFFFF0000u;
  float lo = w - __uint_as_float(hb);
  int WN = ncol >> 4;
  int ks = k >> 5, kg = (k >> 3) & 3, j = k & 7;
  int wn = col >> 4, l15 = col & 15;
  int lane = (kg << 4) | l15;
  int dest = (ks * WN + wn) * 1024 + lane * 8 + j;
  Bf[dest] = (ushort)(ub >> 16);
  Bf[dest + 512] = (ushort)(__float_as_uint(lo) >> 16);
}

// ---------------- fused aggregate + MFMA transform ----------------
// Block: 32 dsts, 512 threads (8 waves). agg[256 rows][64 f] f32 in LDS,
// row = dlocal*8 + rel, 4-word-block swizzle:
//   idx(row,f) = row*64 + ((((f>>2)+(row>>3))&15)<<2) + (f&3)
// Phase 1: raw-sum LDS atomics. Prescale: agg row *= 1/cnt.
// Phase 2: per-wave M=32 x N=16 tile, K=576, split-bf16 3xMFMA emulation,
// K split across waves (2-way L1 / 4-way L2), LDS reduce + bias epilogue.

__device__ __forceinline__ int aidx(int row, int f) {
  return (row << 6) + (((((f >> 2) + (row >> 3)) & 15) << 2) | (f & 3));
}

__device__ __forceinline__ void split8(const float* v, short8v& ah, short8v& al) {
  union { unsigned u[4]; short8v s; } H, L;
#pragma unroll
  for (int j = 0; j < 4; ++j) {
    unsigned u0 = __float_as_uint(v[2 * j]);
    unsigned u1 = __float_as_uint(v[2 * j + 1]);
    unsigned h0 = u0 & 0xFFFF0000u, h1 = u1 & 0xFFFF0000u;
    H.u[j] = h1 | (h0 >> 16);
    float l0 = v[2 * j] - __uint_as_float(h0);
    float l1 = v[2 * j + 1] - __uint_as_float(h1);
    L.u[j] = (__float_as_uint(l1) & 0xFFFF0000u) | (__float_as_uint(l0) >> 16);
  }
  ah = H.s;
  al = L.s;
}

template <int NCOL, bool RELU>
__global__ __launch_bounds__(512, 4) void k_rgcn(
    const float* __restrict__ X, const ushort* __restrict__ Bf,
    const float* __restrict__ Bias, const int* __restrict__ cnt,
    const int* __restrict__ boff, const int2* __restrict__ e2,
    float* __restrict__ Out) {
  constexpr int WN = NCOL / 16;
  constexpr int KSPLIT = (NCOL == 64) ? 2 : 4;

  __shared__ float agg[32 * 512];             // 64 KB
  __shared__ float inv_lds[256];              // [row = dl*8+rel]
  __shared__ __align__(16) float bias_lds[64];

  int t = threadIdx.x;
  int b = blockIdx.x;
  int d0 = b * 32;
  int lane = t & 63, w = t >> 6;

  // zero agg + tables
  f32x4* agg4 = (f32x4*)agg;
#pragma unroll
  for (int q = 0; q < 8; ++q) agg4[t + q * 512] = (f32x4){0.f, 0.f, 0.f, 0.f};
  if (t < 256) {
    int c = cnt[d0 * 8 + t];
    inv_lds[t] = 1.0f / (float)(c < 1 ? 1 : c);
  }
  if (t < NCOL) bias_lds[t] = Bias[t];
  __syncthreads();

  // ---- phase 1: raw-sum aggregation (8-edge batches per wave) ----
  int start = boff[b], end = boff[b + 1];
  for (int e8 = start + w * 8; e8 < end; e8 += 64) {
    int n = end - e8; if (n > 8) n = 8;
    int vx = 0, vy = 0;
    if (lane < n) { int2 sm = e2[e8 + lane]; vx = sm.x; vy = sm.y; }
    if (n == 8) {
      float xv[8]; int rw[8];
#pragma unroll
      for (int u = 0; u < 8; ++u) {
        int s = __shfl(vx, u);
        rw[u] = __shfl(vy, u);
        float v = X[(size_t)s * 64 + lane];
        if (RELU) v = fmaxf(v, 0.f);
        xv[u] = v;
      }
#pragma unroll
      for (int u = 0; u < 8; ++u) atomicAdd(&agg[aidx(rw[u], lane)], xv[u]);
    } else {
      for (int u = 0; u < n; ++u) {
        int s = __shfl(vx, u);
        int row = __shfl(vy, u);
        float v = X[(size_t)s * 64 + lane];
        if (RELU) v = fmaxf(v, 0.f);
        atomicAdd(&agg[aidx(row, lane)], v);
      }
    }
  }
  __syncthreads();

  // ---- prescale rows by 1/cnt (swizzle is intra-row; row-uniform scale ok) ----
#pragma unroll
  for (int q = 0; q < 8; ++q) {
    int i4 = t + q * 512;
    float s = inv_lds[i4 >> 4];
    f32x4 v = agg4[i4];
    v *= s;
    agg4[i4] = v;
  }
  __syncthreads();

  // ---- phase 2: split-bf16 MFMA GEMM, M=32 per wave ----
  int wn, ksp;
  if (NCOL == 64) { wn = w & 3; ksp = w >> 2; }
  else { wn = w & 1; ksp = w >> 1; }
  int l15 = lane & 15, kg = lane >> 4;
  int col = wn * 16 + l15;

  f32x4 hh0 = {0.f,0.f,0.f,0.f}, lh0 = hh0, hl0 = hh0;
  f32x4 hh1 = hh0, lh1 = hh0, hl1 = hh0;

#pragma unroll 3
  for (int ks = ksp; ks < 18; ks += KSPLIT) {
    const ushort* bp = Bf + (ks * WN + wn) * 1024 + lane * 8;
    union { uint4 q; short8v s; } bh, bl;
    bh.q = *(const uint4*)bp;
    bl.q = *(const uint4*)(bp + 512);

    float v0[8], v1[8];
    if (ks < 16) {
      int rr = ks >> 1;
      int f = ((ks & 1) << 5) + (kg << 3);
      int row0 = (l15 << 3) + rr;
      float4 a0 = *(const float4*)&agg[aidx(row0, f)];
      float4 a1 = *(const float4*)&agg[aidx(row0, f + 4)];
      v0[0]=a0.x; v0[1]=a0.y; v0[2]=a0.z; v0[3]=a0.w;
      v0[4]=a1.x; v0[5]=a1.y; v0[6]=a1.z; v0[7]=a1.w;
      int row1 = ((16 + l15) << 3) + rr;
      float4 c0 = *(const float4*)&agg[aidx(row1, f)];
      float4 c1 = *(const float4*)&agg[aidx(row1, f + 4)];
      v1[0]=c0.x; v1[1]=c0.y; v1[2]=c0.z; v1[3]=c0.w;
      v1[4]=c1.x; v1[5]=c1.y; v1[6]=c1.z; v1[7]=c1.w;
    } else {
      int kb = ((ks - 16) << 5) + (kg << 3);
      float4 a0 = *(const float4*)&X[(size_t)(d0 + l15) * 64 + kb];
      float4 a1 = *(const float4*)&X[(size_t)(d0 + l15) * 64 + kb + 4];
      float4 c0 = *(const float4*)&X[(size_t)(d0 + 16 + l15) * 64 + kb];
      float4 c1 = *(const float4*)&X[(size_t)(d0 + 16 + l15) * 64 + kb + 4];
      if (RELU) {
        a0.x=fmaxf(a0.x,0.f); a0.y=fmaxf(a0.y,0.f); a0.z=fmaxf(a0.z,0.f); a0.w=fmaxf(a0.w,0.f);
        a1.x=fmaxf(a1.x,0.f); a1.y=fmaxf(a1.y,0.f); a1.z=fmaxf(a1.z,0.f); a1.w=fmaxf(a1.w,0.f);
        c0.x=fmaxf(c0.x,0.f); c0.y=fmaxf(c0.y,0.f); c0.z=fmaxf(c0.z,0.f); c0.w=fmaxf(c0.w,0.f);
        c1.x=fmaxf(c1.x,0.f); c1.y=fmaxf(c1.y,0.f); c1.z=fmaxf(c1.z,0.f); c1.w=fmaxf(c1.w,0.f);
      }
      v0[0]=a0.x; v0[1]=a0.y; v0[2]=a0.z; v0[3]=a0.w;
      v0[4]=a1.x; v0[5]=a1.y; v0[6]=a1.z; v0[7]=a1.w;
      v1[0]=c0.x; v1[1]=c0.y; v1[2]=c0.z; v1[3]=c0.w;
      v1[4]=c1.x; v1[5]=c1.y; v1[6]=c1.z; v1[7]=c1.w;
    }
    short8v ah0, al0, ah1, al1;
    split8(v0, ah0, al0);
    split8(v1, ah1, al1);
    hh0 = __builtin_amdgcn_mfma_f32_16x16x32_bf16(ah0, bh.s, hh0, 0, 0, 0);
    lh0 = __builtin_amdgcn_mfma_f32_16x16x32_bf16(al0, bh.s, lh0, 0, 0, 0);
    hl0 = __builtin_amdgcn_mfma_f32_16x16x32_bf16(ah0, bl.s, hl0, 0, 0, 0);
    hh1 = __builtin_amdgcn_mfma_f32_16x16x32_bf16(ah1, bh.s, hh1, 0, 0, 0);
    lh1 = __builtin_amdgcn_mfma_f32_16x16x32_bf16(al1, bh.s, lh1, 0, 0, 0);
    hl1 = __builtin_amdgcn_mfma_f32_16x16x32_bf16(ah1, bl.s, hl1, 0, 0, 0);
  }

  // ---- reduce K-split partials (reuse agg as red[KSPLIT][32][NCOL]) ----
  __syncthreads();   // all agg reads complete
  float* red = agg;
#pragma unroll
  for (int i = 0; i < 4; ++i) {
    int r0 = kg * 4 + i;
    red[(ksp * 32 + r0) * NCOL + col] = hh0[i] + lh0[i] + hl0[i];
    red[(ksp * 32 + 16 + r0) * NCOL + col] = hh1[i] + lh1[i] + hl1[i];
  }
  __syncthreads();

  if (NCOL == 64) {
    int idx = t * 4;
    float4 s = *(const float4*)&red[idx];
    float4 u = *(const float4*)&red[2048 + idx];
    s.x += u.x; s.y += u.y; s.z += u.z; s.w += u.w;
    int c = idx & 63;
    float4 bv = *(const float4*)&bias_lds[c];
    s.x += bv.x; s.y += bv.y; s.z += bv.z; s.w += bv.w;
    *(float4*)&Out[(size_t)(d0 + (idx >> 6)) * 64 + c] = s;
  } else {
    int idx = t * 2;
    float2 s = *(const float2*)&red[idx];
#pragma unroll
    for (int p = 1; p < 4; ++p) {
      float2 u = *(const float2*)&red[p * 1024 + idx];
      s.x += u.x; s.y += u.y;
    }
    int c = idx & 31;
    float2 bv = *(const float2*)&bias_lds[c];
    s.x += bv.x; s.y += bv.y;
    *(float2*)&Out[(size_t)(d0 + (idx >> 5)) * 32 + c] = s;
  }
}

// ---------------- launch ----------------

extern "C" void kernel_launch(void* const* d_in, const int* in_sizes, int n_in,
                              void* d_out, int out_size, void* d_ws, size_t ws_size,
                              hipStream_t stream) {
  const float* x = (const float*)d_in[0];
  const int* ei = (const int*)d_in[1];
  const int* et = (const int*)d_in[2];
  const float* w1 = (const float*)d_in[3];
  const float* r1 = (const float*)d_in[4];
  const float* b1 = (const float*)d_in[5];
  const float* w2 = (const float*)d_in[6];
  const float* r2 = (const float*)d_in[7];
  const float* b2 = (const float*)d_in[8];
  float* out = (float*)d_out;

  int* cnt = (int*)d_ws;                  // 1,600,000 ints
  int* hist = cnt + 1600000;              // 6256
  int* cursor = hist + 6256;              // 6256
  int* boff = cursor + 6256;              // 6256 (6251 used)
  int2* e2 = (int2*)(boff + 6256);        // 1,250,000 int2 (10 MB)
  ushort* bf1 = (ushort*)(e2 + N_EDGES);  // 73728 ushort (144 KB)
  ushort* bf2 = bf1 + 73728;              // 36864 ushort (72 KB)
  float* h = (float*)(bf2 + 36864);       // [N,64] 51.2 MB

  k_zero<<<(1600000 + 255) / 256, 256, 0, stream>>>(cnt, 1600000);
  k_count<<<(N_EDGES + 255) / 256, 256, 0, stream>>>(ei, et, cnt);
  k_prep<<<(64 * 576 + 255) / 256, 256, 0, stream>>>(w1, r1, bf1, 64);
  k_prep<<<(32 * 576 + 255) / 256, 256, 0, stream>>>(w2, r2, bf2, 32);
  k_hist<<<NBUCK, 64, 0, stream>>>(cnt, hist);
  k_scan<<<1, 1024, 0, stream>>>(hist, boff, cursor);
  k_scatter<<<(N_EDGES + 255) / 256, 256, 0, stream>>>(ei, et, cursor, e2);

  k_rgcn<64, false><<<NBUCK, 512, 0, stream>>>(x, bf1, b1, cnt, boff, e2, h);
  k_rgcn<32, true><<<NBUCK, 512, 0, stream>>>(h, bf2, b2, cnt, boff, e2, out);
}

// Round 6
// 1089.647 us; speedup vs baseline: 4.1353x; 1.0163x over previous
//
#include <hip/hip_runtime.h>

#define N_NODES 200000
#define N_EDGES 1250000
#define N_RELS 8
#define NBUCK 12500   // N_NODES / 16

typedef __attribute__((ext_vector_type(8))) short short8v;
typedef __attribute__((ext_vector_type(4))) float f32x4;

__device__ __forceinline__ ushort rne_bf16(float v) {
  unsigned u = __float_as_uint(v);
  return (ushort)((u + 0x7FFFu + ((u >> 16) & 1u)) >> 16);
}

// ---------------- setup kernels ----------------

__global__ void k_zero(int* __restrict__ p, int n) {
  int i = blockIdx.x * 256 + threadIdx.x;
  if (i < n) p[i] = 0;
}

__global__ void k_count(const int* __restrict__ ei, const int* __restrict__ et,
                        int* __restrict__ cnt) {
  int e = blockIdx.x * 256 + threadIdx.x;
  if (e < N_EDGES) {
    int dst = ei[N_EDGES + e];
    int r = et[e];
    atomicAdd(&cnt[dst * N_RELS + r], 1);
  }
}

// hist[b] = sum of the 128 cnt entries of bucket b
__global__ __launch_bounds__(64) void k_hist(const int* __restrict__ cnt,
                                             int* __restrict__ hist) {
  int b = blockIdx.x;
  int t = threadIdx.x;
  int2 v = ((const int2*)cnt)[b * 64 + t];
  int s = v.x + v.y;
#pragma unroll
  for (int off = 32; off >= 1; off >>= 1) s += __shfl_down(s, off);
  if (t == 0) hist[b] = s;
}

__global__ __launch_bounds__(1024) void k_scan(const int* __restrict__ hist,
                                               int* __restrict__ boff,
                                               int* __restrict__ cursor) {
  __shared__ int s[1024];
  int t = threadIdx.x;
  int base = t * 16;
  int v[16];
  int sum = 0;
#pragma unroll
  for (int j = 0; j < 16; ++j) {
    v[j] = (base + j < NBUCK) ? hist[base + j] : 0;
    sum += v[j];
  }
  s[t] = sum;
  __syncthreads();
  for (int off = 1; off < 1024; off <<= 1) {
    int a = (t >= off) ? s[t - off] : 0;
    __syncthreads();
    s[t] += a;
    __syncthreads();
  }
  int run = (t > 0) ? s[t - 1] : 0;
#pragma unroll
  for (int j = 0; j < 16; ++j) {
    int i = base + j;
    if (i < NBUCK) { boff[i] = run; cursor[i] = run; }
    else if (i == NBUCK) boff[i] = run;
    run += v[j];
  }
}

__global__ void k_scatter(const int* __restrict__ ei, const int* __restrict__ et,
                          int* __restrict__ cursor, int2* __restrict__ e2) {
  int e = blockIdx.x * 256 + threadIdx.x;
  if (e < N_EDGES) {
    int src = ei[e];
    int dst = ei[N_EDGES + e];
    int r = et[e];
    int pos = atomicAdd(&cursor[dst >> 4], 1);
    e2[pos] = make_int2(src, ((dst & 15) << 3) | r);
  }
}

// x (f32) -> bf16 (RNE), 8 elems/thread
__global__ void k_xcast(const float* __restrict__ X, ushort* __restrict__ Xb, int n8) {
  int i = blockIdx.x * 256 + threadIdx.x;
  if (i >= n8) return;
  float4 a = ((const float4*)X)[i * 2];
  float4 b = ((const float4*)X)[i * 2 + 1];
  union { uint4 q; ushort u[8]; } o;
  o.u[0] = rne_bf16(a.x); o.u[1] = rne_bf16(a.y);
  o.u[2] = rne_bf16(a.z); o.u[3] = rne_bf16(a.w);
  o.u[4] = rne_bf16(b.x); o.u[5] = rne_bf16(b.y);
  o.u[6] = rne_bf16(b.z); o.u[7] = rne_bf16(b.w);
  ((uint4*)Xb)[i] = o.q;
}

// Bf fragment-order hi/lo slabs (as round 5): slab (ks,wn): 512 hi + 512 lo.
__global__ void k_prep(const float* __restrict__ W, const float* __restrict__ Root,
                       ushort* __restrict__ Bf, int ncol) {
  int i = blockIdx.x * 256 + threadIdx.x;
  if (i >= ncol * 576) return;
  int col = i / 576, k = i - col * 576;
  float w = (k < 512) ? W[k * ncol + col] : Root[(k - 512) * ncol + col];
  unsigned ub = __float_as_uint(w);
  unsigned hb = ub & 0xFFFF0000u;
  float lo = w - __uint_as_float(hb);
  int WN = ncol >> 4;
  int ks = k >> 5, kg = (k >> 3) & 3, j = k & 7;
  int wn = col >> 4, l15 = col & 15;
  int lane = (kg << 4) | l15;
  int dest = (ks * WN + wn) * 1024 + lane * 8 + j;
  Bf[dest] = (ushort)(ub >> 16);
  Bf[dest + 512] = (ushort)(__float_as_uint(lo) >> 16);
}

// ---------------- fused aggregate + MFMA transform ----------------
// Block: 16 dsts, 512 threads, ~37KB LDS -> 4 blocks/CU (32 waves).
// agg[128 rows][64 f] f32, row = dl*8+rel, 4-word-block swizzle.
// Phase 1: metas pre-staged in LDS; 8 independent bf16 gathers in flight
// per wave; raw-sum ds atomics; prescale by 1/cnt.
// Phase 2: per-wave M=16 x N=16, K=576, A-hi/lo x B-hi/lo 3-MFMA (rel K),
// bf16-direct 2-MFMA (root K). K split across waves, LDS reduce epilogue.

__device__ __forceinline__ int aidx(int row, int f) {
  return (row << 6) + (((((f >> 2) + (row >> 3)) & 15) << 2) | (f & 3));
}

__device__ __forceinline__ void split8(const float* v, short8v& ah, short8v& al) {
  union { unsigned u[4]; short8v s; } H, L;
#pragma unroll
  for (int j = 0; j < 4; ++j) {
    unsigned u0 = __float_as_uint(v[2 * j]);
    unsigned u1 = __float_as_uint(v[2 * j + 1]);
    unsigned h0 = u0 & 0xFFFF0000u, h1 = u1 & 0xFFFF0000u;
    H.u[j] = h1 | (h0 >> 16);
    float l0 = v[2 * j] - __uint_as_float(h0);
    float l1 = v[2 * j + 1] - __uint_as_float(h1);
    L.u[j] = (__float_as_uint(l1) & 0xFFFF0000u) | (__float_as_uint(l0) >> 16);
  }
  ah = H.s;
  al = L.s;
}

template <int NCOL, bool RELU, bool OUTBF>
__global__ __launch_bounds__(512, 8) void k_rgcn(
    const ushort* __restrict__ Xg, const ushort* __restrict__ Bf,
    const float* __restrict__ Bias, const int* __restrict__ cnt,
    const int* __restrict__ boff, const int2* __restrict__ e2,
    void* __restrict__ OutP) {
  constexpr int WN = NCOL / 16;
  constexpr int KSPLIT = (NCOL == 64) ? 2 : 4;

  __shared__ float agg[128 * 64];              // 32 KB
  __shared__ float inv_lds[128];
  __shared__ __align__(16) float bias_lds[64];
  __shared__ int2 smeta[512];                  // 4 KB

  int t = threadIdx.x;
  int b = blockIdx.x;
  int d0 = b * 16;
  int lane = t & 63, w = t >> 6;

  f32x4* agg4 = (f32x4*)agg;
#pragma unroll
  for (int q = 0; q < 4; ++q) agg4[t + q * 512] = (f32x4){0.f, 0.f, 0.f, 0.f};
  if (t < 128) {
    int c = cnt[d0 * 8 + t];
    inv_lds[t] = 1.0f / (float)(c < 1 ? 1 : c);
  }
  if (t < NCOL) bias_lds[t] = Bias[t];

  // ---- phase 1 ----
  int start = boff[b], end = boff[b + 1];
  for (int c0 = start; c0 < end; c0 += 512) {
    int n = end - c0; if (n > 512) n = 512;
    __syncthreads();
    if (t < n) smeta[t] = e2[c0 + t];
    __syncthreads();
    int per = (n + 7) >> 3;
    int wbeg = w * per;
    int wend = wbeg + per; if (wend > n) wend = n;
    int i0 = wbeg;
    for (; i0 + 8 <= wend; i0 += 8) {
      float xv[8]; int rw[8];
#pragma unroll
      for (int u = 0; u < 8; ++u) {
        int2 m = smeta[i0 + u];
        rw[u] = m.y;
        ushort hv = Xg[(size_t)m.x * 64 + lane];
        float f = __uint_as_float((unsigned)hv << 16);
        if (RELU) f = fmaxf(f, 0.f);
        xv[u] = f;
      }
#pragma unroll
      for (int u = 0; u < 8; ++u) atomicAdd(&agg[aidx(rw[u], lane)], xv[u]);
    }
    for (; i0 < wend; ++i0) {
      int2 m = smeta[i0];
      ushort hv = Xg[(size_t)m.x * 64 + lane];
      float f = __uint_as_float((unsigned)hv << 16);
      if (RELU) f = fmaxf(f, 0.f);
      atomicAdd(&agg[aidx(m.y, lane)], f);
    }
  }
  __syncthreads();

  // ---- prescale by 1/cnt ----
#pragma unroll
  for (int q = 0; q < 4; ++q) {
    int i4 = t + q * 512;
    float s = inv_lds[i4 >> 4];
    f32x4 v = agg4[i4];
    v *= s;
    agg4[i4] = v;
  }
  __syncthreads();

  // ---- phase 2: MFMA, M=16 per wave, K split across waves ----
  int wn, ksp;
  if (NCOL == 64) { wn = w & 3; ksp = w >> 2; }
  else { wn = w & 1; ksp = w >> 1; }
  int l15 = lane & 15, kg = lane >> 4;
  int col = wn * 16 + l15;

  f32x4 hh = {0.f, 0.f, 0.f, 0.f}, lh = hh, hl = hh;

  for (int ks = ksp; ks < 18; ks += KSPLIT) {
    const ushort* bp = Bf + (ks * WN + wn) * 1024 + lane * 8;
    union { uint4 q; short8v s; } bh, bl;
    bh.q = *(const uint4*)bp;
    bl.q = *(const uint4*)(bp + 512);
    if (ks < 16) {
      int rr = ks >> 1;
      int f = ((ks & 1) << 5) + (kg << 3);
      int row = (l15 << 3) + rr;
      float4 a0 = *(const float4*)&agg[aidx(row, f)];
      float4 a1 = *(const float4*)&agg[aidx(row, f + 4)];
      float v[8] = {a0.x, a0.y, a0.z, a0.w, a1.x, a1.y, a1.z, a1.w};
      short8v ah, al;
      split8(v, ah, al);
      hh = __builtin_amdgcn_mfma_f32_16x16x32_bf16(ah, bh.s, hh, 0, 0, 0);
      lh = __builtin_amdgcn_mfma_f32_16x16x32_bf16(al, bh.s, lh, 0, 0, 0);
      hl = __builtin_amdgcn_mfma_f32_16x16x32_bf16(ah, bl.s, hl, 0, 0, 0);
    } else {
      int kb = ((ks - 16) << 5) + (kg << 3);
      union { uint4 q; ushort us[8]; short8v s; } av;
      av.q = *(const uint4*)&Xg[(size_t)(d0 + l15) * 64 + kb];
      if (RELU) {
#pragma unroll
        for (int j = 0; j < 8; ++j)
          if (av.us[j] & 0x8000) av.us[j] = 0;
      }
      hh = __builtin_amdgcn_mfma_f32_16x16x32_bf16(av.s, bh.s, hh, 0, 0, 0);
      hl = __builtin_amdgcn_mfma_f32_16x16x32_bf16(av.s, bl.s, hl, 0, 0, 0);
    }
  }

  // ---- reduce K-split partials via LDS (reuse agg) ----
  __syncthreads();
  float* red = agg;
#pragma unroll
  for (int i = 0; i < 4; ++i)
    red[(ksp * 16 + kg * 4 + i) * NCOL + col] = hh[i] + lh[i] + hl[i];
  __syncthreads();

  if (NCOL == 64) {
    int idx = t * 2;
    float2 s = *(const float2*)&red[idx];
    float2 u = *(const float2*)&red[1024 + idx];
    s.x += u.x; s.y += u.y;
    int c = idx & 63;
    s.x += bias_lds[c];
    s.y += bias_lds[c + 1];
    if (OUTBF) {
      unsigned pk = ((unsigned)rne_bf16(s.y) << 16) | (unsigned)rne_bf16(s.x);
      ((unsigned*)OutP)[(size_t)d0 * 32 + t] = pk;
    } else {
      *(float2*)&((float*)OutP)[(size_t)d0 * 64 + idx] = s;
    }
  } else {
    int idx = t;
    float s = red[idx];
#pragma unroll
    for (int p = 1; p < 4; ++p) s += red[p * 512 + idx];
    ((float*)OutP)[(size_t)d0 * 32 + idx] = s + bias_lds[idx & 31];
  }
}

// ---------------- launch ----------------

extern "C" void kernel_launch(void* const* d_in, const int* in_sizes, int n_in,
                              void* d_out, int out_size, void* d_ws, size_t ws_size,
                              hipStream_t stream) {
  const float* x = (const float*)d_in[0];
  const int* ei = (const int*)d_in[1];
  const int* et = (const int*)d_in[2];
  const float* w1 = (const float*)d_in[3];
  const float* r1 = (const float*)d_in[4];
  const float* b1 = (const float*)d_in[5];
  const float* w2 = (const float*)d_in[6];
  const float* r2 = (const float*)d_in[7];
  const float* b2 = (const float*)d_in[8];
  float* out = (float*)d_out;

  int* cnt = (int*)d_ws;                    // 1,600,000 ints
  int* hist = cnt + 1600000;                // 12512
  int* cursor = hist + 12512;               // 12512
  int* boff = cursor + 12512;               // 12512 (12501 used)
  int2* e2 = (int2*)(boff + 12512);         // 1,250,000 int2
  ushort* bf1 = (ushort*)(e2 + N_EDGES);    // 73728
  ushort* bf2 = bf1 + 73728;                // 36864
  ushort* xbf = bf2 + 36864;                // 12,800,000 (25.6 MB)
  ushort* hbf = xbf + 12800000;             // 12,800,000 (25.6 MB)

  int nz = 1600000 + 12512;  // cnt + hist
  k_zero<<<(nz + 255) / 256, 256, 0, stream>>>(cnt, nz);
  k_count<<<(N_EDGES + 255) / 256, 256, 0, stream>>>(ei, et, cnt);
  k_prep<<<(64 * 576 + 255) / 256, 256, 0, stream>>>(w1, r1, bf1, 64);
  k_prep<<<(32 * 576 + 255) / 256, 256, 0, stream>>>(w2, r2, bf2, 32);
  k_xcast<<<(1600000 + 255) / 256, 256, 0, stream>>>(x, xbf, 1600000);
  k_hist<<<NBUCK, 64, 0, stream>>>(cnt, hist);
  k_scan<<<1, 1024, 0, stream>>>(hist, boff, cursor);
  k_scatter<<<(N_EDGES + 255) / 256, 256, 0, stream>>>(ei, et, cursor, e2);

  k_rgcn<64, false, true><<<NBUCK, 512, 0, stream>>>(xbf, bf1, b1, cnt, boff, e2, hbf);
  k_rgcn<32, true, false><<<NBUCK, 512, 0, stream>>>(hbf, bf2, b2, cnt, boff, e2, out);
}

// Round 7
// 549.845 us; speedup vs baseline: 8.1951x; 1.9817x over previous
//
#include <hip/hip_runtime.h>

#define N_NODES 200000
#define N_EDGES 1250000
#define N_RELS 8
#define NROWS 1600000        // N_NODES * N_RELS
#define NROWS_PAD 1601536    // 782 * 2048
#define NSCAN 782
#define NBUCK 12500          // N_NODES / 16

typedef __attribute__((ext_vector_type(8))) short short8v;
typedef __attribute__((ext_vector_type(4))) float f32x4;

__device__ __forceinline__ ushort rne_bf16(float v) {
  unsigned u = __float_as_uint(v);
  return (ushort)((u + 0x7FFFu + ((u >> 16) & 1u)) >> 16);
}

// agg swizzle: word = row*64 + (f ^ ((row>>3 & 15)<<2)); keeps 4-word blocks
// intact (float4-safe), spreads the 16 fragment rows across all 16 blocks.
__device__ __forceinline__ int aswz(int row, int f) {
  return (row << 6) + (f ^ ((row & 120) >> 1));
}

// ---------------- setup kernels ----------------

__global__ void k_zero(int* __restrict__ p, int n) {
  int i = blockIdx.x * 256 + threadIdx.x;
  if (i < n) p[i] = 0;
}

__global__ void k_count(const int* __restrict__ ei, const int* __restrict__ et,
                        int* __restrict__ cnt) {
  int e = blockIdx.x * 256 + threadIdx.x;
  if (e < N_EDGES) {
    int dst = ei[N_EDGES + e];
    int r = et[e];
    atomicAdd(&cnt[dst * N_RELS + r], 1);
  }
}

// per-2048-row chunk sums
__global__ __launch_bounds__(256) void k_bsum(const int* __restrict__ cnt,
                                              int* __restrict__ bsum) {
  __shared__ int sh[256];
  int b = blockIdx.x, t = threadIdx.x;
  const int4* p = (const int4*)(cnt + b * 2048);
  int4 v0 = p[2 * t], v1 = p[2 * t + 1];
  int s = v0.x + v0.y + v0.z + v0.w + v1.x + v1.y + v1.z + v1.w;
  sh[t] = s;
  __syncthreads();
  for (int o = 128; o >= 1; o >>= 1) {
    if (t < o) sh[t] += sh[t + o];
    __syncthreads();
  }
  if (t == 0) bsum[b] = sh[0];
}

__global__ __launch_bounds__(1024) void k_scan1(const int* __restrict__ bsum,
                                                int* __restrict__ bpre,
                                                int* __restrict__ rowoff) {
  __shared__ int sh[1024];
  int t = threadIdx.x;
  int v = (t < NSCAN) ? bsum[t] : 0;
  sh[t] = v;
  __syncthreads();
  for (int o = 1; o < 1024; o <<= 1) {
    int a = (t >= o) ? sh[t - o] : 0;
    __syncthreads();
    sh[t] += a;
    __syncthreads();
  }
  if (t < NSCAN) bpre[t] = sh[t] - v;
  if (t == 0) rowoff[NROWS] = N_EDGES;
}

__global__ __launch_bounds__(256) void k_apply(const int* __restrict__ cnt,
                                               const int* __restrict__ bpre,
                                               int* __restrict__ rowoff,
                                               int* __restrict__ cursor) {
  __shared__ int sh[256];
  int b = blockIdx.x, t = threadIdx.x;
  const int4* p = (const int4*)(cnt + b * 2048);
  int4 v0 = p[2 * t], v1 = p[2 * t + 1];
  int v[8] = {v0.x, v0.y, v0.z, v0.w, v1.x, v1.y, v1.z, v1.w};
  int s = 0;
#pragma unroll
  for (int j = 0; j < 8; ++j) s += v[j];
  sh[t] = s;
  __syncthreads();
  for (int o = 1; o < 256; o <<= 1) {
    int a = (t >= o) ? sh[t - o] : 0;
    __syncthreads();
    sh[t] += a;
    __syncthreads();
  }
  int run = bpre[b] + sh[t] - s;
  int base = b * 2048 + t * 8;
#pragma unroll
  for (int j = 0; j < 8; ++j) {
    int i = base + j;
    if (i < NROWS) { rowoff[i] = run; cursor[i] = run; }
    run += v[j];
  }
}

// sort edges by row = dst*8+rel; payload: src (18b) | rowlocal (7b) << 18
__global__ void k_scatter(const int* __restrict__ ei, const int* __restrict__ et,
                          int* __restrict__ cursor, int* __restrict__ ep) {
  int e = blockIdx.x * 256 + threadIdx.x;
  if (e < N_EDGES) {
    int src = ei[e];
    int dst = ei[N_EDGES + e];
    int r = et[e];
    int row = dst * N_RELS + r;
    int pos = atomicAdd(&cursor[row], 1);
    ep[pos] = src | ((row & 127) << 18);
  }
}

// x (f32) -> bf16 RNE
__global__ void k_xcast(const float* __restrict__ X, ushort* __restrict__ Xb, int n8) {
  int i = blockIdx.x * 256 + threadIdx.x;
  if (i >= n8) return;
  float4 a = ((const float4*)X)[i * 2];
  float4 b = ((const float4*)X)[i * 2 + 1];
  union { uint4 q; ushort u[8]; } o;
  o.u[0] = rne_bf16(a.x); o.u[1] = rne_bf16(a.y);
  o.u[2] = rne_bf16(a.z); o.u[3] = rne_bf16(a.w);
  o.u[4] = rne_bf16(b.x); o.u[5] = rne_bf16(b.y);
  o.u[6] = rne_bf16(b.z); o.u[7] = rne_bf16(b.w);
  ((uint4*)Xb)[i] = o.q;
}

// Bf fragment-order hi/lo slabs: slab (ks,wn): 512 hi + 512 lo ushorts.
__global__ void k_prep(const float* __restrict__ W, const float* __restrict__ Root,
                       ushort* __restrict__ Bf, int ncol) {
  int i = blockIdx.x * 256 + threadIdx.x;
  if (i >= ncol * 576) return;
  int col = i / 576, k = i - col * 576;
  float w = (k < 512) ? W[k * ncol + col] : Root[(k - 512) * ncol + col];
  unsigned ub = __float_as_uint(w);
  unsigned hb = ub & 0xFFFF0000u;
  float lo = w - __uint_as_float(hb);
  int WN = ncol >> 4;
  int ks = k >> 5, kg = (k >> 3) & 3, j = k & 7;
  int wn = col >> 4, l15 = col & 15;
  int lane = (kg << 4) | l15;
  int dest = (ks * WN + wn) * 1024 + lane * 8 + j;
  Bf[dest] = (ushort)(ub >> 16);
  Bf[dest + 512] = (ushort)(__float_as_uint(lo) >> 16);
}

// ---------------- fused aggregate + MFMA transform ----------------
// Block: 16 dsts = 128 rows, 512 threads (8 waves), ~33.5 KB LDS -> 4 blk/CU.
// Phase 1 (no atomics): edges pre-sorted by row; wave w owns rows
// [w*16, w*16+16) => one contiguous edge slice; register-accumulate runs
// (lane = feature), flush each row once: agg[aswz(row,lane)] = sum/cnt.
// 1-deep software pipeline keeps >=2 gathers in flight per wave.
// Phase 2: per-wave M=16 x N=16 MFMA, K=576, split-bf16 hi/lo (rel K),
// bf16-direct (root K). K split across waves, LDS reduce epilogue.

template <int NCOL, bool RELU, bool OUTBF>
__global__ __launch_bounds__(512, 8) void k_rgcn(
    const ushort* __restrict__ Xg, const ushort* __restrict__ Bf,
    const float* __restrict__ Bias, const int* __restrict__ rowoff,
    const int* __restrict__ ep, void* __restrict__ OutP) {
  constexpr int WN = NCOL / 16;
  constexpr int KSPLIT = (NCOL == 64) ? 2 : 4;

  __shared__ float agg[128 * 64];              // 32 KB
  __shared__ int loff[132];
  __shared__ __align__(16) float bias_lds[64];

  int t = threadIdx.x;
  int b = blockIdx.x;
  int d0 = b * 16;
  int lane = t & 63, w = t >> 6;

  f32x4* agg4 = (f32x4*)agg;
#pragma unroll
  for (int q = 0; q < 4; ++q) agg4[t + q * 512] = (f32x4){0.f, 0.f, 0.f, 0.f};
  if (t < 129) loff[t] = rowoff[b * 128 + t];
  if (t < NCOL) bias_lds[t] = Bias[t];
  __syncthreads();

  // ---- phase 1: sorted-run register aggregation ----
  {
    int s = loff[w * 16], e = loff[w * 16 + 16];
    int cur = -1, nrun = 0;
    float a = 0.f;
    int i = s;
    int pk1 = 0; ushort hv1 = 0;
    if (i < e) {
      pk1 = __builtin_amdgcn_readfirstlane(ep[i]);
      hv1 = Xg[(size_t)(pk1 & 0x3FFFF) * 64 + lane];
    }
    while (i < e) {
      int pk0 = pk1; ushort hv0 = hv1;
      ++i;
      if (i < e) {  // prefetch next edge (independent gather in flight)
        pk1 = __builtin_amdgcn_readfirstlane(ep[i]);
        hv1 = Xg[(size_t)(pk1 & 0x3FFFF) * 64 + lane];
      }
      float v = __uint_as_float((unsigned)hv0 << 16);
      if (RELU) v = fmaxf(v, 0.f);
      int row = pk0 >> 18;
      if (row != cur) {  // wave-uniform (scalar) branch
        if (cur >= 0) agg[aswz(cur, lane)] = a * (1.0f / (float)nrun);
        cur = row; a = 0.f; nrun = 0;
      }
      a += v; ++nrun;
    }
    if (cur >= 0) agg[aswz(cur, lane)] = a * (1.0f / (float)nrun);
  }
  __syncthreads();

  // ---- phase 2: split-bf16 MFMA GEMM, M=16 per wave, K split over waves ----
  int wn, ksp;
  if (NCOL == 64) { wn = w & 3; ksp = w >> 2; }
  else { wn = w & 1; ksp = w >> 1; }
  int l15 = lane & 15, kg = lane >> 4;
  int col = wn * 16 + l15;

  f32x4 hh = {0.f, 0.f, 0.f, 0.f}, lh = hh, hl = hh;

  for (int ks = ksp; ks < 18; ks += KSPLIT) {
    const ushort* bp = Bf + (ks * WN + wn) * 1024 + lane * 8;
    union { uint4 q; short8v s; } bh, bl;
    bh.q = *(const uint4*)bp;
    bl.q = *(const uint4*)(bp + 512);
    if (ks < 16) {
      int rr = ks >> 1;
      int f = ((ks & 1) << 5) + (kg << 3);
      int row = (l15 << 3) + rr;
      float4 a0 = *(const float4*)&agg[aswz(row, f)];
      float4 a1 = *(const float4*)&agg[aswz(row, f + 4)];
      float v[8] = {a0.x, a0.y, a0.z, a0.w, a1.x, a1.y, a1.z, a1.w};
      union { unsigned u[4]; short8v s; } H, L;
#pragma unroll
      for (int j = 0; j < 4; ++j) {
        unsigned u0 = __float_as_uint(v[2 * j]);
        unsigned u1 = __float_as_uint(v[2 * j + 1]);
        unsigned h0 = u0 & 0xFFFF0000u, h1 = u1 & 0xFFFF0000u;
        H.u[j] = h1 | (h0 >> 16);
        float l0 = v[2 * j] - __uint_as_float(h0);
        float l1 = v[2 * j + 1] - __uint_as_float(h1);
        L.u[j] = (__float_as_uint(l1) & 0xFFFF0000u) | (__float_as_uint(l0) >> 16);
      }
      hh = __builtin_amdgcn_mfma_f32_16x16x32_bf16(H.s, bh.s, hh, 0, 0, 0);
      lh = __builtin_amdgcn_mfma_f32_16x16x32_bf16(L.s, bh.s, lh, 0, 0, 0);
      hl = __builtin_amdgcn_mfma_f32_16x16x32_bf16(H.s, bl.s, hl, 0, 0, 0);
    } else {
      int kb = ((ks - 16) << 5) + (kg << 3);
      union { uint4 q; ushort us[8]; short8v s; } av;
      av.q = *(const uint4*)&Xg[(size_t)(d0 + l15) * 64 + kb];
      if (RELU) {
#pragma unroll
        for (int j = 0; j < 8; ++j)
          if (av.us[j] & 0x8000) av.us[j] = 0;
      }
      hh = __builtin_amdgcn_mfma_f32_16x16x32_bf16(av.s, bh.s, hh, 0, 0, 0);
      hl = __builtin_amdgcn_mfma_f32_16x16x32_bf16(av.s, bl.s, hl, 0, 0, 0);
    }
  }

  // ---- reduce K-split partials via LDS (reuse agg) ----
  __syncthreads();
  float* red = agg;
#pragma unroll
  for (int i = 0; i < 4; ++i)
    red[(ksp * 16 + kg * 4 + i) * NCOL + col] = hh[i] + lh[i] + hl[i];
  __syncthreads();

  if (NCOL == 64) {
    int idx = t * 2;
    float2 s = *(const float2*)&red[idx];
    float2 u = *(const float2*)&red[1024 + idx];
    s.x += u.x; s.y += u.y;
    int c = idx & 63;
    s.x += bias_lds[c];
    s.y += bias_lds[c + 1];
    if (OUTBF) {
      unsigned pk = ((unsigned)rne_bf16(s.y) << 16) | (unsigned)rne_bf16(s.x);
      ((unsigned*)OutP)[(size_t)d0 * 32 + t] = pk;
    } else {
      *(float2*)&((float*)OutP)[(size_t)d0 * 64 + idx] = s;
    }
  } else {
    int idx = t;
    float s = red[idx];
#pragma unroll
    for (int p = 1; p < 4; ++p) s += red[p * 512 + idx];
    ((float*)OutP)[(size_t)d0 * 32 + idx] = s + bias_lds[idx & 31];
  }
}

// ---------------- launch ----------------

extern "C" void kernel_launch(void* const* d_in, const int* in_sizes, int n_in,
                              void* d_out, int out_size, void* d_ws, size_t ws_size,
                              hipStream_t stream) {
  const float* x = (const float*)d_in[0];
  const int* ei = (const int*)d_in[1];
  const int* et = (const int*)d_in[2];
  const float* w1 = (const float*)d_in[3];
  const float* r1 = (const float*)d_in[4];
  const float* b1 = (const float*)d_in[5];
  const float* w2 = (const float*)d_in[6];
  const float* r2 = (const float*)d_in[7];
  const float* b2 = (const float*)d_in[8];
  float* out = (float*)d_out;

  int* cnt = (int*)d_ws;                     // NROWS_PAD ints
  int* bsum = cnt + NROWS_PAD;               // 1024
  int* bpre = bsum + 1024;                   // 1024
  int* rowoff = bpre + 1024;                 // NROWS+1 (pad 16)
  int* cursor = rowoff + NROWS + 16;         // NROWS
  int* ep = cursor + NROWS;                  // N_EDGES
  ushort* bf1 = (ushort*)(ep + N_EDGES);     // 73728
  ushort* bf2 = bf1 + 73728;                 // 36864
  ushort* xbf = bf2 + 36864;                 // 12,800,000 (25.6 MB)
  ushort* hbf = xbf + 12800000;              // 12,800,000 (25.6 MB)

  k_zero<<<(NROWS_PAD + 255) / 256, 256, 0, stream>>>(cnt, NROWS_PAD);
  k_count<<<(N_EDGES + 255) / 256, 256, 0, stream>>>(ei, et, cnt);
  k_prep<<<(64 * 576 + 255) / 256, 256, 0, stream>>>(w1, r1, bf1, 64);
  k_prep<<<(32 * 576 + 255) / 256, 256, 0, stream>>>(w2, r2, bf2, 32);
  k_xcast<<<(1600000 + 255) / 256, 256, 0, stream>>>(x, xbf, 1600000);
  k_bsum<<<NSCAN, 256, 0, stream>>>(cnt, bsum);
  k_scan1<<<1, 1024, 0, stream>>>(bsum, bpre, rowoff);
  k_apply<<<NSCAN, 256, 0, stream>>>(cnt, bpre, rowoff, cursor);
  k_scatter<<<(N_EDGES + 255) / 256, 256, 0, stream>>>(ei, et, cursor, ep);

  k_rgcn<64, false, true><<<NBUCK, 512, 0, stream>>>(xbf, bf1, b1, rowoff, ep, hbf);
  k_rgcn<32, true, false><<<NBUCK, 512, 0, stream>>>(hbf, bf2, b2, rowoff, ep, out);
}

// Round 8
// 417.000 us; speedup vs baseline: 10.8058x; 1.3186x over previous
//
#include <hip/hip_runtime.h>

#define N_NODES 200000
#define N_EDGES 1250000
#define N_RELS 8
#define NROWS 1600000        // N_NODES * N_RELS
#define NROWS_PAD 1601536    // 782 * 2048
#define NSCAN 782
#define NBUCK 12500          // N_NODES / 16

typedef __attribute__((ext_vector_type(8))) short short8v;
typedef __attribute__((ext_vector_type(4))) float f32x4;

__device__ __forceinline__ ushort rne_bf16(float v) {
  unsigned u = __float_as_uint(v);
  return (ushort)((u + 0x7FFFu + ((u >> 16) & 1u)) >> 16);
}

// agg swizzle: word = row*64 + (f ^ ((row>>3 & 15)<<2)); float4-safe blocks.
__device__ __forceinline__ int aswz(int row, int f) {
  return (row << 6) + (f ^ ((row & 120) >> 1));
}

// ---------------- setup kernels ----------------

__global__ void k_count(const int* __restrict__ ei, const int* __restrict__ et,
                        int* __restrict__ cnt) {
  int e = blockIdx.x * 256 + threadIdx.x;
  if (e < N_EDGES) {
    int dst = ei[N_EDGES + e];
    int r = et[e];
    atomicAdd(&cnt[dst * N_RELS + r], 1);
  }
}

__global__ __launch_bounds__(256) void k_bsum(const int* __restrict__ cnt,
                                              int* __restrict__ bsum) {
  __shared__ int sh[256];
  int b = blockIdx.x, t = threadIdx.x;
  const int4* p = (const int4*)(cnt + b * 2048);
  int4 v0 = p[2 * t], v1 = p[2 * t + 1];
  int s = v0.x + v0.y + v0.z + v0.w + v1.x + v1.y + v1.z + v1.w;
  sh[t] = s;
  __syncthreads();
  for (int o = 128; o >= 1; o >>= 1) {
    if (t < o) sh[t] += sh[t + o];
    __syncthreads();
  }
  if (t == 0) bsum[b] = sh[0];
}

__global__ __launch_bounds__(1024) void k_scan1(const int* __restrict__ bsum,
                                                int* __restrict__ bpre,
                                                int* __restrict__ rowoff) {
  __shared__ int sh[1024];
  int t = threadIdx.x;
  int v = (t < NSCAN) ? bsum[t] : 0;
  sh[t] = v;
  __syncthreads();
  for (int o = 1; o < 1024; o <<= 1) {
    int a = (t >= o) ? sh[t - o] : 0;
    __syncthreads();
    sh[t] += a;
    __syncthreads();
  }
  if (t < NSCAN) bpre[t] = sh[t] - v;
  if (t == 0) rowoff[NROWS] = N_EDGES;
}

__global__ __launch_bounds__(256) void k_apply(const int* __restrict__ cnt,
                                               const int* __restrict__ bpre,
                                               int* __restrict__ rowoff,
                                               int* __restrict__ cursor) {
  __shared__ int sh[256];
  int b = blockIdx.x, t = threadIdx.x;
  const int4* p = (const int4*)(cnt + b * 2048);
  int4 v0 = p[2 * t], v1 = p[2 * t + 1];
  int v[8] = {v0.x, v0.y, v0.z, v0.w, v1.x, v1.y, v1.z, v1.w};
  int s = 0;
#pragma unroll
  for (int j = 0; j < 8; ++j) s += v[j];
  sh[t] = s;
  __syncthreads();
  for (int o = 1; o < 256; o <<= 1) {
    int a = (t >= o) ? sh[t - o] : 0;
    __syncthreads();
    sh[t] += a;
    __syncthreads();
  }
  int run = bpre[b] + sh[t] - s;
  int base = b * 2048 + t * 8;
#pragma unroll
  for (int j = 0; j < 8; ++j) {
    int i = base + j;
    if (i < NROWS) { rowoff[i] = run; cursor[i] = run; }
    run += v[j];
  }
}

// sort edges by row = dst*8+rel; payload: src (18b) | rowlocal (7b) << 18
__global__ void k_scatter(const int* __restrict__ ei, const int* __restrict__ et,
                          int* __restrict__ cursor, int* __restrict__ ep) {
  int e = blockIdx.x * 256 + threadIdx.x;
  if (e < N_EDGES) {
    int src = ei[e];
    int dst = ei[N_EDGES + e];
    int r = et[e];
    int row = dst * N_RELS + r;
    int pos = atomicAdd(&cursor[row], 1);
    ep[pos] = src | ((row & 127) << 18);
  }
}

// x (f32) -> bf16 RNE
__global__ void k_xcast(const float* __restrict__ X, ushort* __restrict__ Xb, int n8) {
  int i = blockIdx.x * 256 + threadIdx.x;
  if (i >= n8) return;
  float4 a = ((const float4*)X)[i * 2];
  float4 b = ((const float4*)X)[i * 2 + 1];
  union { uint4 q; ushort u[8]; } o;
  o.u[0] = rne_bf16(a.x); o.u[1] = rne_bf16(a.y);
  o.u[2] = rne_bf16(a.z); o.u[3] = rne_bf16(a.w);
  o.u[4] = rne_bf16(b.x); o.u[5] = rne_bf16(b.y);
  o.u[6] = rne_bf16(b.z); o.u[7] = rne_bf16(b.w);
  ((uint4*)Xb)[i] = o.q;
}

// Bf fragment-order hi/lo slabs: slab (ks,wn): 512 hi + 512 lo ushorts.
__global__ void k_prep(const float* __restrict__ W, const float* __restrict__ Root,
                       ushort* __restrict__ Bf, int ncol) {
  int i = blockIdx.x * 256 + threadIdx.x;
  if (i >= ncol * 576) return;
  int col = i / 576, k = i - col * 576;
  float w = (k < 512) ? W[k * ncol + col] : Root[(k - 512) * ncol + col];
  unsigned ub = __float_as_uint(w);
  unsigned hb = ub & 0xFFFF0000u;
  float lo = w - __uint_as_float(hb);
  int WN = ncol >> 4;
  int ks = k >> 5, kg = (k >> 3) & 3, j = k & 7;
  int wn = col >> 4, l15 = col & 15;
  int lane = (kg << 4) | l15;
  int dest = (ks * WN + wn) * 1024 + lane * 8 + j;
  Bf[dest] = (ushort)(ub >> 16);
  Bf[dest + 512] = (ushort)(__float_as_uint(lo) >> 16);
}

// ---------------- fused aggregate + MFMA transform ----------------
// Block: 16 dsts = 128 rows, 512 threads (8 waves), ~33.5 KB LDS -> 4 blk/CU.
// Phase 1 (no atomics, MLP=8): edges sorted by row; wave w owns rows
// [w*16, w*16+16) = contiguous edge slice. Payloads preloaded coalesced
// (lane i <- ep[s+i]); batches of 8 gathers issued back-to-back (clamped
// tail keeps full depth); register run-accumulate; one plain LDS store
// per non-empty row with 1/cnt folded in.
// Phase 2: per-wave M=16 x N=16 MFMA, K=576, split-bf16 hi/lo (rel K),
// bf16-direct (root K). K split across waves, LDS reduce epilogue.

template <int NCOL, bool RELU, bool OUTBF>
__global__ __launch_bounds__(512, 8) void k_rgcn(
    const ushort* __restrict__ Xg, const ushort* __restrict__ Bf,
    const float* __restrict__ Bias, const int* __restrict__ rowoff,
    const int* __restrict__ ep, void* __restrict__ OutP) {
  constexpr int WN = NCOL / 16;
  constexpr int KSPLIT = (NCOL == 64) ? 2 : 4;

  __shared__ float agg[128 * 64];              // 32 KB
  __shared__ int loff[132];
  __shared__ __align__(16) float bias_lds[64];

  int t = threadIdx.x;
  int b = blockIdx.x;
  int d0 = b * 16;
  int lane = t & 63, w = t >> 6;

  f32x4* agg4 = (f32x4*)agg;
#pragma unroll
  for (int q = 0; q < 4; ++q) agg4[t + q * 512] = (f32x4){0.f, 0.f, 0.f, 0.f};
  if (t < 129) loff[t] = rowoff[b * 128 + t];
  if (t < NCOL) bias_lds[t] = Bias[t];
  __syncthreads();

  // ---- phase 1: batched-gather sorted-run aggregation ----
  {
    int s = loff[w * 16], e = loff[w * 16 + 16];
    int cur = -1, nrun = 0;
    float a = 0.f;
    for (int base = s; base < e; base += 64) {
      int nv = e - base; if (nv > 64) nv = 64;
      int pay = (lane < nv) ? ep[base + lane] : 0;   // coalesced payload block
      for (int j = 0; j < nv; j += 8) {
        ushort hv[8]; int rw[8];
#pragma unroll
        for (int u = 0; u < 8; ++u) {
          int idx = j + u;
          if (idx > nv - 1) idx = nv - 1;            // clamped: tail stays batched
          int pk = __shfl(pay, idx);
          rw[u] = pk >> 18;
          hv[u] = Xg[(size_t)(pk & 0x3FFFF) * 64 + lane];
        }
        int nb = nv - j; if (nb > 8) nb = 8;
#pragma unroll
        for (int u = 0; u < 8; ++u) {
          if (u < nb) {
            float v = __uint_as_float((unsigned)hv[u] << 16);
            if (RELU) v = fmaxf(v, 0.f);
            if (rw[u] != cur) {                      // all-lanes-uniform branch
              if (cur >= 0) agg[aswz(cur, lane)] = a * (1.0f / (float)nrun);
              cur = rw[u]; a = 0.f; nrun = 0;
            }
            a += v; ++nrun;
          }
        }
      }
    }
    if (cur >= 0) agg[aswz(cur, lane)] = a * (1.0f / (float)nrun);
  }
  __syncthreads();

  // ---- phase 2: split-bf16 MFMA GEMM, M=16 per wave, K split over waves ----
  int wn, ksp;
  if (NCOL == 64) { wn = w & 3; ksp = w >> 2; }
  else { wn = w & 1; ksp = w >> 1; }
  int l15 = lane & 15, kg = lane >> 4;
  int col = wn * 16 + l15;

  f32x4 hh = {0.f, 0.f, 0.f, 0.f}, lh = hh, hl = hh;

  for (int ks = ksp; ks < 18; ks += KSPLIT) {
    const ushort* bp = Bf + (ks * WN + wn) * 1024 + lane * 8;
    union { uint4 q; short8v s; } bh, bl;
    bh.q = *(const uint4*)bp;
    bl.q = *(const uint4*)(bp + 512);
    if (ks < 16) {
      int rr = ks >> 1;
      int f = ((ks & 1) << 5) + (kg << 3);
      int row = (l15 << 3) + rr;
      float4 a0 = *(const float4*)&agg[aswz(row, f)];
      float4 a1 = *(const float4*)&agg[aswz(row, f + 4)];
      float v[8] = {a0.x, a0.y, a0.z, a0.w, a1.x, a1.y, a1.z, a1.w};
      union { unsigned u[4]; short8v s; } H, L;
#pragma unroll
      for (int j = 0; j < 4; ++j) {
        unsigned u0 = __float_as_uint(v[2 * j]);
        unsigned u1 = __float_as_uint(v[2 * j + 1]);
        unsigned h0 = u0 & 0xFFFF0000u, h1 = u1 & 0xFFFF0000u;
        H.u[j] = h1 | (h0 >> 16);
        float l0 = v[2 * j] - __uint_as_float(h0);
        float l1 = v[2 * j + 1] - __uint_as_float(h1);
        L.u[j] = (__float_as_uint(l1) & 0xFFFF0000u) | (__float_as_uint(l0) >> 16);
      }
      hh = __builtin_amdgcn_mfma_f32_16x16x32_bf16(H.s, bh.s, hh, 0, 0, 0);
      lh = __builtin_amdgcn_mfma_f32_16x16x32_bf16(L.s, bh.s, lh, 0, 0, 0);
      hl = __builtin_amdgcn_mfma_f32_16x16x32_bf16(H.s, bl.s, hl, 0, 0, 0);
    } else {
      int kb = ((ks - 16) << 5) + (kg << 3);
      union { uint4 q; ushort us[8]; short8v s; } av;
      av.q = *(const uint4*)&Xg[(size_t)(d0 + l15) * 64 + kb];
      if (RELU) {
#pragma unroll
        for (int j = 0; j < 8; ++j)
          if (av.us[j] & 0x8000) av.us[j] = 0;
      }
      hh = __builtin_amdgcn_mfma_f32_16x16x32_bf16(av.s, bh.s, hh, 0, 0, 0);
      hl = __builtin_amdgcn_mfma_f32_16x16x32_bf16(av.s, bl.s, hl, 0, 0, 0);
    }
  }

  // ---- reduce K-split partials via LDS (reuse agg) ----
  __syncthreads();
  float* red = agg;
#pragma unroll
  for (int i = 0; i < 4; ++i)
    red[(ksp * 16 + kg * 4 + i) * NCOL + col] = hh[i] + lh[i] + hl[i];
  __syncthreads();

  if (NCOL == 64) {
    int idx = t * 2;
    float2 s = *(const float2*)&red[idx];
    float2 u = *(const float2*)&red[1024 + idx];
    s.x += u.x; s.y += u.y;
    int c = idx & 63;
    s.x += bias_lds[c];
    s.y += bias_lds[c + 1];
    if (OUTBF) {
      unsigned pk = ((unsigned)rne_bf16(s.y) << 16) | (unsigned)rne_bf16(s.x);
      ((unsigned*)OutP)[(size_t)d0 * 32 + t] = pk;
    } else {
      *(float2*)&((float*)OutP)[(size_t)d0 * 64 + idx] = s;
    }
  } else {
    int idx = t;
    float s = red[idx];
#pragma unroll
    for (int p = 1; p < 4; ++p) s += red[p * 512 + idx];
    ((float*)OutP)[(size_t)d0 * 32 + idx] = s + bias_lds[idx & 31];
  }
}

// ---------------- launch ----------------

extern "C" void kernel_launch(void* const* d_in, const int* in_sizes, int n_in,
                              void* d_out, int out_size, void* d_ws, size_t ws_size,
                              hipStream_t stream) {
  const float* x = (const float*)d_in[0];
  const int* ei = (const int*)d_in[1];
  const int* et = (const int*)d_in[2];
  const float* w1 = (const float*)d_in[3];
  const float* r1 = (const float*)d_in[4];
  const float* b1 = (const float*)d_in[5];
  const float* w2 = (const float*)d_in[6];
  const float* r2 = (const float*)d_in[7];
  const float* b2 = (const float*)d_in[8];
  float* out = (float*)d_out;

  int* cnt = (int*)d_ws;                     // NROWS_PAD ints
  int* bsum = cnt + NROWS_PAD;               // 1024
  int* bpre = bsum + 1024;                   // 1024
  int* rowoff = bpre + 1024;                 // NROWS+1 (pad 16)
  int* cursor = rowoff + NROWS + 16;         // NROWS
  int* ep = cursor + NROWS;                  // N_EDGES
  ushort* bf1 = (ushort*)(ep + N_EDGES);     // 73728
  ushort* bf2 = bf1 + 73728;                 // 36864
  ushort* xbf = bf2 + 36864;                 // 12,800,000 (25.6 MB)
  ushort* hbf = xbf + 12800000;              // 12,800,000 (25.6 MB)

  hipMemsetAsync(cnt, 0, (size_t)NROWS_PAD * 4, stream);
  k_count<<<(N_EDGES + 255) / 256, 256, 0, stream>>>(ei, et, cnt);
  k_prep<<<(64 * 576 + 255) / 256, 256, 0, stream>>>(w1, r1, bf1, 64);
  k_prep<<<(32 * 576 + 255) / 256, 256, 0, stream>>>(w2, r2, bf2, 32);
  k_xcast<<<(1600000 + 255) / 256, 256, 0, stream>>>(x, xbf, 1600000);
  k_bsum<<<NSCAN, 256, 0, stream>>>(cnt, bsum);
  k_scan1<<<1, 1024, 0, stream>>>(bsum, bpre, rowoff);
  k_apply<<<NSCAN, 256, 0, stream>>>(cnt, bpre, rowoff, cursor);
  k_scatter<<<(N_EDGES + 255) / 256, 256, 0, stream>>>(ei, et, cursor, ep);

  k_rgcn<64, false, true><<<NBUCK, 512, 0, stream>>>(xbf, bf1, b1, rowoff, ep, hbf);
  k_rgcn<32, true, false><<<NBUCK, 512, 0, stream>>>(hbf, bf2, b2, rowoff, ep, out);
}

// Round 9
// 379.273 us; speedup vs baseline: 11.8806x; 1.0995x over previous
//
#include <hip/hip_runtime.h>

#define N_NODES 200000
#define N_EDGES 1250000
#define N_RELS 8
#define NROWS 1600000        // N_NODES * N_RELS
#define NROWS_PAD 1601536    // 782 * 2048
#define NSCAN 782
#define NBUCK 12500          // N_NODES / 16

#define NB_COUNT 4883        // ceil(N_EDGES/256)
#define NB_XCAST 6250        // 1.6M/256
#define NB_PREP1 144         // 64*576/256
#define NB_PREP2 72          // 32*576/256

typedef __attribute__((ext_vector_type(8))) short short8v;
typedef __attribute__((ext_vector_type(4))) float f32x4;

__device__ __forceinline__ ushort rne_bf16(float v) {
  unsigned u = __float_as_uint(v);
  return (ushort)((u + 0x7FFFu + ((u >> 16) & 1u)) >> 16);
}

// ---------------- fused setup: count | xcast | prep1 | prep2 ----------------

__device__ __forceinline__ void prep_body(const float* W, const float* Root,
                                          ushort* Bf, int ncol, int i) {
  int col = i / 576, k = i - col * 576;
  float w = (k < 512) ? W[k * ncol + col] : Root[(k - 512) * ncol + col];
  unsigned ub = __float_as_uint(w);
  unsigned hb = ub & 0xFFFF0000u;
  float lo = w - __uint_as_float(hb);
  int WN = ncol >> 4;
  int ks = k >> 5, kg = (k >> 3) & 3, j = k & 7;
  int wn = col >> 4, l15 = col & 15;
  int lane = (kg << 4) | l15;
  int dest = (ks * WN + wn) * 1024 + lane * 8 + j;
  Bf[dest] = (ushort)(ub >> 16);
  Bf[dest + 512] = (ushort)(__float_as_uint(lo) >> 16);
}

__global__ __launch_bounds__(256) void k_setup(
    const int* __restrict__ ei, const int* __restrict__ et, int* __restrict__ cnt,
    const float* __restrict__ x, ushort* __restrict__ xbf,
    const float* __restrict__ w1, const float* __restrict__ r1, ushort* __restrict__ bf1,
    const float* __restrict__ w2, const float* __restrict__ r2, ushort* __restrict__ bf2) {
  int blk = blockIdx.x, t = threadIdx.x;
  if (blk < NB_COUNT) {
    int e = blk * 256 + t;
    if (e < N_EDGES) {
      int dst = ei[N_EDGES + e];
      int r = et[e];
      atomicAdd(&cnt[dst * N_RELS + r], 1);
    }
  } else if (blk < NB_COUNT + NB_XCAST) {
    int i = (blk - NB_COUNT) * 256 + t;   // i < 1.6M
    float4 a = ((const float4*)x)[i * 2];
    float4 b = ((const float4*)x)[i * 2 + 1];
    union { uint4 q; ushort u[8]; } o;
    o.u[0] = rne_bf16(a.x); o.u[1] = rne_bf16(a.y);
    o.u[2] = rne_bf16(a.z); o.u[3] = rne_bf16(a.w);
    o.u[4] = rne_bf16(b.x); o.u[5] = rne_bf16(b.y);
    o.u[6] = rne_bf16(b.z); o.u[7] = rne_bf16(b.w);
    ((uint4*)xbf)[i] = o.q;
  } else if (blk < NB_COUNT + NB_XCAST + NB_PREP1) {
    int i = (blk - NB_COUNT - NB_XCAST) * 256 + t;
    prep_body(w1, r1, bf1, 64, i);
  } else {
    int i = (blk - NB_COUNT - NB_XCAST - NB_PREP1) * 256 + t;
    prep_body(w2, r2, bf2, 32, i);
  }
}

// ---------------- sort infrastructure ----------------

__global__ __launch_bounds__(256) void k_bsum(const int* __restrict__ cnt,
                                              int* __restrict__ bsum) {
  __shared__ int sh[256];
  int b = blockIdx.x, t = threadIdx.x;
  const int4* p = (const int4*)(cnt + b * 2048);
  int4 v0 = p[2 * t], v1 = p[2 * t + 1];
  int s = v0.x + v0.y + v0.z + v0.w + v1.x + v1.y + v1.z + v1.w;
  sh[t] = s;
  __syncthreads();
  for (int o = 128; o >= 1; o >>= 1) {
    if (t < o) sh[t] += sh[t + o];
    __syncthreads();
  }
  if (t == 0) bsum[b] = sh[0];
}

__global__ __launch_bounds__(1024) void k_scan1(const int* __restrict__ bsum,
                                                int* __restrict__ bpre,
                                                int* __restrict__ rowoff) {
  __shared__ int sh[1024];
  int t = threadIdx.x;
  int v = (t < NSCAN) ? bsum[t] : 0;
  sh[t] = v;
  __syncthreads();
  for (int o = 1; o < 1024; o <<= 1) {
    int a = (t >= o) ? sh[t - o] : 0;
    __syncthreads();
    sh[t] += a;
    __syncthreads();
  }
  if (t < NSCAN) bpre[t] = sh[t] - v;
  if (t == 0) rowoff[NROWS] = N_EDGES;
}

__global__ __launch_bounds__(256) void k_apply(const int* __restrict__ cnt,
                                               const int* __restrict__ bpre,
                                               int* __restrict__ rowoff,
                                               int* __restrict__ cursor) {
  __shared__ int sh[256];
  int b = blockIdx.x, t = threadIdx.x;
  const int4* p = (const int4*)(cnt + b * 2048);
  int4 v0 = p[2 * t], v1 = p[2 * t + 1];
  int v[8] = {v0.x, v0.y, v0.z, v0.w, v1.x, v1.y, v1.z, v1.w};
  int s = 0;
#pragma unroll
  for (int j = 0; j < 8; ++j) s += v[j];
  sh[t] = s;
  __syncthreads();
  for (int o = 1; o < 256; o <<= 1) {
    int a = (t >= o) ? sh[t - o] : 0;
    __syncthreads();
    sh[t] += a;
    __syncthreads();
  }
  int run = bpre[b] + sh[t] - s;
  int base = b * 2048 + t * 8;
#pragma unroll
  for (int j = 0; j < 8; ++j) {
    int i = base + j;
    if (i < NROWS) { rowoff[i] = run; cursor[i] = run; }
    run += v[j];
  }
}

// sort edges by row = dst*8+rel; payload: (src*128) | rowlocal<<25
__global__ void k_scatter(const int* __restrict__ ei, const int* __restrict__ et,
                          int* __restrict__ cursor, int* __restrict__ ep) {
  int e = blockIdx.x * 256 + threadIdx.x;
  if (e < N_EDGES) {
    int src = ei[e];
    int dst = ei[N_EDGES + e];
    int r = et[e];
    int row = dst * N_RELS + r;
    int pos = atomicAdd(&cursor[row], 1);
    ep[pos] = (src << 7) | ((row & 127) << 25);
  }
}

// ---------------- fused aggregate + MFMA transform ----------------
// Block: 16 dsts = 128 rows, 512 threads (8 waves), ~33.5 KB LDS -> 4 blk/CU.
// Phase 1: sorted contiguous edge slice per wave; payload preloaded; 16-deep
// batched gathers; register run-accumulate (f32); flush once per non-empty
// row: mean -> bf16 hi/lo planes (swizzled), two ds_write_b16.
// Phase 2: MFMA A-fragments read DIRECTLY as b128 bf16 from the planes (no
// in-loop split); K=576; 3 MFMA/iter (rel K), 2 (root K, plain bf16).
// K split across waves, LDS reduce epilogue. Relu pre-applied to h at L1
// write, so no RELU anywhere in L2.

template <int NCOL, bool RELUOUT, bool OUTBF>
__global__ __launch_bounds__(512, 8) void k_rgcn(
    const ushort* __restrict__ Xg, const ushort* __restrict__ Bf,
    const float* __restrict__ Bias, const int* __restrict__ rowoff,
    const int* __restrict__ ep, void* __restrict__ OutP) {
  constexpr int WN = NCOL / 16;
  constexpr int KSPLIT = (NCOL == 64) ? 2 : 4;

  __shared__ __align__(16) ushort aggH[128 * 64];   // 16 KB
  __shared__ __align__(16) ushort aggL[128 * 64];   // 16 KB
  __shared__ int loff[132];
  __shared__ __align__(16) float bias_lds[64];

  int t = threadIdx.x;
  int b = blockIdx.x;
  int d0 = b * 16;
  int lane = t & 63, w = t >> 6;

  {
    uint4 zz = make_uint4(0, 0, 0, 0);
    ((uint4*)aggH)[t] = zz; ((uint4*)aggH)[t + 512] = zz;
    ((uint4*)aggL)[t] = zz; ((uint4*)aggL)[t + 512] = zz;
  }
  if (t < 129) loff[t] = rowoff[b * 128 + t];
  if (t < NCOL) bias_lds[t] = Bias[t];
  __syncthreads();

  // ---- phase 1 ----
  {
    int s = loff[w * 16], e = loff[w * 16 + 16];
    const char* Xb = (const char*)Xg;
    unsigned lane2 = (unsigned)(lane << 1);
    int cur = -1, nrun = 0;
    float a = 0.f;
    for (int base = s; base < e; base += 64) {
      int nv = e - base; if (nv > 64) nv = 64;
      int pl = lane; if (pl > nv - 1) pl = nv - 1;
      int pay = ep[base + pl];
      for (int j = 0; j < nv; j += 16) {
        int pk[16]; ushort hv[16];
#pragma unroll
        for (int u = 0; u < 16; ++u) {
          int idx = j + u; if (idx > nv - 1) idx = nv - 1;
          pk[u] = __shfl(pay, idx);
          hv[u] = *(const ushort*)(Xb + (((unsigned)pk[u] & 0x01FFFFFFu) + lane2));
        }
        int nb = nv - j; if (nb > 16) nb = 16;
#pragma unroll
        for (int u = 0; u < 16; ++u) {
          if (u < nb) {
            int row = (int)((unsigned)pk[u] >> 25);
            float v = __uint_as_float((unsigned)hv[u] << 16);
            if (row != cur) {
              if (cur >= 0) {
                float m = a * (1.0f / (float)nrun);
                unsigned um = __float_as_uint(m);
                float lo = m - __uint_as_float(um & 0xFFFF0000u);
                int sw = (cur << 6) + (lane ^ (((cur >> 3) & 7) << 3));
                aggH[sw] = (ushort)(um >> 16);
                aggL[sw] = (ushort)(__float_as_uint(lo) >> 16);
              }
              cur = row; a = 0.f; nrun = 0;
            }
            a += v; ++nrun;
          }
        }
      }
    }
    if (cur >= 0) {
      float m = a * (1.0f / (float)nrun);
      unsigned um = __float_as_uint(m);
      float lo = m - __uint_as_float(um & 0xFFFF0000u);
      int sw = (cur << 6) + (lane ^ (((cur >> 3) & 7) << 3));
      aggH[sw] = (ushort)(um >> 16);
      aggL[sw] = (ushort)(__float_as_uint(lo) >> 16);
    }
  }
  __syncthreads();

  // ---- phase 2: MFMA, M=16 per wave, K split over waves ----
  int wn, ksp;
  if (NCOL == 64) { wn = w & 3; ksp = w >> 2; }
  else { wn = w & 1; ksp = w >> 1; }
  int l15 = lane & 15, kg = lane >> 4;
  int col = wn * 16 + l15;

  f32x4 hh = {0.f, 0.f, 0.f, 0.f}, lh = hh, hl = hh;

  for (int ks = ksp; ks < 18; ks += KSPLIT) {
    const ushort* bp = Bf + (ks * WN + wn) * 1024 + lane * 8;
    union { uint4 q; short8v s; } bh, bl;
    bh.q = *(const uint4*)bp;
    bl.q = *(const uint4*)(bp + 512);
    if (ks < 16) {
      int rr = ks >> 1;
      int f0 = ((ks & 1) << 5) + (kg << 3);
      int row = (l15 << 3) + rr;
      int sw = (row << 6) + (f0 ^ ((l15 & 7) << 3));
      union { uint4 q; short8v s; } ah, al;
      ah.q = *(const uint4*)&aggH[sw];
      al.q = *(const uint4*)&aggL[sw];
      hh = __builtin_amdgcn_mfma_f32_16x16x32_bf16(ah.s, bh.s, hh, 0, 0, 0);
      lh = __builtin_amdgcn_mfma_f32_16x16x32_bf16(al.s, bh.s, lh, 0, 0, 0);
      hl = __builtin_amdgcn_mfma_f32_16x16x32_bf16(ah.s, bl.s, hl, 0, 0, 0);
    } else {
      int kb = ((ks - 16) << 5) + (kg << 3);
      union { uint4 q; short8v s; } av;
      av.q = *(const uint4*)&Xg[(size_t)(d0 + l15) * 64 + kb];
      hh = __builtin_amdgcn_mfma_f32_16x16x32_bf16(av.s, bh.s, hh, 0, 0, 0);
      hl = __builtin_amdgcn_mfma_f32_16x16x32_bf16(av.s, bl.s, hl, 0, 0, 0);
    }
  }

  // ---- reduce K-split partials via LDS (reuse aggH as f32 buffer) ----
  __syncthreads();
  float* red = (float*)aggH;
#pragma unroll
  for (int i = 0; i < 4; ++i)
    red[(ksp * 16 + kg * 4 + i) * NCOL + col] = hh[i] + lh[i] + hl[i];
  __syncthreads();

  if (NCOL == 64) {
    int idx = t * 2;
    float2 s = *(const float2*)&red[idx];
    float2 u = *(const float2*)&red[1024 + idx];
    int c = idx & 63;
    s.x += u.x + bias_lds[c];
    s.y += u.y + bias_lds[c + 1];
    if (RELUOUT) { s.x = fmaxf(s.x, 0.f); s.y = fmaxf(s.y, 0.f); }
    if (OUTBF) {
      unsigned pk2 = ((unsigned)rne_bf16(s.y) << 16) | (unsigned)rne_bf16(s.x);
      ((unsigned*)OutP)[(size_t)d0 * 32 + t] = pk2;
    } else {
      *(float2*)&((float*)OutP)[(size_t)d0 * 64 + idx] = s;
    }
  } else {
    int idx = t;
    float s = red[idx];
#pragma unroll
    for (int p = 1; p < 4; ++p) s += red[p * 512 + idx];
    ((float*)OutP)[(size_t)d0 * 32 + idx] = s + bias_lds[idx & 31];
  }
}

// ---------------- launch ----------------

extern "C" void kernel_launch(void* const* d_in, const int* in_sizes, int n_in,
                              void* d_out, int out_size, void* d_ws, size_t ws_size,
                              hipStream_t stream) {
  const float* x = (const float*)d_in[0];
  const int* ei = (const int*)d_in[1];
  const int* et = (const int*)d_in[2];
  const float* w1 = (const float*)d_in[3];
  const float* r1 = (const float*)d_in[4];
  const float* b1 = (const float*)d_in[5];
  const float* w2 = (const float*)d_in[6];
  const float* r2 = (const float*)d_in[7];
  const float* b2 = (const float*)d_in[8];
  float* out = (float*)d_out;

  int* cnt = (int*)d_ws;                     // NROWS_PAD ints
  int* bsum = cnt + NROWS_PAD;               // 1024
  int* bpre = bsum + 1024;                   // 1024
  int* rowoff = bpre + 1024;                 // NROWS+1 (pad 16)
  int* cursor = rowoff + NROWS + 16;         // NROWS
  int* ep = cursor + NROWS;                  // N_EDGES
  ushort* bf1 = (ushort*)(ep + N_EDGES);     // 73728
  ushort* bf2 = bf1 + 73728;                 // 36864
  ushort* xbf = bf2 + 36864;                 // 12,800,000 (25.6 MB)
  ushort* hbf = xbf + 12800000;              // 12,800,000 (25.6 MB)

  hipMemsetAsync(cnt, 0, (size_t)NROWS_PAD * 4, stream);
  k_setup<<<NB_COUNT + NB_XCAST + NB_PREP1 + NB_PREP2, 256, 0, stream>>>(
      ei, et, cnt, x, xbf, w1, r1, bf1, w2, r2, bf2);
  k_bsum<<<NSCAN, 256, 0, stream>>>(cnt, bsum);
  k_scan1<<<1, 1024, 0, stream>>>(bsum, bpre, rowoff);
  k_apply<<<NSCAN, 256, 0, stream>>>(cnt, bpre, rowoff, cursor);
  k_scatter<<<(N_EDGES + 255) / 256, 256, 0, stream>>>(ei, et, cursor, ep);

  k_rgcn<64, true, true><<<NBUCK, 512, 0, stream>>>(xbf, bf1, b1, rowoff, ep, hbf);
  k_rgcn<32, false, false><<<NBUCK, 512, 0, stream>>>(hbf, bf2, b2, rowoff, ep, out);
}

// Round 10
// 368.964 us; speedup vs baseline: 12.2126x; 1.0279x over previous
//
#include <hip/hip_runtime.h>

#define N_NODES 200000
#define N_EDGES 1250000
#define N_RELS 8
#define NROWS 1600000        // N_NODES * N_RELS
#define NROWS_PAD 1601536    // 782 * 2048
#define NSCAN 782
#define NBUCK 12500          // N_NODES / 16

#define NB_COUNT 4883        // ceil(N_EDGES/256)
#define NB_XCAST 6250        // 1.6M/256
#define NB_PREP1 144         // 64*576/256
#define NB_PREP2 72          // 32*576/256

typedef __attribute__((ext_vector_type(8))) short short8v;
typedef __attribute__((ext_vector_type(4))) float f32x4;

__device__ __forceinline__ ushort rne_bf16(float v) {
  unsigned u = __float_as_uint(v);
  return (ushort)((u + 0x7FFFu + ((u >> 16) & 1u)) >> 16);
}

// ---------------- fused setup: count | xcast | prep1 | prep2 ----------------

__device__ __forceinline__ void prep_body(const float* W, const float* Root,
                                          ushort* Bf, int ncol, int i) {
  int col = i / 576, k = i - col * 576;
  float w = (k < 512) ? W[k * ncol + col] : Root[(k - 512) * ncol + col];
  unsigned ub = __float_as_uint(w);
  unsigned hb = ub & 0xFFFF0000u;
  float lo = w - __uint_as_float(hb);
  int WN = ncol >> 4;
  int ks = k >> 5, kg = (k >> 3) & 3, j = k & 7;
  int wn = col >> 4, l15 = col & 15;
  int lane = (kg << 4) | l15;
  int dest = (ks * WN + wn) * 1024 + lane * 8 + j;
  Bf[dest] = (ushort)(ub >> 16);
  Bf[dest + 512] = (ushort)(__float_as_uint(lo) >> 16);
}

__global__ __launch_bounds__(256) void k_setup(
    const int* __restrict__ ei, const int* __restrict__ et, int* __restrict__ cnt,
    const float* __restrict__ x, ushort* __restrict__ xbf,
    const float* __restrict__ w1, const float* __restrict__ r1, ushort* __restrict__ bf1,
    const float* __restrict__ w2, const float* __restrict__ r2, ushort* __restrict__ bf2) {
  int blk = blockIdx.x, t = threadIdx.x;
  if (blk < NB_COUNT) {
    int e = blk * 256 + t;
    if (e < N_EDGES) {
      int dst = ei[N_EDGES + e];
      int r = et[e];
      atomicAdd(&cnt[dst * N_RELS + r], 1);
    }
  } else if (blk < NB_COUNT + NB_XCAST) {
    int i = (blk - NB_COUNT) * 256 + t;   // i < 1.6M
    float4 a = ((const float4*)x)[i * 2];
    float4 b = ((const float4*)x)[i * 2 + 1];
    union { uint4 q; ushort u[8]; } o;
    o.u[0] = rne_bf16(a.x); o.u[1] = rne_bf16(a.y);
    o.u[2] = rne_bf16(a.z); o.u[3] = rne_bf16(a.w);
    o.u[4] = rne_bf16(b.x); o.u[5] = rne_bf16(b.y);
    o.u[6] = rne_bf16(b.z); o.u[7] = rne_bf16(b.w);
    ((uint4*)xbf)[i] = o.q;
  } else if (blk < NB_COUNT + NB_XCAST + NB_PREP1) {
    int i = (blk - NB_COUNT - NB_XCAST) * 256 + t;
    prep_body(w1, r1, bf1, 64, i);
  } else {
    int i = (blk - NB_COUNT - NB_XCAST - NB_PREP1) * 256 + t;
    prep_body(w2, r2, bf2, 32, i);
  }
}

// ---------------- sort infrastructure ----------------

__global__ __launch_bounds__(256) void k_bsum(const int* __restrict__ cnt,
                                              int* __restrict__ bsum) {
  __shared__ int sh[256];
  int b = blockIdx.x, t = threadIdx.x;
  const int4* p = (const int4*)(cnt + b * 2048);
  int4 v0 = p[2 * t], v1 = p[2 * t + 1];
  int s = v0.x + v0.y + v0.z + v0.w + v1.x + v1.y + v1.z + v1.w;
  sh[t] = s;
  __syncthreads();
  for (int o = 128; o >= 1; o >>= 1) {
    if (t < o) sh[t] += sh[t + o];
    __syncthreads();
  }
  if (t == 0) bsum[b] = sh[0];
}

__global__ __launch_bounds__(1024) void k_scan1(const int* __restrict__ bsum,
                                                int* __restrict__ bpre,
                                                int* __restrict__ rowoff) {
  __shared__ int sh[1024];
  int t = threadIdx.x;
  int v = (t < NSCAN) ? bsum[t] : 0;
  sh[t] = v;
  __syncthreads();
  for (int o = 1; o < 1024; o <<= 1) {
    int a = (t >= o) ? sh[t - o] : 0;
    __syncthreads();
    sh[t] += a;
    __syncthreads();
  }
  if (t < NSCAN) bpre[t] = sh[t] - v;
  if (t == 0) rowoff[NROWS] = N_EDGES;
}

__global__ __launch_bounds__(256) void k_apply(const int* __restrict__ cnt,
                                               const int* __restrict__ bpre,
                                               int* __restrict__ rowoff,
                                               int* __restrict__ cursor) {
  __shared__ int sh[256];
  int b = blockIdx.x, t = threadIdx.x;
  const int4* p = (const int4*)(cnt + b * 2048);
  int4 v0 = p[2 * t], v1 = p[2 * t + 1];
  int v[8] = {v0.x, v0.y, v0.z, v0.w, v1.x, v1.y, v1.z, v1.w};
  int s = 0;
#pragma unroll
  for (int j = 0; j < 8; ++j) s += v[j];
  sh[t] = s;
  __syncthreads();
  for (int o = 1; o < 256; o <<= 1) {
    int a = (t >= o) ? sh[t - o] : 0;
    __syncthreads();
    sh[t] += a;
    __syncthreads();
  }
  int run = bpre[b] + sh[t] - s;
  int base = b * 2048 + t * 8;
#pragma unroll
  for (int j = 0; j < 8; ++j) {
    int i = base + j;
    if (i < NROWS) { rowoff[i] = run; cursor[i] = run; }
    run += v[j];
  }
}

// sort edges by row = dst*8+rel; payload: (src*128) | rowlocal<<25
__global__ void k_scatter(const int* __restrict__ ei, const int* __restrict__ et,
                          int* __restrict__ cursor, int* __restrict__ ep) {
  int e = blockIdx.x * 256 + threadIdx.x;
  if (e < N_EDGES) {
    int src = ei[e];
    int dst = ei[N_EDGES + e];
    int r = et[e];
    int row = dst * N_RELS + r;
    int pos = atomicAdd(&cursor[row], 1);
    ep[pos] = (src << 7) | ((row & 127) << 25);
  }
}

// ---------------- fused aggregate + MFMA transform ----------------
// Block: 16 dsts = 128 rows, 512 threads (8 waves), ~33.5 KB LDS -> 4 blk/CU.
// Phase 1 (scalarized edge stream): wave-uniform payload slice read via
// s_load into SGPRs (no shfl, no LDS); gather = SGPR base + lane*2 voffset;
// row-change test is a SCALAR branch (flush body only executes when taken).
// 8 gathers in flight per batch. Flush: mean -> bf16 hi/lo planes, two
// ds_write_b16 (swizzled).
// Phase 2: MFMA A-fragments read as b128 bf16 from the planes; K=576;
// 3 MFMA/iter (rel K), 2 (root K). K split across waves; padded-stride LDS
// reduce epilogue (no bank conflicts).

template <int NCOL, bool RELUOUT, bool OUTBF>
__global__ __launch_bounds__(512, 8) void k_rgcn(
    const ushort* __restrict__ Xg, const ushort* __restrict__ Bf,
    const float* __restrict__ Bias, const int* __restrict__ rowoff,
    const int* __restrict__ ep, void* __restrict__ OutP) {
  constexpr int WN = NCOL / 16;
  constexpr int KSPLIT = (NCOL == 64) ? 2 : 4;
  constexpr int RP = NCOL + 4;   // padded reduce stride

  __shared__ __align__(16) ushort aggH[128 * 64];   // 16 KB
  __shared__ __align__(16) ushort aggL[128 * 64];   // 16 KB
  __shared__ int loff[132];
  __shared__ __align__(16) float bias_lds[64];

  int t = threadIdx.x;
  int b = blockIdx.x;
  int d0 = b * 16;
  int lane = t & 63, w = t >> 6;

  {
    uint4 zz = make_uint4(0, 0, 0, 0);
    ((uint4*)aggH)[t] = zz; ((uint4*)aggH)[t + 512] = zz;
    ((uint4*)aggL)[t] = zz; ((uint4*)aggL)[t + 512] = zz;
  }
  if (t < 129) loff[t] = rowoff[b * 128 + t];
  if (t < NCOL) bias_lds[t] = Bias[t];
  __syncthreads();

  // ---- phase 1: scalar edge stream, batched gathers, branchy flush ----
  {
    int s = __builtin_amdgcn_readfirstlane(loff[w * 16]);
    int e = __builtin_amdgcn_readfirstlane(loff[w * 16 + 16]);
    int n = e - s;
    const int* wep = ep + s;
    const char* Xb = (const char*)Xg;
    unsigned lane2 = (unsigned)(lane << 1);
    int cur = -1, nrun = 0;
    float a = 0.f;

#define FLUSH()                                                         \
    {                                                                   \
      float m = a * __builtin_amdgcn_rcpf((float)nrun);                 \
      unsigned um = __float_as_uint(m);                                 \
      float lo = m - __uint_as_float(um & 0xFFFF0000u);                 \
      int sw = (cur << 6) + (lane ^ (((cur >> 3) & 7) << 3));           \
      aggH[sw] = (ushort)(um >> 16);                                    \
      aggL[sw] = (ushort)(__float_as_uint(lo) >> 16);                   \
    }

    int i = 0;
    for (; i + 8 <= n; i += 8) {
      int pk[8];
#pragma unroll
      for (int u = 0; u < 8; ++u)
        pk[u] = __builtin_amdgcn_readfirstlane(wep[i + u]);
      ushort hv[8];
#pragma unroll
      for (int u = 0; u < 8; ++u)
        hv[u] = *(const ushort*)(Xb + (((unsigned)pk[u] & 0x01FFFFFFu) + lane2));
#pragma unroll
      for (int u = 0; u < 8; ++u) {
        int row = (int)((unsigned)pk[u] >> 25);
        float v = __uint_as_float((unsigned)hv[u] << 16);
        if (row != cur) {            // scalar cmp + branch
          if (cur >= 0) FLUSH();
          cur = row; a = 0.f; nrun = 0;
        }
        a += v; ++nrun;
      }
    }
    for (; i < n; ++i) {
      int pk = __builtin_amdgcn_readfirstlane(wep[i]);
      ushort hv = *(const ushort*)(Xb + (((unsigned)pk & 0x01FFFFFFu) + lane2));
      int row = (int)((unsigned)pk >> 25);
      float v = __uint_as_float((unsigned)hv << 16);
      if (row != cur) {
        if (cur >= 0) FLUSH();
        cur = row; a = 0.f; nrun = 0;
      }
      a += v; ++nrun;
    }
    if (cur >= 0) FLUSH();
#undef FLUSH
  }
  __syncthreads();

  // ---- phase 2: MFMA, M=16 per wave, K split over waves ----
  int wn, ksp;
  if (NCOL == 64) { wn = w & 3; ksp = w >> 2; }
  else { wn = w & 1; ksp = w >> 1; }
  int l15 = lane & 15, kg = lane >> 4;
  int col = wn * 16 + l15;

  f32x4 hh = {0.f, 0.f, 0.f, 0.f}, lh = hh, hl = hh;

  for (int ks = ksp; ks < 18; ks += KSPLIT) {
    const ushort* bp = Bf + (ks * WN + wn) * 1024 + lane * 8;
    union { uint4 q; short8v s; } bh, bl;
    bh.q = *(const uint4*)bp;
    bl.q = *(const uint4*)(bp + 512);
    if (ks < 16) {
      int rr = ks >> 1;
      int f0 = ((ks & 1) << 5) + (kg << 3);
      int row = (l15 << 3) + rr;
      int sw = (row << 6) + (f0 ^ ((l15 & 7) << 3));
      union { uint4 q; short8v s; } ah, al;
      ah.q = *(const uint4*)&aggH[sw];
      al.q = *(const uint4*)&aggL[sw];
      hh = __builtin_amdgcn_mfma_f32_16x16x32_bf16(ah.s, bh.s, hh, 0, 0, 0);
      lh = __builtin_amdgcn_mfma_f32_16x16x32_bf16(al.s, bh.s, lh, 0, 0, 0);
      hl = __builtin_amdgcn_mfma_f32_16x16x32_bf16(ah.s, bl.s, hl, 0, 0, 0);
    } else {
      int kb = ((ks - 16) << 5) + (kg << 3);
      union { uint4 q; short8v s; } av;
      av.q = *(const uint4*)&Xg[(size_t)(d0 + l15) * 64 + kb];
      hh = __builtin_amdgcn_mfma_f32_16x16x32_bf16(av.s, bh.s, hh, 0, 0, 0);
      hl = __builtin_amdgcn_mfma_f32_16x16x32_bf16(av.s, bl.s, hl, 0, 0, 0);
    }
  }

  // ---- reduce K-split partials via LDS (padded stride, reuse aggH) ----
  __syncthreads();
  float* red = (float*)aggH;
#pragma unroll
  for (int i = 0; i < 4; ++i)
    red[(ksp * 16 + kg * 4 + i) * RP + col] = hh[i] + lh[i] + hl[i];
  __syncthreads();

  if (NCOL == 64) {
    int r = t >> 5, c = (t & 31) * 2;
    float2 s = *(const float2*)&red[r * RP + c];
    float2 u = *(const float2*)&red[(16 + r) * RP + c];
    s.x += u.x + bias_lds[c];
    s.y += u.y + bias_lds[c + 1];
    if (RELUOUT) { s.x = fmaxf(s.x, 0.f); s.y = fmaxf(s.y, 0.f); }
    if (OUTBF) {
      unsigned pk2 = ((unsigned)rne_bf16(s.y) << 16) | (unsigned)rne_bf16(s.x);
      ((unsigned*)OutP)[((size_t)(d0 + r) * 64 + c) >> 1] = pk2;
    } else {
      *(float2*)&((float*)OutP)[(size_t)(d0 + r) * 64 + c] = s;
    }
  } else {
    int r = t >> 5, c = t & 31;
    float s = red[r * RP + c];
#pragma unroll
    for (int p = 1; p < 4; ++p) s += red[(p * 16 + r) * RP + c];
    ((float*)OutP)[(size_t)(d0 + r) * 32 + c] = s + bias_lds[c];
  }
}

// ---------------- launch ----------------

extern "C" void kernel_launch(void* const* d_in, const int* in_sizes, int n_in,
                              void* d_out, int out_size, void* d_ws, size_t ws_size,
                              hipStream_t stream) {
  const float* x = (const float*)d_in[0];
  const int* ei = (const int*)d_in[1];
  const int* et = (const int*)d_in[2];
  const float* w1 = (const float*)d_in[3];
  const float* r1 = (const float*)d_in[4];
  const float* b1 = (const float*)d_in[5];
  const float* w2 = (const float*)d_in[6];
  const float* r2 = (const float*)d_in[7];
  const float* b2 = (const float*)d_in[8];
  float* out = (float*)d_out;

  int* cnt = (int*)d_ws;                     // NROWS_PAD ints
  int* bsum = cnt + NROWS_PAD;               // 1024
  int* bpre = bsum + 1024;                   // 1024
  int* rowoff = bpre + 1024;                 // NROWS+1 (pad 16)
  int* cursor = rowoff + NROWS + 16;         // NROWS
  int* ep = cursor + NROWS;                  // N_EDGES
  ushort* bf1 = (ushort*)(ep + N_EDGES);     // 73728
  ushort* bf2 = bf1 + 73728;                 // 36864
  ushort* xbf = bf2 + 36864;                 // 12,800,000 (25.6 MB)
  ushort* hbf = xbf + 12800000;              // 12,800,000 (25.6 MB)

  hipMemsetAsync(cnt, 0, (size_t)NROWS_PAD * 4, stream);
  k_setup<<<NB_COUNT + NB_XCAST + NB_PREP1 + NB_PREP2, 256, 0, stream>>>(
      ei, et, cnt, x, xbf, w1, r1, bf1, w2, r2, bf2);
  k_bsum<<<NSCAN, 256, 0, stream>>>(cnt, bsum);
  k_scan1<<<1, 1024, 0, stream>>>(bsum, bpre, rowoff);
  k_apply<<<NSCAN, 256, 0, stream>>>(cnt, bpre, rowoff, cursor);
  k_scatter<<<(N_EDGES + 255) / 256, 256, 0, stream>>>(ei, et, cursor, ep);

  k_rgcn<64, true, true><<<NBUCK, 512, 0, stream>>>(xbf, bf1, b1, rowoff, ep, hbf);
  k_rgcn<32, false, false><<<NBUCK, 512, 0, stream>>>(hbf, bf2, b2, rowoff, ep, out);
}

// Round 11
// 354.448 us; speedup vs baseline: 12.7127x; 1.0410x over previous
//
#include <hip/hip_runtime.h>

#define N_NODES 200000
#define N_EDGES 1250000
#define N_RELS 8
#define NROWS 1600000        // N_NODES * N_RELS
#define NROWS_PAD 1601536    // 782 * 2048
#define NSCAN 782
#define NBUCK 12500          // N_NODES / 16

#define NB_COUNT 4883        // ceil(N_EDGES/256)
#define NB_XCAST 6250        // 1.6M/256
#define NB_PREP1 144         // 64*576/256
#define NB_PREP2 72          // 32*576/256

typedef __attribute__((ext_vector_type(8))) short short8v;
typedef __attribute__((ext_vector_type(4))) float f32x4;

__device__ __forceinline__ ushort rne_bf16(float v) {
  unsigned u = __float_as_uint(v);
  return (ushort)((u + 0x7FFFu + ((u >> 16) & 1u)) >> 16);
}

// ---------------- fused setup: count | xcast | prep1 | prep2 ----------------

// Bf fragment-order single-plane bf16 (RNE): slab (ks,wn) = 512 ushorts;
// element (lane, j) = B[k = ks*32 + (lane>>4)*8 + j][col = wn*16 + (lane&15)]
__device__ __forceinline__ void prep_body(const float* W, const float* Root,
                                          ushort* Bf, int ncol, int i) {
  int col = i / 576, k = i - col * 576;
  float w = (k < 512) ? W[k * ncol + col] : Root[(k - 512) * ncol + col];
  int WN = ncol >> 4;
  int ks = k >> 5, kg = (k >> 3) & 3, j = k & 7;
  int wn = col >> 4, l15 = col & 15;
  int lane = (kg << 4) | l15;
  Bf[(ks * WN + wn) * 512 + lane * 8 + j] = rne_bf16(w);
}

__global__ __launch_bounds__(256) void k_setup(
    const int* __restrict__ ei, const int* __restrict__ et, int* __restrict__ cnt,
    const float* __restrict__ x, ushort* __restrict__ xbf,
    const float* __restrict__ w1, const float* __restrict__ r1, ushort* __restrict__ bf1,
    const float* __restrict__ w2, const float* __restrict__ r2, ushort* __restrict__ bf2) {
  int blk = blockIdx.x, t = threadIdx.x;
  if (blk < NB_COUNT) {
    int e = blk * 256 + t;
    if (e < N_EDGES) {
      int dst = ei[N_EDGES + e];
      int r = et[e];
      atomicAdd(&cnt[dst * N_RELS + r], 1);
    }
  } else if (blk < NB_COUNT + NB_XCAST) {
    int i = (blk - NB_COUNT) * 256 + t;   // i < 1.6M
    float4 a = ((const float4*)x)[i * 2];
    float4 b = ((const float4*)x)[i * 2 + 1];
    union { uint4 q; ushort u[8]; } o;
    o.u[0] = rne_bf16(a.x); o.u[1] = rne_bf16(a.y);
    o.u[2] = rne_bf16(a.z); o.u[3] = rne_bf16(a.w);
    o.u[4] = rne_bf16(b.x); o.u[5] = rne_bf16(b.y);
    o.u[6] = rne_bf16(b.z); o.u[7] = rne_bf16(b.w);
    ((uint4*)xbf)[i] = o.q;
  } else if (blk < NB_COUNT + NB_XCAST + NB_PREP1) {
    int i = (blk - NB_COUNT - NB_XCAST) * 256 + t;
    prep_body(w1, r1, bf1, 64, i);
  } else {
    int i = (blk - NB_COUNT - NB_XCAST - NB_PREP1) * 256 + t;
    prep_body(w2, r2, bf2, 32, i);
  }
}

// ---------------- sort infrastructure ----------------

__global__ __launch_bounds__(256) void k_bsum(const int* __restrict__ cnt,
                                              int* __restrict__ bsum) {
  __shared__ int sh[256];
  int b = blockIdx.x, t = threadIdx.x;
  const int4* p = (const int4*)(cnt + b * 2048);
  int4 v0 = p[2 * t], v1 = p[2 * t + 1];
  int s = v0.x + v0.y + v0.z + v0.w + v1.x + v1.y + v1.z + v1.w;
  sh[t] = s;
  __syncthreads();
  for (int o = 128; o >= 1; o >>= 1) {
    if (t < o) sh[t] += sh[t + o];
    __syncthreads();
  }
  if (t == 0) bsum[b] = sh[0];
}

__global__ __launch_bounds__(1024) void k_scan1(const int* __restrict__ bsum,
                                                int* __restrict__ bpre,
                                                int* __restrict__ rowoff) {
  __shared__ int sh[1024];
  int t = threadIdx.x;
  int v = (t < NSCAN) ? bsum[t] : 0;
  sh[t] = v;
  __syncthreads();
  for (int o = 1; o < 1024; o <<= 1) {
    int a = (t >= o) ? sh[t - o] : 0;
    __syncthreads();
    sh[t] += a;
    __syncthreads();
  }
  if (t < NSCAN) bpre[t] = sh[t] - v;
  if (t == 0) rowoff[NROWS] = N_EDGES;
}

__global__ __launch_bounds__(256) void k_apply(const int* __restrict__ cnt,
                                               const int* __restrict__ bpre,
                                               int* __restrict__ rowoff,
                                               int* __restrict__ cursor) {
  __shared__ int sh[256];
  int b = blockIdx.x, t = threadIdx.x;
  const int4* p = (const int4*)(cnt + b * 2048);
  int4 v0 = p[2 * t], v1 = p[2 * t + 1];
  int v[8] = {v0.x, v0.y, v0.z, v0.w, v1.x, v1.y, v1.z, v1.w};
  int s = 0;
#pragma unroll
  for (int j = 0; j < 8; ++j) s += v[j];
  sh[t] = s;
  __syncthreads();
  for (int o = 1; o < 256; o <<= 1) {
    int a = (t >= o) ? sh[t - o] : 0;
    __syncthreads();
    sh[t] += a;
    __syncthreads();
  }
  int run = bpre[b] + sh[t] - s;
  int base = b * 2048 + t * 8;
#pragma unroll
  for (int j = 0; j < 8; ++j) {
    int i = base + j;
    if (i < NROWS) { rowoff[i] = run; cursor[i] = run; }
    run += v[j];
  }
}

// sort edges by row = dst*8+rel; payload: (src*128) | rowlocal<<25
__global__ void k_scatter(const int* __restrict__ ei, const int* __restrict__ et,
                          int* __restrict__ cursor, int* __restrict__ ep) {
  int e = blockIdx.x * 256 + threadIdx.x;
  if (e < N_EDGES) {
    int src = ei[e];
    int dst = ei[N_EDGES + e];
    int r = et[e];
    int row = dst * N_RELS + r;
    int pos = atomicAdd(&cursor[row], 1);
    ep[pos] = (src << 7) | ((row & 127) << 25);
  }
}

// ---------------- fused aggregate + MFMA transform ----------------
// Block: 16 dsts = 128 rows, 512 threads (8 waves), ~18 KB LDS.
// Phase 1 (scalarized edge stream): wave-uniform payloads via readfirstlane;
// gather = base + lane*2; run-break is a scalar branch; 8 gathers in flight.
// Flush: mean (f32) -> RNE bf16 -> ONE ds_write_b16 into the swizzled plane.
// Phase 2: pure-bf16 MFMA (single plane, 1 MFMA + 1 A-read + 1 B-load per
// k-step), K=576 (512 rel from LDS + 64 root from Xg). K split across waves,
// padded-stride LDS reduce epilogue.

template <int NCOL, bool RELUOUT, bool OUTBF>
__global__ __launch_bounds__(512, 8) void k_rgcn(
    const ushort* __restrict__ Xg, const ushort* __restrict__ Bf,
    const float* __restrict__ Bias, const int* __restrict__ rowoff,
    const int* __restrict__ ep, void* __restrict__ OutP) {
  constexpr int WN = NCOL / 16;
  constexpr int KSPLIT = (NCOL == 64) ? 2 : 4;
  constexpr int RP = NCOL + 4;   // padded reduce stride

  __shared__ __align__(16) ushort agg[128 * 64];    // 16 KB bf16 plane
  __shared__ int loff[132];
  __shared__ __align__(16) float bias_lds[64];

  int t = threadIdx.x;
  int b = blockIdx.x;
  int d0 = b * 16;
  int lane = t & 63, w = t >> 6;

  {
    uint4 zz = make_uint4(0, 0, 0, 0);
    ((uint4*)agg)[t] = zz; ((uint4*)agg)[t + 512] = zz;
  }
  if (t < 129) loff[t] = rowoff[b * 128 + t];
  if (t < NCOL) bias_lds[t] = Bias[t];
  __syncthreads();

  // ---- phase 1: scalar edge stream, batched gathers, branchy flush ----
  {
    int s = __builtin_amdgcn_readfirstlane(loff[w * 16]);
    int e = __builtin_amdgcn_readfirstlane(loff[w * 16 + 16]);
    int n = e - s;
    const int* wep = ep + s;
    const char* Xb = (const char*)Xg;
    unsigned lane2 = (unsigned)(lane << 1);
    int cur = -1, nrun = 0;
    float a = 0.f;

#define FLUSH()                                                         \
    {                                                                   \
      float m = a * __builtin_amdgcn_rcpf((float)nrun);                 \
      int sw = (cur << 6) + (lane ^ (((cur >> 3) & 7) << 3));           \
      agg[sw] = rne_bf16(m);                                            \
    }

    int i = 0;
    for (; i + 8 <= n; i += 8) {
      int pk[8];
#pragma unroll
      for (int u = 0; u < 8; ++u)
        pk[u] = __builtin_amdgcn_readfirstlane(wep[i + u]);
      ushort hv[8];
#pragma unroll
      for (int u = 0; u < 8; ++u)
        hv[u] = *(const ushort*)(Xb + (((unsigned)pk[u] & 0x01FFFFFFu) + lane2));
#pragma unroll
      for (int u = 0; u < 8; ++u) {
        int row = (int)((unsigned)pk[u] >> 25);
        float v = __uint_as_float((unsigned)hv[u] << 16);
        if (row != cur) {            // scalar cmp + branch
          if (cur >= 0) FLUSH();
          cur = row; a = 0.f; nrun = 0;
        }
        a += v; ++nrun;
      }
    }
    for (; i < n; ++i) {
      int pk = __builtin_amdgcn_readfirstlane(wep[i]);
      ushort hv = *(const ushort*)(Xb + (((unsigned)pk & 0x01FFFFFFu) + lane2));
      int row = (int)((unsigned)pk >> 25);
      float v = __uint_as_float((unsigned)hv << 16);
      if (row != cur) {
        if (cur >= 0) FLUSH();
        cur = row; a = 0.f; nrun = 0;
      }
      a += v; ++nrun;
    }
    if (cur >= 0) FLUSH();
#undef FLUSH
  }
  __syncthreads();

  // ---- phase 2: pure-bf16 MFMA, M=16 per wave, K split over waves ----
  int wn, ksp;
  if (NCOL == 64) { wn = w & 3; ksp = w >> 2; }
  else { wn = w & 1; ksp = w >> 1; }
  int l15 = lane & 15, kg = lane >> 4;
  int col = wn * 16 + l15;

  f32x4 acc = {0.f, 0.f, 0.f, 0.f};

  for (int ks = ksp; ks < 18; ks += KSPLIT) {
    const ushort* bp = Bf + (ks * WN + wn) * 512 + lane * 8;
    union { uint4 q; short8v s; } bh;
    bh.q = *(const uint4*)bp;
    union { uint4 q; short8v s; } ah;
    if (ks < 16) {
      int rr = ks >> 1;
      int f0 = ((ks & 1) << 5) + (kg << 3);
      int row = (l15 << 3) + rr;
      int sw = (row << 6) + (f0 ^ ((l15 & 7) << 3));
      ah.q = *(const uint4*)&agg[sw];
    } else {
      int kb = ((ks - 16) << 5) + (kg << 3);
      ah.q = *(const uint4*)&Xg[(size_t)(d0 + l15) * 64 + kb];
    }
    acc = __builtin_amdgcn_mfma_f32_16x16x32_bf16(ah.s, bh.s, acc, 0, 0, 0);
  }

  // ---- reduce K-split partials via LDS (padded stride, reuse agg) ----
  __syncthreads();
  float* red = (float*)agg;
#pragma unroll
  for (int i = 0; i < 4; ++i)
    red[(ksp * 16 + kg * 4 + i) * RP + col] = acc[i];
  __syncthreads();

  if (NCOL == 64) {
    int r = t >> 5, c = (t & 31) * 2;
    float2 s = *(const float2*)&red[r * RP + c];
    float2 u = *(const float2*)&red[(16 + r) * RP + c];
    s.x += u.x + bias_lds[c];
    s.y += u.y + bias_lds[c + 1];
    if (RELUOUT) { s.x = fmaxf(s.x, 0.f); s.y = fmaxf(s.y, 0.f); }
    if (OUTBF) {
      unsigned pk2 = ((unsigned)rne_bf16(s.y) << 16) | (unsigned)rne_bf16(s.x);
      ((unsigned*)OutP)[((size_t)(d0 + r) * 64 + c) >> 1] = pk2;
    } else {
      *(float2*)&((float*)OutP)[(size_t)(d0 + r) * 64 + c] = s;
    }
  } else {
    int r = t >> 5, c = t & 31;
    float s = red[r * RP + c];
#pragma unroll
    for (int p = 1; p < 4; ++p) s += red[(p * 16 + r) * RP + c];
    ((float*)OutP)[(size_t)(d0 + r) * 32 + c] = s + bias_lds[c];
  }
}

// ---------------- launch ----------------

extern "C" void kernel_launch(void* const* d_in, const int* in_sizes, int n_in,
                              void* d_out, int out_size, void* d_ws, size_t ws_size,
                              hipStream_t stream) {
  const float* x = (const float*)d_in[0];
  const int* ei = (const int*)d_in[1];
  const int* et = (const int*)d_in[2];
  const float* w1 = (const float*)d_in[3];
  const float* r1 = (const float*)d_in[4];
  const float* b1 = (const float*)d_in[5];
  const float* w2 = (const float*)d_in[6];
  const float* r2 = (const float*)d_in[7];
  const float* b2 = (const float*)d_in[8];
  float* out = (float*)d_out;

  int* cnt = (int*)d_ws;                     // NROWS_PAD ints
  int* bsum = cnt + NROWS_PAD;               // 1024
  int* bpre = bsum + 1024;                   // 1024
  int* rowoff = bpre + 1024;                 // NROWS+1 (pad 16)
  int* cursor = rowoff + NROWS + 16;         // NROWS
  int* ep = cursor + NROWS;                  // N_EDGES
  ushort* bf1 = (ushort*)(ep + N_EDGES);     // 36864 (single plane)
  ushort* bf2 = bf1 + 36864;                 // 18432
  ushort* xbf = bf2 + 18432;                 // 12,800,000 (25.6 MB)
  ushort* hbf = xbf + 12800000;              // 12,800,000 (25.6 MB)

  hipMemsetAsync(cnt, 0, (size_t)NROWS_PAD * 4, stream);
  k_setup<<<NB_COUNT + NB_XCAST + NB_PREP1 + NB_PREP2, 256, 0, stream>>>(
      ei, et, cnt, x, xbf, w1, r1, bf1, w2, r2, bf2);
  k_bsum<<<NSCAN, 256, 0, stream>>>(cnt, bsum);
  k_scan1<<<1, 1024, 0, stream>>>(bsum, bpre, rowoff);
  k_apply<<<NSCAN, 256, 0, stream>>>(cnt, bpre, rowoff, cursor);
  k_scatter<<<(N_EDGES + 255) / 256, 256, 0, stream>>>(ei, et, cursor, ep);

  k_rgcn<64, true, true><<<NBUCK, 512, 0, stream>>>(xbf, bf1, b1, rowoff, ep, hbf);
  k_rgcn<32, false, false><<<NBUCK, 512, 0, stream>>>(hbf, bf2, b2, rowoff, ep, out);
}

// Round 12
// 323.603 us; speedup vs baseline: 13.9245x; 1.0953x over previous
//
#include <hip/hip_runtime.h>

#define N_NODES 200000
#define N_EDGES 1250000
#define N_RELS 8
#define NROWS 1600000        // N_NODES * N_RELS
#define NROWS_PAD 1601536    // 782 * 2048
#define NSCAN 782
#define NBUCK 6250           // N_NODES / 32

#define NB_COUNT 4883        // ceil(N_EDGES/256)
#define NB_XCAST 6250        // 1.6M/256
#define NB_PREP1 144         // 64*576/256
#define NB_PREP2 72          // 32*576/256

typedef __attribute__((ext_vector_type(8))) short short8v;
typedef __attribute__((ext_vector_type(4))) float f32x4;

__device__ __forceinline__ ushort rne_bf16(float v) {
  unsigned u = __float_as_uint(v);
  return (ushort)((u + 0x7FFFu + ((u >> 16) & 1u)) >> 16);
}

// ---------------- fused setup: count | xcast | prep1 | prep2 ----------------

// Bf fragment-order single-plane bf16 (RNE): slab (ks,wn) = 512 ushorts;
// element (lane, j) = B[k = ks*32 + (lane>>4)*8 + j][col = wn*16 + (lane&15)]
__device__ __forceinline__ void prep_body(const float* W, const float* Root,
                                          ushort* Bf, int ncol, int i) {
  int col = i / 576, k = i - col * 576;
  float w = (k < 512) ? W[k * ncol + col] : Root[(k - 512) * ncol + col];
  int WN = ncol >> 4;
  int ks = k >> 5, kg = (k >> 3) & 3, j = k & 7;
  int wn = col >> 4, l15 = col & 15;
  int lane = (kg << 4) | l15;
  Bf[(ks * WN + wn) * 512 + lane * 8 + j] = rne_bf16(w);
}

__global__ __launch_bounds__(256) void k_setup(
    const int* __restrict__ ei, const int* __restrict__ et, int* __restrict__ cnt,
    const float* __restrict__ x, ushort* __restrict__ xbf,
    const float* __restrict__ w1, const float* __restrict__ r1, ushort* __restrict__ bf1,
    const float* __restrict__ w2, const float* __restrict__ r2, ushort* __restrict__ bf2) {
  int blk = blockIdx.x, t = threadIdx.x;
  if (blk < NB_COUNT) {
    int e = blk * 256 + t;
    if (e < N_EDGES) {
      int dst = ei[N_EDGES + e];
      int r = et[e];
      atomicAdd(&cnt[dst * N_RELS + r], 1);
    }
  } else if (blk < NB_COUNT + NB_XCAST) {
    int i = (blk - NB_COUNT) * 256 + t;   // i < 1.6M
    float4 a = ((const float4*)x)[i * 2];
    float4 b = ((const float4*)x)[i * 2 + 1];
    union { uint4 q; ushort u[8]; } o;
    o.u[0] = rne_bf16(a.x); o.u[1] = rne_bf16(a.y);
    o.u[2] = rne_bf16(a.z); o.u[3] = rne_bf16(a.w);
    o.u[4] = rne_bf16(b.x); o.u[5] = rne_bf16(b.y);
    o.u[6] = rne_bf16(b.z); o.u[7] = rne_bf16(b.w);
    ((uint4*)xbf)[i] = o.q;
  } else if (blk < NB_COUNT + NB_XCAST + NB_PREP1) {
    int i = (blk - NB_COUNT - NB_XCAST) * 256 + t;
    prep_body(w1, r1, bf1, 64, i);
  } else {
    int i = (blk - NB_COUNT - NB_XCAST - NB_PREP1) * 256 + t;
    prep_body(w2, r2, bf2, 32, i);
  }
}

// ---------------- sort infrastructure ----------------

__global__ __launch_bounds__(256) void k_bsum(const int* __restrict__ cnt,
                                              int* __restrict__ bsum) {
  __shared__ int sh[256];
  int b = blockIdx.x, t = threadIdx.x;
  const int4* p = (const int4*)(cnt + b * 2048);
  int4 v0 = p[2 * t], v1 = p[2 * t + 1];
  int s = v0.x + v0.y + v0.z + v0.w + v1.x + v1.y + v1.z + v1.w;
  sh[t] = s;
  __syncthreads();
  for (int o = 128; o >= 1; o >>= 1) {
    if (t < o) sh[t] += sh[t + o];
    __syncthreads();
  }
  if (t == 0) bsum[b] = sh[0];
}

__global__ __launch_bounds__(1024) void k_scan1(const int* __restrict__ bsum,
                                                int* __restrict__ bpre,
                                                int* __restrict__ rowoff) {
  __shared__ int sh[1024];
  int t = threadIdx.x;
  int v = (t < NSCAN) ? bsum[t] : 0;
  sh[t] = v;
  __syncthreads();
  for (int o = 1; o < 1024; o <<= 1) {
    int a = (t >= o) ? sh[t - o] : 0;
    __syncthreads();
    sh[t] += a;
    __syncthreads();
  }
  if (t < NSCAN) bpre[t] = sh[t] - v;
  if (t == 0) rowoff[NROWS] = N_EDGES;
}

__global__ __launch_bounds__(256) void k_apply(const int* __restrict__ cnt,
                                               const int* __restrict__ bpre,
                                               int* __restrict__ rowoff,
                                               int* __restrict__ cursor) {
  __shared__ int sh[256];
  int b = blockIdx.x, t = threadIdx.x;
  const int4* p = (const int4*)(cnt + b * 2048);
  int4 v0 = p[2 * t], v1 = p[2 * t + 1];
  int v[8] = {v0.x, v0.y, v0.z, v0.w, v1.x, v1.y, v1.z, v1.w};
  int s = 0;
#pragma unroll
  for (int j = 0; j < 8; ++j) s += v[j];
  sh[t] = s;
  __syncthreads();
  for (int o = 1; o < 256; o <<= 1) {
    int a = (t >= o) ? sh[t - o] : 0;
    __syncthreads();
    sh[t] += a;
    __syncthreads();
  }
  int run = bpre[b] + sh[t] - s;
  int base = b * 2048 + t * 8;
#pragma unroll
  for (int j = 0; j < 8; ++j) {
    int i = base + j;
    if (i < NROWS) { rowoff[i] = run; cursor[i] = run; }
    run += v[j];
  }
}

// sort edges by row = dst*8+rel; payload: src (18b) | rowlocal (8b) << 18
__global__ void k_scatter(const int* __restrict__ ei, const int* __restrict__ et,
                          int* __restrict__ cursor, int* __restrict__ ep) {
  int e = blockIdx.x * 256 + threadIdx.x;
  if (e < N_EDGES) {
    int src = ei[e];
    int dst = ei[N_EDGES + e];
    int r = et[e];
    int row = dst * N_RELS + r;
    int pos = atomicAdd(&cursor[row], 1);
    ep[pos] = src | ((row & 255) << 18);
  }
}

// ---------------- fused aggregate + MFMA transform ----------------
// Block: 32 dsts = 256 rows, 512 threads (8 waves), ~34 KB LDS -> 4 blk/CU.
// Wave partition: threads t<9 binary-search loff[0..256] so each wave's
// contiguous row range holds ~n/8 edges (row-aligned; imbalance bounded by
// one run length).
// Phase 1: scalarized edge stream (readfirstlane payloads, scalar run-break
// branch, 8 gathers in flight); flush mean -> RNE bf16 -> one ds_write_b16.
// Phase 2 (NCOL=64): 8 waves = 2 M x 4 N, full K=576 per wave, DIRECT global
// epilogue (no reduce). (NCOL=32): 2 M x 2 N x 2 K-split, 2-way LDS reduce.

template <int NCOL, bool RELUOUT, bool OUTBF>
__global__ __launch_bounds__(512, 8) void k_rgcn(
    const ushort* __restrict__ Xg, const ushort* __restrict__ Bf,
    const float* __restrict__ Bias, const int* __restrict__ rowoff,
    const int* __restrict__ ep, void* __restrict__ OutP) {
  __shared__ __align__(16) ushort agg[256 * 64];    // 32 KB bf16 plane
  __shared__ int loff[260];
  __shared__ int wsplit[12];
  __shared__ __align__(16) float bias_lds[64];

  int t = threadIdx.x;
  int b = blockIdx.x;
  int d0 = b * 32;
  int lane = t & 63, w = t >> 6;

  {
    uint4 zz = make_uint4(0, 0, 0, 0);
    uint4* a4 = (uint4*)agg;
#pragma unroll
    for (int q = 0; q < 4; ++q) a4[t + q * 512] = zz;
  }
  if (t < 257) loff[t] = rowoff[b * 256 + t];
  if (t < NCOL) bias_lds[t] = Bias[t];
  __syncthreads();
  if (t < 9) {
    int s0 = loff[0], ntot = loff[256] - s0;
    int target = s0 + ((ntot * t) >> 3);
    int lo = 0, hi = 256;
    while (lo < hi) {
      int mid = (lo + hi) >> 1;
      if (loff[mid] < target) lo = mid + 1; else hi = mid;
    }
    wsplit[t] = lo;
  }
  __syncthreads();

  // ---- phase 1: scalar edge stream, batched gathers, branchy flush ----
  {
    int s = __builtin_amdgcn_readfirstlane(loff[wsplit[w]]);
    int e = __builtin_amdgcn_readfirstlane(loff[wsplit[w + 1]]);
    int n = e - s;
    const int* wep = ep + s;
    const char* Xb = (const char*)Xg;
    unsigned lane2 = (unsigned)(lane << 1);
    int cur = -1, nrun = 0;
    float a = 0.f;

#define FLUSH()                                                         \
    {                                                                   \
      float m = a * __builtin_amdgcn_rcpf((float)nrun);                 \
      int sw = (cur << 6) + (lane ^ (((cur >> 3) & 7) << 3));           \
      agg[sw] = rne_bf16(m);                                            \
    }

    int i = 0;
    for (; i + 8 <= n; i += 8) {
      int pk[8];
#pragma unroll
      for (int u = 0; u < 8; ++u)
        pk[u] = __builtin_amdgcn_readfirstlane(wep[i + u]);
      ushort hv[8];
#pragma unroll
      for (int u = 0; u < 8; ++u)
        hv[u] = *(const ushort*)(Xb + ((((unsigned)pk[u] & 0x3FFFFu) << 7) + lane2));
#pragma unroll
      for (int u = 0; u < 8; ++u) {
        int row = (int)((unsigned)pk[u] >> 18);
        float v = __uint_as_float((unsigned)hv[u] << 16);
        if (row != cur) {            // scalar cmp + branch
          if (cur >= 0) FLUSH();
          cur = row; a = 0.f; nrun = 0;
        }
        a += v; ++nrun;
      }
    }
    for (; i < n; ++i) {
      int pk = __builtin_amdgcn_readfirstlane(wep[i]);
      ushort hv = *(const ushort*)(Xb + ((((unsigned)pk & 0x3FFFFu) << 7) + lane2));
      int row = (int)((unsigned)pk >> 18);
      float v = __uint_as_float((unsigned)hv << 16);
      if (row != cur) {
        if (cur >= 0) FLUSH();
        cur = row; a = 0.f; nrun = 0;
      }
      a += v; ++nrun;
    }
    if (cur >= 0) FLUSH();
#undef FLUSH
  }
  __syncthreads();

  // ---- phase 2: pure-bf16 MFMA ----
  int l15 = lane & 15, kg = lane >> 4;
  f32x4 acc = {0.f, 0.f, 0.f, 0.f};

  if constexpr (NCOL == 64) {
    int wm = w >> 2, wn = w & 3;
    int col = wn * 16 + l15;
    for (int ks = 0; ks < 18; ++ks) {
      union { uint4 q; short8v s; } bh, ah;
      bh.q = *(const uint4*)(Bf + (ks * 4 + wn) * 512 + lane * 8);
      if (ks < 16) {
        int rr = ks >> 1;
        int f0 = ((ks & 1) << 5) + (kg << 3);
        int row = ((wm * 16 + l15) << 3) + rr;
        int sw = (row << 6) + (f0 ^ ((l15 & 7) << 3));
        ah.q = *(const uint4*)&agg[sw];
      } else {
        int kb = ((ks - 16) << 5) + (kg << 3);
        ah.q = *(const uint4*)&Xg[(size_t)(d0 + wm * 16 + l15) * 64 + kb];
      }
      acc = __builtin_amdgcn_mfma_f32_16x16x32_bf16(ah.s, bh.s, acc, 0, 0, 0);
    }
    // direct epilogue
#pragma unroll
    for (int i2 = 0; i2 < 4; ++i2) {
      float v = acc[i2] + bias_lds[col];
      if (RELUOUT) v = fmaxf(v, 0.f);
      size_t o = (size_t)(d0 + wm * 16 + kg * 4 + i2) * 64 + col;
      if (OUTBF) ((ushort*)OutP)[o] = rne_bf16(v);
      else ((float*)OutP)[o] = v;
    }
  } else {
    int wm = w >> 2, wn = (w >> 1) & 1, ksp = w & 1;
    int col = wn * 16 + l15;
    for (int ks = ksp; ks < 18; ks += 2) {
      union { uint4 q; short8v s; } bh, ah;
      bh.q = *(const uint4*)(Bf + (ks * 2 + wn) * 512 + lane * 8);
      if (ks < 16) {
        int rr = ks >> 1;
        int f0 = ((ks & 1) << 5) + (kg << 3);
        int row = ((wm * 16 + l15) << 3) + rr;
        int sw = (row << 6) + (f0 ^ ((l15 & 7) << 3));
        ah.q = *(const uint4*)&agg[sw];
      } else {
        int kb = ((ks - 16) << 5) + (kg << 3);
        ah.q = *(const uint4*)&Xg[(size_t)(d0 + wm * 16 + l15) * 64 + kb];
      }
      acc = __builtin_amdgcn_mfma_f32_16x16x32_bf16(ah.s, bh.s, acc, 0, 0, 0);
    }
    __syncthreads();               // agg reads done before reuse
    float* red = (float*)agg;
    int rbase = wm * 16 + kg * 4;
    if (ksp == 1) {
#pragma unroll
      for (int i2 = 0; i2 < 4; ++i2) red[(rbase + i2) * 36 + col] = acc[i2];
    }
    __syncthreads();
    if (ksp == 0) {
#pragma unroll
      for (int i2 = 0; i2 < 4; ++i2) {
        float v = acc[i2] + red[(rbase + i2) * 36 + col] + bias_lds[col];
        if (RELUOUT) v = fmaxf(v, 0.f);
        ((float*)OutP)[(size_t)(d0 + rbase + i2) * 32 + col] = v;
      }
    }
  }
}

// ---------------- launch ----------------

extern "C" void kernel_launch(void* const* d_in, const int* in_sizes, int n_in,
                              void* d_out, int out_size, void* d_ws, size_t ws_size,
                              hipStream_t stream) {
  const float* x = (const float*)d_in[0];
  const int* ei = (const int*)d_in[1];
  const int* et = (const int*)d_in[2];
  const float* w1 = (const float*)d_in[3];
  const float* r1 = (const float*)d_in[4];
  const float* b1 = (const float*)d_in[5];
  const float* w2 = (const float*)d_in[6];
  const float* r2 = (const float*)d_in[7];
  const float* b2 = (const float*)d_in[8];
  float* out = (float*)d_out;

  int* cnt = (int*)d_ws;                     // NROWS_PAD ints
  int* bsum = cnt + NROWS_PAD;               // 1024
  int* bpre = bsum + 1024;                   // 1024
  int* rowoff = bpre + 1024;                 // NROWS+1 (pad 16)
  int* cursor = rowoff + NROWS + 16;         // NROWS
  int* ep = cursor + NROWS;                  // N_EDGES
  ushort* bf1 = (ushort*)(ep + N_EDGES);     // 36864 (single plane)
  ushort* bf2 = bf1 + 36864;                 // 18432
  ushort* xbf = bf2 + 18432;                 // 12,800,000 (25.6 MB)
  ushort* hbf = xbf + 12800000;              // 12,800,000 (25.6 MB)

  hipMemsetAsync(cnt, 0, (size_t)NROWS_PAD * 4, stream);
  k_setup<<<NB_COUNT + NB_XCAST + NB_PREP1 + NB_PREP2, 256, 0, stream>>>(
      ei, et, cnt, x, xbf, w1, r1, bf1, w2, r2, bf2);
  k_bsum<<<NSCAN, 256, 0, stream>>>(cnt, bsum);
  k_scan1<<<1, 1024, 0, stream>>>(bsum, bpre, rowoff);
  k_apply<<<NSCAN, 256, 0, stream>>>(cnt, bpre, rowoff, cursor);
  k_scatter<<<(N_EDGES + 255) / 256, 256, 0, stream>>>(ei, et, cursor, ep);

  k_rgcn<64, true, true><<<NBUCK, 512, 0, stream>>>(xbf, bf1, b1, rowoff, ep, hbf);
  k_rgcn<32, false, false><<<NBUCK, 512, 0, stream>>>(hbf, bf2, b2, rowoff, ep, out);
}

// Round 13
// 297.613 us; speedup vs baseline: 15.1405x; 1.0873x over previous
//
#include <hip/hip_runtime.h>

#define N_NODES 200000
#define N_EDGES 1250000
#define N_RELS 8
#define NROWS 1600000        // N_NODES * N_RELS
#define NROWS_PAD 1601536    // 782 * 2048
#define NSCAN 782
#define NBUCK 6250           // N_NODES / 32

#define NB_COUNT 4883        // ceil(N_EDGES/256)
#define NB_XCAST 6250        // 1.6M/256
#define NB_PREP1 144         // 64*576/256
#define NB_PREP2 72          // 32*576/256

typedef __attribute__((ext_vector_type(8))) short short8v;
typedef __attribute__((ext_vector_type(4))) float f32x4;

__device__ __forceinline__ ushort rne_bf16(float v) {
  unsigned u = __float_as_uint(v);
  return (ushort)((u + 0x7FFFu + ((u >> 16) & 1u)) >> 16);
}

// ---------------- fused setup: count(+rank) | xcast | prep1 | prep2 ----------------

// Bf fragment-order single-plane bf16 (RNE): slab (ks,wn) = 512 ushorts;
// element (lane, j) = B[k = ks*32 + (lane>>4)*8 + j][col = wn*16 + (lane&15)]
__device__ __forceinline__ void prep_body(const float* W, const float* Root,
                                          ushort* Bf, int ncol, int i) {
  int col = i / 576, k = i - col * 576;
  float w = (k < 512) ? W[k * ncol + col] : Root[(k - 512) * ncol + col];
  int WN = ncol >> 4;
  int ks = k >> 5, kg = (k >> 3) & 3, j = k & 7;
  int wn = col >> 4, l15 = col & 15;
  int lane = (kg << 4) | l15;
  Bf[(ks * WN + wn) * 512 + lane * 8 + j] = rne_bf16(w);
}

__global__ __launch_bounds__(256) void k_setup(
    const int* __restrict__ ei, const int* __restrict__ et, int* __restrict__ cnt,
    int* __restrict__ er,
    const float* __restrict__ x, ushort* __restrict__ xbf,
    const float* __restrict__ w1, const float* __restrict__ r1, ushort* __restrict__ bf1,
    const float* __restrict__ w2, const float* __restrict__ r2, ushort* __restrict__ bf2) {
  int blk = blockIdx.x, t = threadIdx.x;
  if (blk < NB_COUNT) {
    int e = blk * 256 + t;
    if (e < N_EDGES) {
      int dst = ei[N_EDGES + e];
      int r = et[e];
      er[e] = atomicAdd(&cnt[dst * N_RELS + r], 1);   // rank within (dst,rel)
    }
  } else if (blk < NB_COUNT + NB_XCAST) {
    int i = (blk - NB_COUNT) * 256 + t;   // i < 1.6M
    float4 a = ((const float4*)x)[i * 2];
    float4 b = ((const float4*)x)[i * 2 + 1];
    union { uint4 q; ushort u[8]; } o;
    o.u[0] = rne_bf16(a.x); o.u[1] = rne_bf16(a.y);
    o.u[2] = rne_bf16(a.z); o.u[3] = rne_bf16(a.w);
    o.u[4] = rne_bf16(b.x); o.u[5] = rne_bf16(b.y);
    o.u[6] = rne_bf16(b.z); o.u[7] = rne_bf16(b.w);
    ((uint4*)xbf)[i] = o.q;
  } else if (blk < NB_COUNT + NB_XCAST + NB_PREP1) {
    int i = (blk - NB_COUNT - NB_XCAST) * 256 + t;
    prep_body(w1, r1, bf1, 64, i);
  } else {
    int i = (blk - NB_COUNT - NB_XCAST - NB_PREP1) * 256 + t;
    prep_body(w2, r2, bf2, 32, i);
  }
}

// ---------------- sort infrastructure ----------------

__global__ __launch_bounds__(256) void k_bsum(const int* __restrict__ cnt,
                                              int* __restrict__ bsum) {
  __shared__ int sh[256];
  int b = blockIdx.x, t = threadIdx.x;
  const int4* p = (const int4*)(cnt + b * 2048);
  int4 v0 = p[2 * t], v1 = p[2 * t + 1];
  int s = v0.x + v0.y + v0.z + v0.w + v1.x + v1.y + v1.z + v1.w;
  sh[t] = s;
  __syncthreads();
  for (int o = 128; o >= 1; o >>= 1) {
    if (t < o) sh[t] += sh[t + o];
    __syncthreads();
  }
  if (t == 0) bsum[b] = sh[0];
}

__global__ __launch_bounds__(1024) void k_scan1(const int* __restrict__ bsum,
                                                int* __restrict__ bpre,
                                                int* __restrict__ rowoff) {
  __shared__ int sh[1024];
  int t = threadIdx.x;
  int v = (t < NSCAN) ? bsum[t] : 0;
  sh[t] = v;
  __syncthreads();
  for (int o = 1; o < 1024; o <<= 1) {
    int a = (t >= o) ? sh[t - o] : 0;
    __syncthreads();
    sh[t] += a;
    __syncthreads();
  }
  if (t < NSCAN) bpre[t] = sh[t] - v;
  if (t == 0) rowoff[NROWS] = N_EDGES;
}

__global__ __launch_bounds__(256) void k_apply(const int* __restrict__ cnt,
                                               const int* __restrict__ bpre,
                                               int* __restrict__ rowoff) {
  __shared__ int sh[256];
  int b = blockIdx.x, t = threadIdx.x;
  const int4* p = (const int4*)(cnt + b * 2048);
  int4 v0 = p[2 * t], v1 = p[2 * t + 1];
  int v[8] = {v0.x, v0.y, v0.z, v0.w, v1.x, v1.y, v1.z, v1.w};
  int s = 0;
#pragma unroll
  for (int j = 0; j < 8; ++j) s += v[j];
  sh[t] = s;
  __syncthreads();
  for (int o = 1; o < 256; o <<= 1) {
    int a = (t >= o) ? sh[t - o] : 0;
    __syncthreads();
    sh[t] += a;
    __syncthreads();
  }
  int run = bpre[b] + sh[t] - s;
  int base = b * 2048 + t * 8;
#pragma unroll
  for (int j = 0; j < 8; ++j) {
    int i = base + j;
    if (i < NROWS) rowoff[i] = run;
    run += v[j];
  }
}

// place edges sorted by row = dst*8+rel (no atomics: pos = rowoff + rank)
__global__ void k_scatter(const int* __restrict__ ei, const int* __restrict__ et,
                          const int* __restrict__ rowoff, const int* __restrict__ er,
                          int* __restrict__ ep) {
  int e = blockIdx.x * 256 + threadIdx.x;
  if (e < N_EDGES) {
    int src = ei[e];
    int dst = ei[N_EDGES + e];
    int r = et[e];
    int row = dst * N_RELS + r;
    int pos = rowoff[row] + er[e];
    ep[pos] = src | ((row & 255) << 18);
  }
}

// ---------------- fused aggregate + MFMA transform ----------------
// Block: 32 dsts = 256 rows, 512 threads (8 waves), ~34 KB LDS -> 4 blk/CU.
// Wave partition: threads t<9 binary-search loff[0..256] so each wave's
// contiguous row range holds ~n/8 edges.
// Phase 1 (3-stage software pipeline): payload batch k+3 issues while rows
// of k+2 are readfirstlane'd and its gathers launch, and batch k (gathers
// issued 2 steps earlier) is consumed -> gather latency hidden. Scalar
// run-break branch; flush mean -> RNE bf16 -> one ds_write_b16 (swizzled).
// Phase 2 (NCOL=64): 8 waves = 2M x 4N, full K=576/wave, direct global
// epilogue. (NCOL=32): 2M x 2N x 2K-split, 2-way LDS reduce.

template <int NCOL, bool RELUOUT, bool OUTBF>
__global__ __launch_bounds__(512, 8) void k_rgcn(
    const ushort* __restrict__ Xg, const ushort* __restrict__ Bf,
    const float* __restrict__ Bias, const int* __restrict__ rowoff,
    const int* __restrict__ ep, void* __restrict__ OutP) {
  __shared__ __align__(16) ushort agg[256 * 64];    // 32 KB bf16 plane
  __shared__ int loff[260];
  __shared__ int wsplit[12];
  __shared__ __align__(16) float bias_lds[64];

  int t = threadIdx.x;
  int b = blockIdx.x;
  int d0 = b * 32;
  int lane = t & 63, w = t >> 6;

  {
    uint4 zz = make_uint4(0, 0, 0, 0);
    uint4* a4 = (uint4*)agg;
#pragma unroll
    for (int q = 0; q < 4; ++q) a4[t + q * 512] = zz;
  }
  if (t < 257) loff[t] = rowoff[b * 256 + t];
  if (t < NCOL) bias_lds[t] = Bias[t];
  __syncthreads();
  if (t < 9) {
    int s0 = loff[0], ntot = loff[256] - s0;
    int target = s0 + ((ntot * t) >> 3);
    int lo = 0, hi = 256;
    while (lo < hi) {
      int mid = (lo + hi) >> 1;
      if (loff[mid] < target) lo = mid + 1; else hi = mid;
    }
    wsplit[t] = lo;
  }
  __syncthreads();

  // ---- phase 1: 3-stage pipelined scalar edge stream ----
  {
    int s = __builtin_amdgcn_readfirstlane(loff[wsplit[w]]);
    int e = __builtin_amdgcn_readfirstlane(loff[wsplit[w + 1]]);
    int n = e - s;
    const int* wep = ep + s;
    const char* Xb = (const char*)Xg;
    unsigned lane2 = (unsigned)(lane << 1);
    int cur = -1, nrun = 0;
    float a = 0.f;

#define FLUSH()                                                         \
    {                                                                   \
      float m = a * __builtin_amdgcn_rcpf((float)nrun);                 \
      int sw = (cur << 6) + (lane ^ (((cur >> 3) & 7) << 3));           \
      agg[sw] = rne_bf16(m);                                            \
    }
#define PAYLOAD(P, B)                                                   \
    _Pragma("unroll")                                                   \
    for (int u = 0; u < 8; ++u) {                                       \
      int idx = (B) + u; if (idx > n - 1) idx = n - 1;                  \
      P[u] = wep[idx];                                                  \
    }
#define RFLG(S, P, HV)                                                  \
    _Pragma("unroll")                                                   \
    for (int u = 0; u < 8; ++u) {                                       \
      S[u] = __builtin_amdgcn_readfirstlane(P[u]);                      \
      HV[u] = *(const ushort*)(Xb + ((((unsigned)S[u] & 0x3FFFFu) << 7) + lane2)); \
    }
#define ACCUM(S, HV, B)                                                 \
    {                                                                   \
      int nb = n - (B); if (nb > 8) nb = 8;                             \
      _Pragma("unroll")                                                 \
      for (int u = 0; u < 8; ++u) {                                     \
        if (u < nb) {                                                   \
          int row = (int)((unsigned)S[u] >> 18);                        \
          float v = __uint_as_float((unsigned)HV[u] << 16);             \
          if (row != cur) {                                             \
            if (cur >= 0) FLUSH();                                      \
            cur = row; a = 0.f; nrun = 0;                               \
          }                                                             \
          a += v; ++nrun;                                               \
        }                                                               \
      }                                                                 \
    }

    if (n > 0) {
      int p0[8], p1[8], p2[8], s0[8], s1[8], s2[8];
      ushort hv0[8], hv1[8], hv2[8];
      PAYLOAD(p0, 0); PAYLOAD(p1, 8); PAYLOAD(p2, 16);
      RFLG(s0, p0, hv0);
      RFLG(s1, p1, hv1);
      for (int base = 0; base < n; base += 24) {
        PAYLOAD(p0, base + 24);
        RFLG(s2, p2, hv2);
        ACCUM(s0, hv0, base);
        PAYLOAD(p1, base + 32);
        RFLG(s0, p0, hv0);
        ACCUM(s1, hv1, base + 8);
        PAYLOAD(p2, base + 40);
        RFLG(s1, p1, hv1);
        ACCUM(s2, hv2, base + 16);
      }
      if (cur >= 0) FLUSH();
    }
#undef ACCUM
#undef RFLG
#undef PAYLOAD
#undef FLUSH
  }
  __syncthreads();

  // ---- phase 2: pure-bf16 MFMA ----
  int l15 = lane & 15, kg = lane >> 4;
  f32x4 acc = {0.f, 0.f, 0.f, 0.f};

  if constexpr (NCOL == 64) {
    int wm = w >> 2, wn = w & 3;
    int col = wn * 16 + l15;
    for (int ks = 0; ks < 18; ++ks) {
      union { uint4 q; short8v s; } bh, ah;
      bh.q = *(const uint4*)(Bf + (ks * 4 + wn) * 512 + lane * 8);
      if (ks < 16) {
        int rr = ks >> 1;
        int f0 = ((ks & 1) << 5) + (kg << 3);
        int row = ((wm * 16 + l15) << 3) + rr;
        int sw = (row << 6) + (f0 ^ ((l15 & 7) << 3));
        ah.q = *(const uint4*)&agg[sw];
      } else {
        int kb = ((ks - 16) << 5) + (kg << 3);
        ah.q = *(const uint4*)&Xg[(size_t)(d0 + wm * 16 + l15) * 64 + kb];
      }
      acc = __builtin_amdgcn_mfma_f32_16x16x32_bf16(ah.s, bh.s, acc, 0, 0, 0);
    }
    // direct epilogue
#pragma unroll
    for (int i2 = 0; i2 < 4; ++i2) {
      float v = acc[i2] + bias_lds[col];
      if (RELUOUT) v = fmaxf(v, 0.f);
      size_t o = (size_t)(d0 + wm * 16 + kg * 4 + i2) * 64 + col;
      if (OUTBF) ((ushort*)OutP)[o] = rne_bf16(v);
      else ((float*)OutP)[o] = v;
    }
  } else {
    int wm = w >> 2, wn = (w >> 1) & 1, ksp = w & 1;
    int col = wn * 16 + l15;
    for (int ks = ksp; ks < 18; ks += 2) {
      union { uint4 q; short8v s; } bh, ah;
      bh.q = *(const uint4*)(Bf + (ks * 2 + wn) * 512 + lane * 8);
      if (ks < 16) {
        int rr = ks >> 1;
        int f0 = ((ks & 1) << 5) + (kg << 3);
        int row = ((wm * 16 + l15) << 3) + rr;
        int sw = (row << 6) + (f0 ^ ((l15 & 7) << 3));
        ah.q = *(const uint4*)&agg[sw];
      } else {
        int kb = ((ks - 16) << 5) + (kg << 3);
        ah.q = *(const uint4*)&Xg[(size_t)(d0 + wm * 16 + l15) * 64 + kb];
      }
      acc = __builtin_amdgcn_mfma_f32_16x16x32_bf16(ah.s, bh.s, acc, 0, 0, 0);
    }
    __syncthreads();               // agg reads done before reuse
    float* red = (float*)agg;
    int rbase = wm * 16 + kg * 4;
    if (ksp == 1) {
#pragma unroll
      for (int i2 = 0; i2 < 4; ++i2) red[(rbase + i2) * 36 + col] = acc[i2];
    }
    __syncthreads();
    if (ksp == 0) {
#pragma unroll
      for (int i2 = 0; i2 < 4; ++i2) {
        float v = acc[i2] + red[(rbase + i2) * 36 + col] + bias_lds[col];
        if (RELUOUT) v = fmaxf(v, 0.f);
        ((float*)OutP)[(size_t)(d0 + rbase + i2) * 32 + col] = v;
      }
    }
  }
}

// ---------------- launch ----------------

extern "C" void kernel_launch(void* const* d_in, const int* in_sizes, int n_in,
                              void* d_out, int out_size, void* d_ws, size_t ws_size,
                              hipStream_t stream) {
  const float* x = (const float*)d_in[0];
  const int* ei = (const int*)d_in[1];
  const int* et = (const int*)d_in[2];
  const float* w1 = (const float*)d_in[3];
  const float* r1 = (const float*)d_in[4];
  const float* b1 = (const float*)d_in[5];
  const float* w2 = (const float*)d_in[6];
  const float* r2 = (const float*)d_in[7];
  const float* b2 = (const float*)d_in[8];
  float* out = (float*)d_out;

  int* cnt = (int*)d_ws;                     // NROWS_PAD ints
  int* bsum = cnt + NROWS_PAD;               // 1024
  int* bpre = bsum + 1024;                   // 1024
  int* rowoff = bpre + 1024;                 // NROWS+1 (pad 16)
  int* er = rowoff + NROWS + 16;             // N_EDGES (edge rank)
  int* ep = er + N_EDGES;                    // N_EDGES
  ushort* bf1 = (ushort*)(ep + N_EDGES);     // 36864 (single plane)
  ushort* bf2 = bf1 + 36864;                 // 18432
  ushort* xbf = bf2 + 18432;                 // 12,800,000 (25.6 MB)
  ushort* hbf = xbf + 12800000;              // 12,800,000 (25.6 MB)

  hipMemsetAsync(cnt, 0, (size_t)NROWS_PAD * 4, stream);
  k_setup<<<NB_COUNT + NB_XCAST + NB_PREP1 + NB_PREP2, 256, 0, stream>>>(
      ei, et, cnt, er, x, xbf, w1, r1, bf1, w2, r2, bf2);
  k_bsum<<<NSCAN, 256, 0, stream>>>(cnt, bsum);
  k_scan1<<<1, 1024, 0, stream>>>(bsum, bpre, rowoff);
  k_apply<<<NSCAN, 256, 0, stream>>>(cnt, bpre, rowoff);
  k_scatter<<<(N_EDGES + 255) / 256, 256, 0, stream>>>(ei, et, rowoff, er, ep);

  k_rgcn<64, true, true><<<NBUCK, 512, 0, stream>>>(xbf, bf1, b1, rowoff, ep, hbf);
  k_rgcn<32, false, false><<<NBUCK, 512, 0, stream>>>(hbf, bf2, b2, rowoff, ep, out);
}

// Round 14
// 276.331 us; speedup vs baseline: 16.3066x; 1.0770x over previous
//
#include <hip/hip_runtime.h>

#define N_NODES 200000
#define N_EDGES 1250000
#define N_RELS 8
#define NROWS 1600000        // N_NODES * N_RELS
#define NROWS_PAD 1601536    // 782 * 2048
#define NSCAN 782
#define NBUCK 6250           // N_NODES / 32

#define NB_COUNT 4883        // ceil(N_EDGES/256)
#define NB_XCAST 6250        // 1.6M/256
#define NB_PREP1 144         // 64*576/256
#define NB_PREP2 72          // 32*576/256

typedef __attribute__((ext_vector_type(8))) short short8v;
typedef __attribute__((ext_vector_type(4))) float f32x4;

__device__ __forceinline__ ushort rne_bf16(float v) {
  unsigned u = __float_as_uint(v);
  return (ushort)((u + 0x7FFFu + ((u >> 16) & 1u)) >> 16);
}

// ---------------- fused setup: count(+rank) | xcast | prep1 | prep2 ----------------

__device__ __forceinline__ void prep_body(const float* W, const float* Root,
                                          ushort* Bf, int ncol, int i) {
  int col = i / 576, k = i - col * 576;
  float w = (k < 512) ? W[k * ncol + col] : Root[(k - 512) * ncol + col];
  int WN = ncol >> 4;
  int ks = k >> 5, kg = (k >> 3) & 3, j = k & 7;
  int wn = col >> 4, l15 = col & 15;
  int lane = (kg << 4) | l15;
  Bf[(ks * WN + wn) * 512 + lane * 8 + j] = rne_bf16(w);
}

__global__ __launch_bounds__(256) void k_setup(
    const int* __restrict__ ei, const int* __restrict__ et, int* __restrict__ cnt,
    int* __restrict__ er,
    const float* __restrict__ x, ushort* __restrict__ xbf,
    const float* __restrict__ w1, const float* __restrict__ r1, ushort* __restrict__ bf1,
    const float* __restrict__ w2, const float* __restrict__ r2, ushort* __restrict__ bf2) {
  int blk = blockIdx.x, t = threadIdx.x;
  if (blk < NB_COUNT) {
    int e = blk * 256 + t;
    if (e < N_EDGES) {
      int dst = ei[N_EDGES + e];
      int r = et[e];
      er[e] = atomicAdd(&cnt[dst * N_RELS + r], 1);   // rank within (dst,rel)
    }
  } else if (blk < NB_COUNT + NB_XCAST) {
    int i = (blk - NB_COUNT) * 256 + t;   // i < 1.6M
    float4 a = ((const float4*)x)[i * 2];
    float4 b = ((const float4*)x)[i * 2 + 1];
    union { uint4 q; ushort u[8]; } o;
    o.u[0] = rne_bf16(a.x); o.u[1] = rne_bf16(a.y);
    o.u[2] = rne_bf16(a.z); o.u[3] = rne_bf16(a.w);
    o.u[4] = rne_bf16(b.x); o.u[5] = rne_bf16(b.y);
    o.u[6] = rne_bf16(b.z); o.u[7] = rne_bf16(b.w);
    ((uint4*)xbf)[i] = o.q;
  } else if (blk < NB_COUNT + NB_XCAST + NB_PREP1) {
    int i = (blk - NB_COUNT - NB_XCAST) * 256 + t;
    prep_body(w1, r1, bf1, 64, i);
  } else {
    int i = (blk - NB_COUNT - NB_XCAST - NB_PREP1) * 256 + t;
    prep_body(w2, r2, bf2, 32, i);
  }
}

// ---------------- sort infrastructure ----------------

__global__ __launch_bounds__(256) void k_bsum(const int* __restrict__ cnt,
                                              int* __restrict__ bsum) {
  __shared__ int sh[256];
  int b = blockIdx.x, t = threadIdx.x;
  const int4* p = (const int4*)(cnt + b * 2048);
  int4 v0 = p[2 * t], v1 = p[2 * t + 1];
  int s = v0.x + v0.y + v0.z + v0.w + v1.x + v1.y + v1.z + v1.w;
  sh[t] = s;
  __syncthreads();
  for (int o = 128; o >= 1; o >>= 1) {
    if (t < o) sh[t] += sh[t + o];
    __syncthreads();
  }
  if (t == 0) bsum[b] = sh[0];
}

__global__ __launch_bounds__(1024) void k_scan1(const int* __restrict__ bsum,
                                                int* __restrict__ bpre,
                                                int* __restrict__ rowoff) {
  __shared__ int sh[1024];
  int t = threadIdx.x;
  int v = (t < NSCAN) ? bsum[t] : 0;
  sh[t] = v;
  __syncthreads();
  for (int o = 1; o < 1024; o <<= 1) {
    int a = (t >= o) ? sh[t - o] : 0;
    __syncthreads();
    sh[t] += a;
    __syncthreads();
  }
  if (t < NSCAN) bpre[t] = sh[t] - v;
  if (t == 0) rowoff[NROWS] = N_EDGES;
}

__global__ __launch_bounds__(256) void k_apply(const int* __restrict__ cnt,
                                               const int* __restrict__ bpre,
                                               int* __restrict__ rowoff) {
  __shared__ int sh[256];
  int b = blockIdx.x, t = threadIdx.x;
  const int4* p = (const int4*)(cnt + b * 2048);
  int4 v0 = p[2 * t], v1 = p[2 * t + 1];
  int v[8] = {v0.x, v0.y, v0.z, v0.w, v1.x, v1.y, v1.z, v1.w};
  int s = 0;
#pragma unroll
  for (int j = 0; j < 8; ++j) s += v[j];
  sh[t] = s;
  __syncthreads();
  for (int o = 1; o < 256; o <<= 1) {
    int a = (t >= o) ? sh[t - o] : 0;
    __syncthreads();
    sh[t] += a;
    __syncthreads();
  }
  int run = bpre[b] + sh[t] - s;
  int base = b * 2048 + t * 8;
#pragma unroll
  for (int j = 0; j < 8; ++j) {
    int i = base + j;
    if (i < NROWS) rowoff[i] = run;
    run += v[j];
  }
}

// place edges sorted by row = dst*8+rel (no atomics: pos = rowoff + rank)
__global__ void k_scatter(const int* __restrict__ ei, const int* __restrict__ et,
                          const int* __restrict__ rowoff, const int* __restrict__ er,
                          int* __restrict__ ep) {
  int e = blockIdx.x * 256 + threadIdx.x;
  if (e < N_EDGES) {
    int src = ei[e];
    int dst = ei[N_EDGES + e];
    int r = et[e];
    int row = dst * N_RELS + r;
    int pos = rowoff[row] + er[e];
    ep[pos] = src | ((row & 255) << 18);
  }
}

// ---------------- fused aggregate + MFMA transform ----------------
// Block: 32 dsts = 256 rows, 512 threads (8 waves), ~34 KB LDS -> 4 blk/CU.
// Wave partition: threads t<9 binary-search loff[0..256] so each wave's
// contiguous row range holds ~n/8 edges.
// Phase 1: scalarized edge stream — payload load ADJACENT to readfirstlane
// (compiler emits s_load; round-13 separation regressed FETCH +60B/edge),
// 8 gathers in flight, scalar run-break branch; flush mean -> RNE bf16 ->
// one ds_write_b16 (swizzled plane).
// Phase 2 (NCOL=64): 8 waves = 2M x 4N, full K=576/wave; epilogue staged in
// LDS then coalesced uint2 stores (fixes 100MB partial-line RMW writes).
// (NCOL=32): 2M x 2N x 2K-split, 2-way LDS reduce, direct f32 stores.

template <int NCOL, bool RELUOUT, bool OUTBF>
__global__ __launch_bounds__(512, 8) void k_rgcn(
    const ushort* __restrict__ Xg, const ushort* __restrict__ Bf,
    const float* __restrict__ Bias, const int* __restrict__ rowoff,
    const int* __restrict__ ep, void* __restrict__ OutP) {
  __shared__ __align__(16) ushort agg[256 * 64];    // 32 KB bf16 plane
  __shared__ int loff[260];
  __shared__ int wsplit[12];
  __shared__ __align__(16) float bias_lds[64];

  int t = threadIdx.x;
  int b = blockIdx.x;
  int d0 = b * 32;
  int lane = t & 63, w = t >> 6;

  {
    uint4 zz = make_uint4(0, 0, 0, 0);
    uint4* a4 = (uint4*)agg;
#pragma unroll
    for (int q = 0; q < 4; ++q) a4[t + q * 512] = zz;
  }
  if (t < 257) loff[t] = rowoff[b * 256 + t];
  if (t < NCOL) bias_lds[t] = Bias[t];
  __syncthreads();
  if (t < 9) {
    int s0 = loff[0], ntot = loff[256] - s0;
    int target = s0 + ((ntot * t) >> 3);
    int lo = 0, hi = 256;
    while (lo < hi) {
      int mid = (lo + hi) >> 1;
      if (loff[mid] < target) lo = mid + 1; else hi = mid;
    }
    wsplit[t] = lo;
  }
  __syncthreads();

  // ---- phase 1: scalar edge stream, batched gathers, branchy flush ----
  {
    int s = __builtin_amdgcn_readfirstlane(loff[wsplit[w]]);
    int e = __builtin_amdgcn_readfirstlane(loff[wsplit[w + 1]]);
    int n = e - s;
    const int* wep = ep + s;
    const char* Xb = (const char*)Xg;
    unsigned lane2 = (unsigned)(lane << 1);
    int cur = -1, nrun = 0;
    float a = 0.f;

#define FLUSH()                                                         \
    {                                                                   \
      float m = a * __builtin_amdgcn_rcpf((float)nrun);                 \
      int sw = (cur << 6) + (lane ^ (((cur >> 3) & 7) << 3));           \
      agg[sw] = rne_bf16(m);                                            \
    }

    int i = 0;
    for (; i + 8 <= n; i += 8) {
      int pk[8];
#pragma unroll
      for (int u = 0; u < 8; ++u)
        pk[u] = __builtin_amdgcn_readfirstlane(wep[i + u]);
      ushort hv[8];
#pragma unroll
      for (int u = 0; u < 8; ++u)
        hv[u] = *(const ushort*)(Xb + ((((unsigned)pk[u] & 0x3FFFFu) << 7) + lane2));
#pragma unroll
      for (int u = 0; u < 8; ++u) {
        int row = (int)((unsigned)pk[u] >> 18);
        float v = __uint_as_float((unsigned)hv[u] << 16);
        if (row != cur) {            // scalar cmp + branch
          if (cur >= 0) FLUSH();
          cur = row; a = 0.f; nrun = 0;
        }
        a += v; ++nrun;
      }
    }
    for (; i < n; ++i) {
      int pk = __builtin_amdgcn_readfirstlane(wep[i]);
      ushort hv = *(const ushort*)(Xb + ((((unsigned)pk & 0x3FFFFu) << 7) + lane2));
      int row = (int)((unsigned)pk >> 18);
      float v = __uint_as_float((unsigned)hv << 16);
      if (row != cur) {
        if (cur >= 0) FLUSH();
        cur = row; a = 0.f; nrun = 0;
      }
      a += v; ++nrun;
    }
    if (cur >= 0) FLUSH();
#undef FLUSH
  }
  __syncthreads();

  // ---- phase 2: pure-bf16 MFMA ----
  int l15 = lane & 15, kg = lane >> 4;
  f32x4 acc = {0.f, 0.f, 0.f, 0.f};

  if constexpr (NCOL == 64) {
    int wm = w >> 2, wn = w & 3;
    int col = wn * 16 + l15;
    for (int ks = 0; ks < 18; ++ks) {
      union { uint4 q; short8v s; } bh, ah;
      bh.q = *(const uint4*)(Bf + (ks * 4 + wn) * 512 + lane * 8);
      if (ks < 16) {
        int rr = ks >> 1;
        int f0 = ((ks & 1) << 5) + (kg << 3);
        int row = ((wm * 16 + l15) << 3) + rr;
        int sw = (row << 6) + (f0 ^ ((l15 & 7) << 3));
        ah.q = *(const uint4*)&agg[sw];
      } else {
        int kb = ((ks - 16) << 5) + (kg << 3);
        ah.q = *(const uint4*)&Xg[(size_t)(d0 + wm * 16 + l15) * 64 + kb];
      }
      acc = __builtin_amdgcn_mfma_f32_16x16x32_bf16(ah.s, bh.s, acc, 0, 0, 0);
    }
    // epilogue: LDS-staged coalesced stores
    __syncthreads();                 // all agg reads done; reuse as stage
#pragma unroll
    for (int i2 = 0; i2 < 4; ++i2) {
      float v = acc[i2] + bias_lds[col];
      if (RELUOUT) v = fmaxf(v, 0.f);
      agg[(wm * 16 + kg * 4 + i2) * 64 + col] = rne_bf16(v);
    }
    __syncthreads();
    {
      int r = t >> 4, c4 = t & 15;
      uint2 v = *(const uint2*)&agg[r * 64 + c4 * 4];
      if (OUTBF) {
        ((uint2*)OutP)[(size_t)(d0 + r) * 16 + c4] = v;
      } else {
        // unused path for NCOL=64 f32 (not instantiated)
        ((uint2*)OutP)[(size_t)(d0 + r) * 16 + c4] = v;
      }
    }
  } else {
    int wm = w >> 2, wn = (w >> 1) & 1, ksp = w & 1;
    int col = wn * 16 + l15;
    for (int ks = ksp; ks < 18; ks += 2) {
      union { uint4 q; short8v s; } bh, ah;
      bh.q = *(const uint4*)(Bf + (ks * 2 + wn) * 512 + lane * 8);
      if (ks < 16) {
        int rr = ks >> 1;
        int f0 = ((ks & 1) << 5) + (kg << 3);
        int row = ((wm * 16 + l15) << 3) + rr;
        int sw = (row << 6) + (f0 ^ ((l15 & 7) << 3));
        ah.q = *(const uint4*)&agg[sw];
      } else {
        int kb = ((ks - 16) << 5) + (kg << 3);
        ah.q = *(const uint4*)&Xg[(size_t)(d0 + wm * 16 + l15) * 64 + kb];
      }
      acc = __builtin_amdgcn_mfma_f32_16x16x32_bf16(ah.s, bh.s, acc, 0, 0, 0);
    }
    __syncthreads();               // agg reads done before reuse
    float* red = (float*)agg;
    int rbase = wm * 16 + kg * 4;
    if (ksp == 1) {
#pragma unroll
      for (int i2 = 0; i2 < 4; ++i2) red[(rbase + i2) * 36 + col] = acc[i2];
    }
    __syncthreads();
    if (ksp == 0) {
#pragma unroll
      for (int i2 = 0; i2 < 4; ++i2) {
        float v = acc[i2] + red[(rbase + i2) * 36 + col] + bias_lds[col];
        if (RELUOUT) v = fmaxf(v, 0.f);
        ((float*)OutP)[(size_t)(d0 + rbase + i2) * 32 + col] = v;
      }
    }
  }
}

// ---------------- launch ----------------

extern "C" void kernel_launch(void* const* d_in, const int* in_sizes, int n_in,
                              void* d_out, int out_size, void* d_ws, size_t ws_size,
                              hipStream_t stream) {
  const float* x = (const float*)d_in[0];
  const int* ei = (const int*)d_in[1];
  const int* et = (const int*)d_in[2];
  const float* w1 = (const float*)d_in[3];
  const float* r1 = (const float*)d_in[4];
  const float* b1 = (const float*)d_in[5];
  const float* w2 = (const float*)d_in[6];
  const float* r2 = (const float*)d_in[7];
  const float* b2 = (const float*)d_in[8];
  float* out = (float*)d_out;

  int* cnt = (int*)d_ws;                     // NROWS_PAD ints
  int* bsum = cnt + NROWS_PAD;               // 1024
  int* bpre = bsum + 1024;                   // 1024
  int* rowoff = bpre + 1024;                 // NROWS+1 (pad 16)
  int* er = rowoff + NROWS + 16;             // N_EDGES (edge rank)
  int* ep = er + N_EDGES;                    // N_EDGES
  ushort* bf1 = (ushort*)(ep + N_EDGES);     // 36864 (single plane)
  ushort* bf2 = bf1 + 36864;                 // 18432
  ushort* xbf = bf2 + 18432;                 // 12,800,000 (25.6 MB)
  ushort* hbf = xbf + 12800000;              // 12,800,000 (25.6 MB)

  hipMemsetAsync(cnt, 0, (size_t)NROWS_PAD * 4, stream);
  k_setup<<<NB_COUNT + NB_XCAST + NB_PREP1 + NB_PREP2, 256, 0, stream>>>(
      ei, et, cnt, er, x, xbf, w1, r1, bf1, w2, r2, bf2);
  k_bsum<<<NSCAN, 256, 0, stream>>>(cnt, bsum);
  k_scan1<<<1, 1024, 0, stream>>>(bsum, bpre, rowoff);
  k_apply<<<NSCAN, 256, 0, stream>>>(cnt, bpre, rowoff);
  k_scatter<<<(N_EDGES + 255) / 256, 256, 0, stream>>>(ei, et, rowoff, er, ep);

  k_rgcn<64, true, true><<<NBUCK, 512, 0, stream>>>(xbf, bf1, b1, rowoff, ep, hbf);
  k_rgcn<32, false, false><<<NBUCK, 512, 0, stream>>>(hbf, bf2, b2, rowoff, ep, out);
}

// Round 15
// 271.422 us; speedup vs baseline: 16.6015x; 1.0181x over previous
//
#include <hip/hip_runtime.h>

#define N_NODES 200000
#define N_EDGES 1250000
#define N_RELS 8
#define NROWS 1600000        // N_NODES * N_RELS
#define NROWS_PAD 1601536    // 782 * 2048
#define NSCAN 782
#define NBUCK 6250           // N_NODES / 32

#define NB_COUNT 4883        // ceil(N_EDGES/256)
#define NB_XCAST 6250        // 1.6M/256
#define NB_PREP1 144         // 64*576/256
#define NB_PREP2 72          // 32*576/256

typedef __attribute__((ext_vector_type(8))) short short8v;
typedef __attribute__((ext_vector_type(4))) float f32x4;

__device__ __forceinline__ ushort rne_bf16(float v) {
  unsigned u = __float_as_uint(v);
  return (ushort)((u + 0x7FFFu + ((u >> 16) & 1u)) >> 16);
}

// ---------------- fused setup: count(+rank) | xcast | prep1 | prep2 ----------------

__device__ __forceinline__ void prep_body(const float* W, const float* Root,
                                          ushort* Bf, int ncol, int i) {
  int col = i / 576, k = i - col * 576;
  float w = (k < 512) ? W[k * ncol + col] : Root[(k - 512) * ncol + col];
  int WN = ncol >> 4;
  int ks = k >> 5, kg = (k >> 3) & 3, j = k & 7;
  int wn = col >> 4, l15 = col & 15;
  int lane = (kg << 4) | l15;
  Bf[(ks * WN + wn) * 512 + lane * 8 + j] = rne_bf16(w);
}

__global__ __launch_bounds__(256) void k_setup(
    const int* __restrict__ ei, const int* __restrict__ et, int* __restrict__ cnt,
    int* __restrict__ er,
    const float* __restrict__ x, ushort* __restrict__ xbf,
    const float* __restrict__ w1, const float* __restrict__ r1, ushort* __restrict__ bf1,
    const float* __restrict__ w2, const float* __restrict__ r2, ushort* __restrict__ bf2) {
  int blk = blockIdx.x, t = threadIdx.x;
  if (blk < NB_COUNT) {
    int e = blk * 256 + t;
    if (e < N_EDGES) {
      int dst = ei[N_EDGES + e];
      int r = et[e];
      er[e] = atomicAdd(&cnt[dst * N_RELS + r], 1);   // rank within (dst,rel)
    }
  } else if (blk < NB_COUNT + NB_XCAST) {
    int i = (blk - NB_COUNT) * 256 + t;   // i < 1.6M
    float4 a = ((const float4*)x)[i * 2];
    float4 b = ((const float4*)x)[i * 2 + 1];
    union { uint4 q; ushort u[8]; } o;
    o.u[0] = rne_bf16(a.x); o.u[1] = rne_bf16(a.y);
    o.u[2] = rne_bf16(a.z); o.u[3] = rne_bf16(a.w);
    o.u[4] = rne_bf16(b.x); o.u[5] = rne_bf16(b.y);
    o.u[6] = rne_bf16(b.z); o.u[7] = rne_bf16(b.w);
    ((uint4*)xbf)[i] = o.q;
  } else if (blk < NB_COUNT + NB_XCAST + NB_PREP1) {
    int i = (blk - NB_COUNT - NB_XCAST) * 256 + t;
    prep_body(w1, r1, bf1, 64, i);
  } else {
    int i = (blk - NB_COUNT - NB_XCAST - NB_PREP1) * 256 + t;
    prep_body(w2, r2, bf2, 32, i);
  }
}

// ---------------- sort infrastructure ----------------

__global__ __launch_bounds__(256) void k_bsum(const int* __restrict__ cnt,
                                              int* __restrict__ bsum) {
  __shared__ int sh[256];
  int b = blockIdx.x, t = threadIdx.x;
  const int4* p = (const int4*)(cnt + b * 2048);
  int4 v0 = p[2 * t], v1 = p[2 * t + 1];
  int s = v0.x + v0.y + v0.z + v0.w + v1.x + v1.y + v1.z + v1.w;
  sh[t] = s;
  __syncthreads();
  for (int o = 128; o >= 1; o >>= 1) {
    if (t < o) sh[t] += sh[t + o];
    __syncthreads();
  }
  if (t == 0) bsum[b] = sh[0];
}

__global__ __launch_bounds__(1024) void k_scan1(const int* __restrict__ bsum,
                                                int* __restrict__ bpre,
                                                int* __restrict__ rowoff) {
  __shared__ int sh[1024];
  int t = threadIdx.x;
  int v = (t < NSCAN) ? bsum[t] : 0;
  sh[t] = v;
  __syncthreads();
  for (int o = 1; o < 1024; o <<= 1) {
    int a = (t >= o) ? sh[t - o] : 0;
    __syncthreads();
    sh[t] += a;
    __syncthreads();
  }
  if (t < NSCAN) bpre[t] = sh[t] - v;
  if (t == 0) rowoff[NROWS] = N_EDGES;
}

__global__ __launch_bounds__(256) void k_apply(const int* __restrict__ cnt,
                                               const int* __restrict__ bpre,
                                               int* __restrict__ rowoff) {
  __shared__ int sh[256];
  int b = blockIdx.x, t = threadIdx.x;
  const int4* p = (const int4*)(cnt + b * 2048);
  int4 v0 = p[2 * t], v1 = p[2 * t + 1];
  int v[8] = {v0.x, v0.y, v0.z, v0.w, v1.x, v1.y, v1.z, v1.w};
  int s = 0;
#pragma unroll
  for (int j = 0; j < 8; ++j) s += v[j];
  sh[t] = s;
  __syncthreads();
  for (int o = 1; o < 256; o <<= 1) {
    int a = (t >= o) ? sh[t - o] : 0;
    __syncthreads();
    sh[t] += a;
    __syncthreads();
  }
  int run = bpre[b] + sh[t] - s;
  int base = b * 2048 + t * 8;
#pragma unroll
  for (int j = 0; j < 8; ++j) {
    int i = base + j;
    if (i < NROWS) rowoff[i] = run;
    run += v[j];
  }
}

// place edges sorted by row = dst*8+rel (no atomics: pos = rowoff + rank)
__global__ void k_scatter(const int* __restrict__ ei, const int* __restrict__ et,
                          const int* __restrict__ rowoff, const int* __restrict__ er,
                          int* __restrict__ ep) {
  int e = blockIdx.x * 256 + threadIdx.x;
  if (e < N_EDGES) {
    int src = ei[e];
    int dst = ei[N_EDGES + e];
    int r = et[e];
    int row = dst * N_RELS + r;
    int pos = rowoff[row] + er[e];
    ep[pos] = src | ((row & 255) << 18);
  }
}

// ---------------- fused aggregate + MFMA transform ----------------
// Block: 32 dsts = 256 rows, 512 threads (8 waves), ~34 KB LDS -> 4 blk/CU.
// Wave partition: threads t<9 binary-search loff[0..256] so each wave's
// contiguous row range holds ~n/8 edges.
// Phase 1 (depth-2 pipeline, A/B batch buffers, static-indexed): LOADP keeps
// payload-load ADJACENT to readfirstlane (s_load idiom preserved; r13's
// separation regressed FETCH +60B/edge). Consume of batch k runs after the
// gathers of batch k+1 are issued -> L3 latency overlapped. Scalar run-break
// branch; flush: mean -> round-half-up bf16 -> one ds_write_b16 (swizzled).
// Phase 2 (NCOL=64): 8 waves = 2M x 4N, full K=576/wave; LDS-staged
// coalesced uint2 epilogue. (NCOL=32): 2M x 2N x 2K-split, 2-way LDS reduce.

template <int NCOL, bool RELUOUT, bool OUTBF>
__global__ __launch_bounds__(512, 8) void k_rgcn(
    const ushort* __restrict__ Xg, const ushort* __restrict__ Bf,
    const float* __restrict__ Bias, const int* __restrict__ rowoff,
    const int* __restrict__ ep, void* __restrict__ OutP) {
  __shared__ __align__(16) ushort agg[256 * 64];    // 32 KB bf16 plane
  __shared__ int loff[260];
  __shared__ int wsplit[12];
  __shared__ __align__(16) float bias_lds[64];

  int t = threadIdx.x;
  int b = blockIdx.x;
  int d0 = b * 32;
  int lane = t & 63, w = t >> 6;

  {
    uint4 zz = make_uint4(0, 0, 0, 0);
    uint4* a4 = (uint4*)agg;
#pragma unroll
    for (int q = 0; q < 4; ++q) a4[t + q * 512] = zz;
  }
  if (t < 257) loff[t] = rowoff[b * 256 + t];
  if (t < NCOL) bias_lds[t] = Bias[t];
  __syncthreads();
  if (t < 9) {
    int s0 = loff[0], ntot = loff[256] - s0;
    int target = s0 + ((ntot * t) >> 3);
    int lo = 0, hi = 256;
    while (lo < hi) {
      int mid = (lo + hi) >> 1;
      if (loff[mid] < target) lo = mid + 1; else hi = mid;
    }
    wsplit[t] = lo;
  }
  __syncthreads();

  // ---- phase 1: depth-2 pipelined scalar edge stream ----
  {
    int s = __builtin_amdgcn_readfirstlane(loff[wsplit[w]]);
    int e = __builtin_amdgcn_readfirstlane(loff[wsplit[w + 1]]);
    int n = e - s;
    const int* wep = ep + s;
    const char* Xb = (const char*)Xg;
    unsigned lane2 = (unsigned)(lane << 1);
    int cur = -1, nrun = 0;
    float a = 0.f;

#define FLUSH()                                                         \
    {                                                                   \
      float m = a * __builtin_amdgcn_rcpf((float)nrun);                 \
      int sw = (cur << 6) + (lane ^ (((cur >> 3) & 7) << 3));           \
      agg[sw] = (ushort)((__float_as_uint(m) + 0x8000u) >> 16);         \
    }
#define LOADP(BASE, PK, HV)                                             \
    {                                                                   \
      _Pragma("unroll")                                                 \
      for (int u = 0; u < 8; ++u)                                       \
        PK[u] = __builtin_amdgcn_readfirstlane(wep[(BASE) + u]);        \
      _Pragma("unroll")                                                 \
      for (int u = 0; u < 8; ++u)                                       \
        HV[u] = *(const ushort*)(Xb + ((((unsigned)PK[u] & 0x3FFFFu) << 7) + lane2)); \
    }
#define CONSUME(PK, HV)                                                 \
    {                                                                   \
      _Pragma("unroll")                                                 \
      for (int u = 0; u < 8; ++u) {                                     \
        int row = (int)((unsigned)PK[u] >> 18);                         \
        float v = __uint_as_float((unsigned)HV[u] << 16);               \
        if (row != cur) {                                               \
          if (cur >= 0) FLUSH();                                        \
          cur = row; a = 0.f; nrun = 0;                                 \
        }                                                               \
        a += v; ++nrun;                                                 \
      }                                                                 \
    }

    int nb = n >> 3;   // full 8-edge batches
    if (nb > 0) {
      int pkA[8], pkB[8];
      ushort hvA[8], hvB[8];
      LOADP(0, pkA, hvA);
      int k = 0;
      while (true) {
        if (k + 1 < nb) LOADP((k + 1) << 3, pkB, hvB);
        CONSUME(pkA, hvA);
        ++k; if (k >= nb) break;
        if (k + 1 < nb) LOADP((k + 1) << 3, pkA, hvA);
        CONSUME(pkB, hvB);
        ++k; if (k >= nb) break;
      }
    }
    for (int i = nb << 3; i < n; ++i) {
      int pk = __builtin_amdgcn_readfirstlane(wep[i]);
      ushort hv = *(const ushort*)(Xb + ((((unsigned)pk & 0x3FFFFu) << 7) + lane2));
      int row = (int)((unsigned)pk >> 18);
      float v = __uint_as_float((unsigned)hv << 16);
      if (row != cur) {
        if (cur >= 0) FLUSH();
        cur = row; a = 0.f; nrun = 0;
      }
      a += v; ++nrun;
    }
    if (cur >= 0) FLUSH();
#undef CONSUME
#undef LOADP
#undef FLUSH
  }
  __syncthreads();

  // ---- phase 2: pure-bf16 MFMA ----
  int l15 = lane & 15, kg = lane >> 4;
  f32x4 acc = {0.f, 0.f, 0.f, 0.f};

  if constexpr (NCOL == 64) {
    int wm = w >> 2, wn = w & 3;
    int col = wn * 16 + l15;
    for (int ks = 0; ks < 18; ++ks) {
      union { uint4 q; short8v s; } bh, ah;
      bh.q = *(const uint4*)(Bf + (ks * 4 + wn) * 512 + lane * 8);
      if (ks < 16) {
        int rr = ks >> 1;
        int f0 = ((ks & 1) << 5) + (kg << 3);
        int row = ((wm * 16 + l15) << 3) + rr;
        int sw = (row << 6) + (f0 ^ ((l15 & 7) << 3));
        ah.q = *(const uint4*)&agg[sw];
      } else {
        int kb = ((ks - 16) << 5) + (kg << 3);
        ah.q = *(const uint4*)&Xg[(size_t)(d0 + wm * 16 + l15) * 64 + kb];
      }
      acc = __builtin_amdgcn_mfma_f32_16x16x32_bf16(ah.s, bh.s, acc, 0, 0, 0);
    }
    // epilogue: LDS-staged coalesced stores
    __syncthreads();                 // all agg reads done; reuse as stage
#pragma unroll
    for (int i2 = 0; i2 < 4; ++i2) {
      float v = acc[i2] + bias_lds[col];
      if (RELUOUT) v = fmaxf(v, 0.f);
      agg[(wm * 16 + kg * 4 + i2) * 64 + col] = rne_bf16(v);
    }
    __syncthreads();
    {
      int r = t >> 4, c4 = t & 15;
      uint2 v = *(const uint2*)&agg[r * 64 + c4 * 4];
      ((uint2*)OutP)[(size_t)(d0 + r) * 16 + c4] = v;
    }
  } else {
    int wm = w >> 2, wn = (w >> 1) & 1, ksp = w & 1;
    int col = wn * 16 + l15;
    for (int ks = ksp; ks < 18; ks += 2) {
      union { uint4 q; short8v s; } bh, ah;
      bh.q = *(const uint4*)(Bf + (ks * 2 + wn) * 512 + lane * 8);
      if (ks < 16) {
        int rr = ks >> 1;
        int f0 = ((ks & 1) << 5) + (kg << 3);
        int row = ((wm * 16 + l15) << 3) + rr;
        int sw = (row << 6) + (f0 ^ ((l15 & 7) << 3));
        ah.q = *(const uint4*)&agg[sw];
      } else {
        int kb = ((ks - 16) << 5) + (kg << 3);
        ah.q = *(const uint4*)&Xg[(size_t)(d0 + wm * 16 + l15) * 64 + kb];
      }
      acc = __builtin_amdgcn_mfma_f32_16x16x32_bf16(ah.s, bh.s, acc, 0, 0, 0);
    }
    __syncthreads();               // agg reads done before reuse
    float* red = (float*)agg;
    int rbase = wm * 16 + kg * 4;
    if (ksp == 1) {
#pragma unroll
      for (int i2 = 0; i2 < 4; ++i2) red[(rbase + i2) * 36 + col] = acc[i2];
    }
    __syncthreads();
    if (ksp == 0) {
#pragma unroll
      for (int i2 = 0; i2 < 4; ++i2) {
        float v = acc[i2] + red[(rbase + i2) * 36 + col] + bias_lds[col];
        if (RELUOUT) v = fmaxf(v, 0.f);
        ((float*)OutP)[(size_t)(d0 + rbase + i2) * 32 + col] = v;
      }
    }
  }
}

// ---------------- launch ----------------

extern "C" void kernel_launch(void* const* d_in, const int* in_sizes, int n_in,
                              void* d_out, int out_size, void* d_ws, size_t ws_size,
                              hipStream_t stream) {
  const float* x = (const float*)d_in[0];
  const int* ei = (const int*)d_in[1];
  const int* et = (const int*)d_in[2];
  const float* w1 = (const float*)d_in[3];
  const float* r1 = (const float*)d_in[4];
  const float* b1 = (const float*)d_in[5];
  const float* w2 = (const float*)d_in[6];
  const float* r2 = (const float*)d_in[7];
  const float* b2 = (const float*)d_in[8];
  float* out = (float*)d_out;

  int* cnt = (int*)d_ws;                     // NROWS_PAD ints
  int* bsum = cnt + NROWS_PAD;               // 1024
  int* bpre = bsum + 1024;                   // 1024
  int* rowoff = bpre + 1024;                 // NROWS+1 (pad 16)
  int* er = rowoff + NROWS + 16;             // N_EDGES (edge rank)
  int* ep = er + N_EDGES;                    // N_EDGES
  ushort* bf1 = (ushort*)(ep + N_EDGES);     // 36864 (single plane)
  ushort* bf2 = bf1 + 36864;                 // 18432
  ushort* xbf = bf2 + 18432;                 // 12,800,000 (25.6 MB)
  ushort* hbf = xbf + 12800000;              // 12,800,000 (25.6 MB)

  hipMemsetAsync(cnt, 0, (size_t)NROWS_PAD * 4, stream);
  k_setup<<<NB_COUNT + NB_XCAST + NB_PREP1 + NB_PREP2, 256, 0, stream>>>(
      ei, et, cnt, er, x, xbf, w1, r1, bf1, w2, r2, bf2);
  k_bsum<<<NSCAN, 256, 0, stream>>>(cnt, bsum);
  k_scan1<<<1, 1024, 0, stream>>>(bsum, bpre, rowoff);
  k_apply<<<NSCAN, 256, 0, stream>>>(cnt, bpre, rowoff);
  k_scatter<<<(N_EDGES + 255) / 256, 256, 0, stream>>>(ei, et, rowoff, er, ep);

  k_rgcn<64, true, true><<<NBUCK, 512, 0, stream>>>(xbf, bf1, b1, rowoff, ep, hbf);
  k_rgcn<32, false, false><<<NBUCK, 512, 0, stream>>>(hbf, bf2, b2, rowoff, ep, out);
}

// Round 16
// 264.232 us; speedup vs baseline: 17.0532x; 1.0272x over previous
//
#include <hip/hip_runtime.h>

#define N_NODES 200000
#define N_EDGES 1250000
#define N_RELS 8
#define NROWS 1600000        // N_NODES * N_RELS
#define NROWS_PAD 1601536    // 782 * 2048
#define NSCAN 782
#define NBUCK 6250           // N_NODES / 32

#define NB_COUNT 4883        // ceil(N_EDGES/256)
#define NB_XCAST 6250        // 1.6M/256
#define NB_PREP1 144         // 64*576/256
#define NB_PREP2 72          // 32*576/256

typedef __attribute__((ext_vector_type(8))) short short8v;
typedef __attribute__((ext_vector_type(4))) float f32x4;

__device__ __forceinline__ ushort rne_bf16(float v) {
  unsigned u = __float_as_uint(v);
  return (ushort)((u + 0x7FFFu + ((u >> 16) & 1u)) >> 16);
}

// ---------------- fused setup: count(+rank) | xcast | prep1 | prep2 ----------------

__device__ __forceinline__ void prep_body(const float* W, const float* Root,
                                          ushort* Bf, int ncol, int i) {
  int col = i / 576, k = i - col * 576;
  float w = (k < 512) ? W[k * ncol + col] : Root[(k - 512) * ncol + col];
  int WN = ncol >> 4;
  int ks = k >> 5, kg = (k >> 3) & 3, j = k & 7;
  int wn = col >> 4, l15 = col & 15;
  int lane = (kg << 4) | l15;
  Bf[(ks * WN + wn) * 512 + lane * 8 + j] = rne_bf16(w);
}

__global__ __launch_bounds__(256) void k_setup(
    const int* __restrict__ ei, const int* __restrict__ et, int* __restrict__ cnt,
    int* __restrict__ er,
    const float* __restrict__ x, ushort* __restrict__ xbf,
    const float* __restrict__ w1, const float* __restrict__ r1, ushort* __restrict__ bf1,
    const float* __restrict__ w2, const float* __restrict__ r2, ushort* __restrict__ bf2) {
  int blk = blockIdx.x, t = threadIdx.x;
  if (blk < NB_COUNT) {
    int e = blk * 256 + t;
    if (e < N_EDGES) {
      int dst = ei[N_EDGES + e];
      int r = et[e];
      er[e] = atomicAdd(&cnt[dst * N_RELS + r], 1);   // rank within (dst,rel)
    }
  } else if (blk < NB_COUNT + NB_XCAST) {
    int i = (blk - NB_COUNT) * 256 + t;   // i < 1.6M
    float4 a = ((const float4*)x)[i * 2];
    float4 b = ((const float4*)x)[i * 2 + 1];
    union { uint4 q; ushort u[8]; } o;
    o.u[0] = rne_bf16(a.x); o.u[1] = rne_bf16(a.y);
    o.u[2] = rne_bf16(a.z); o.u[3] = rne_bf16(a.w);
    o.u[4] = rne_bf16(b.x); o.u[5] = rne_bf16(b.y);
    o.u[6] = rne_bf16(b.z); o.u[7] = rne_bf16(b.w);
    ((uint4*)xbf)[i] = o.q;
  } else if (blk < NB_COUNT + NB_XCAST + NB_PREP1) {
    int i = (blk - NB_COUNT - NB_XCAST) * 256 + t;
    prep_body(w1, r1, bf1, 64, i);
  } else {
    int i = (blk - NB_COUNT - NB_XCAST - NB_PREP1) * 256 + t;
    prep_body(w2, r2, bf2, 32, i);
  }
}

// ---------------- sort infrastructure ----------------

__global__ __launch_bounds__(256) void k_bsum(const int* __restrict__ cnt,
                                              int* __restrict__ bsum) {
  __shared__ int sh[256];
  int b = blockIdx.x, t = threadIdx.x;
  const int4* p = (const int4*)(cnt + b * 2048);
  int4 v0 = p[2 * t], v1 = p[2 * t + 1];
  int s = v0.x + v0.y + v0.z + v0.w + v1.x + v1.y + v1.z + v1.w;
  sh[t] = s;
  __syncthreads();
  for (int o = 128; o >= 1; o >>= 1) {
    if (t < o) sh[t] += sh[t + o];
    __syncthreads();
  }
  if (t == 0) bsum[b] = sh[0];
}

__global__ __launch_bounds__(1024) void k_scan1(const int* __restrict__ bsum,
                                                int* __restrict__ bpre,
                                                int* __restrict__ rowoff) {
  __shared__ int sh[1024];
  int t = threadIdx.x;
  int v = (t < NSCAN) ? bsum[t] : 0;
  sh[t] = v;
  __syncthreads();
  for (int o = 1; o < 1024; o <<= 1) {
    int a = (t >= o) ? sh[t - o] : 0;
    __syncthreads();
    sh[t] += a;
    __syncthreads();
  }
  if (t < NSCAN) bpre[t] = sh[t] - v;
  if (t == 0) rowoff[NROWS] = N_EDGES;
}

__global__ __launch_bounds__(256) void k_apply(const int* __restrict__ cnt,
                                               const int* __restrict__ bpre,
                                               int* __restrict__ rowoff) {
  __shared__ int sh[256];
  int b = blockIdx.x, t = threadIdx.x;
  const int4* p = (const int4*)(cnt + b * 2048);
  int4 v0 = p[2 * t], v1 = p[2 * t + 1];
  int v[8] = {v0.x, v0.y, v0.z, v0.w, v1.x, v1.y, v1.z, v1.w};
  int s = 0;
#pragma unroll
  for (int j = 0; j < 8; ++j) s += v[j];
  sh[t] = s;
  __syncthreads();
  for (int o = 1; o < 256; o <<= 1) {
    int a = (t >= o) ? sh[t - o] : 0;
    __syncthreads();
    sh[t] += a;
    __syncthreads();
  }
  int run = bpre[b] + sh[t] - s;
  int base = b * 2048 + t * 8;
#pragma unroll
  for (int j = 0; j < 8; ++j) {
    int i = base + j;
    if (i < NROWS) rowoff[i] = run;
    run += v[j];
  }
}

// place edges sorted by row = dst*8+rel (no atomics: pos = rowoff + rank)
__global__ void k_scatter(const int* __restrict__ ei, const int* __restrict__ et,
                          const int* __restrict__ rowoff, const int* __restrict__ er,
                          int* __restrict__ ep) {
  int e = blockIdx.x * 256 + threadIdx.x;
  if (e < N_EDGES) {
    int src = ei[e];
    int dst = ei[N_EDGES + e];
    int r = et[e];
    int row = dst * N_RELS + r;
    int pos = rowoff[row] + er[e];
    ep[pos] = src | ((row & 255) << 18);
  }
}

// ---------------- fused aggregate + MFMA transform ----------------
// Block: 32 dsts = 256 rows, 512 threads (8 waves), ~34 KB LDS -> 4 blk/CU.
// Wave partition: threads t<9 binary-search loff[0..256] so each wave's
// contiguous row range holds ~n/8 edges.
// Phase 1 (readlane superblocks): one coalesced 64-edge payload load per
// wave, preloaded one superblock ahead; per-edge payload via v_readlane
// (register op -> SGPR, no scalar-memory latency; r15's s_load-per-batch
// serialized ~250 cyc/batch). Depth-2 A/B gather pipeline retained. Scalar
// run-break branch; flush mean -> round-half-up bf16 -> one ds_write_b16.
// Phase 2 (NCOL=64): 8 waves = 2M x 4N, full K=576/wave; LDS-staged
// coalesced uint2 epilogue. (NCOL=32): 2M x 2N x 2K-split, 2-way LDS reduce.

template <int NCOL, bool RELUOUT, bool OUTBF>
__global__ __launch_bounds__(512, 8) void k_rgcn(
    const ushort* __restrict__ Xg, const ushort* __restrict__ Bf,
    const float* __restrict__ Bias, const int* __restrict__ rowoff,
    const int* __restrict__ ep, void* __restrict__ OutP) {
  __shared__ __align__(16) ushort agg[256 * 64];    // 32 KB bf16 plane
  __shared__ int loff[260];
  __shared__ int wsplit[12];
  __shared__ __align__(16) float bias_lds[64];

  int t = threadIdx.x;
  int b = blockIdx.x;
  int d0 = b * 32;
  int lane = t & 63, w = t >> 6;

  {
    uint4 zz = make_uint4(0, 0, 0, 0);
    uint4* a4 = (uint4*)agg;
#pragma unroll
    for (int q = 0; q < 4; ++q) a4[t + q * 512] = zz;
  }
  if (t < 257) loff[t] = rowoff[b * 256 + t];
  if (t < NCOL) bias_lds[t] = Bias[t];
  __syncthreads();
  if (t < 9) {
    int s0 = loff[0], ntot = loff[256] - s0;
    int target = s0 + ((ntot * t) >> 3);
    int lo = 0, hi = 256;
    while (lo < hi) {
      int mid = (lo + hi) >> 1;
      if (loff[mid] < target) lo = mid + 1; else hi = mid;
    }
    wsplit[t] = lo;
  }
  __syncthreads();

  // ---- phase 1: readlane superblocks + depth-2 gather pipeline ----
  {
    int s = __builtin_amdgcn_readfirstlane(loff[wsplit[w]]);
    int e = __builtin_amdgcn_readfirstlane(loff[wsplit[w + 1]]);
    int n = e - s;
    const int* wep = ep + s;
    const char* Xb = (const char*)Xg;
    unsigned lane2 = (unsigned)(lane << 1);
    int cur = -1, nrun = 0;
    float a = 0.f;

#define FLUSH()                                                         \
    {                                                                   \
      float m = a * __builtin_amdgcn_rcpf((float)nrun);                 \
      int sw = (cur << 6) + (lane ^ (((cur >> 3) & 7) << 3));           \
      agg[sw] = (ushort)((__float_as_uint(m) + 0x8000u) >> 16);         \
    }
#define LOADP(PAY, BASE, NV, PK, HV)                                    \
    {                                                                   \
      _Pragma("unroll")                                                 \
      for (int u = 0; u < 8; ++u) {                                     \
        int idx = (BASE) + u; if (idx > (NV) - 1) idx = (NV) - 1;       \
        PK[u] = __builtin_amdgcn_readlane(PAY, idx);                    \
        HV[u] = *(const ushort*)(Xb + ((((unsigned)PK[u] & 0x3FFFFu) << 7) + lane2)); \
      }                                                                 \
    }
#define CONSUME(PK, HV, BASE, NV)                                       \
    {                                                                   \
      int nbb = (NV) - (BASE); if (nbb > 8) nbb = 8;                    \
      _Pragma("unroll")                                                 \
      for (int u = 0; u < 8; ++u) {                                     \
        if (u < nbb) {                                                  \
          int row = (int)((unsigned)PK[u] >> 18);                       \
          float v = __uint_as_float((unsigned)HV[u] << 16);             \
          if (row != cur) {                                             \
            if (cur >= 0) FLUSH();                                      \
            cur = row; a = 0.f; nrun = 0;                               \
          }                                                             \
          a += v; ++nrun;                                               \
        }                                                               \
      }                                                                 \
    }

    if (n > 0) {
      // preload first payload superblock
      int nv0 = n < 64 ? n : 64;
      int pl0 = lane; if (pl0 > nv0 - 1) pl0 = nv0 - 1;
      int payA = wep[pl0];
      for (int base = 0; base < n; base += 64) {
        int nv = n - base; if (nv > 64) nv = 64;
        int nxt = base + 64;
        int payB = payA;
        if (nxt < n) {   // issue next superblock's payload load early
          int nv2 = n - nxt; if (nv2 > 64) nv2 = 64;
          int pl = lane; if (pl > nv2 - 1) pl = nv2 - 1;
          payB = wep[nxt + pl];
        }
        int nb = (nv + 7) >> 3;
        {
          int pkA[8], pkB[8];
          ushort hvA[8], hvB[8];
          LOADP(payA, 0, nv, pkA, hvA);
          int k = 0;
          while (true) {
            if (k + 1 < nb) LOADP(payA, (k + 1) << 3, nv, pkB, hvB);
            CONSUME(pkA, hvA, k << 3, nv);
            ++k; if (k >= nb) break;
            if (k + 1 < nb) LOADP(payA, (k + 1) << 3, nv, pkA, hvA);
            CONSUME(pkB, hvB, k << 3, nv);
            ++k; if (k >= nb) break;
          }
        }
        payA = payB;
      }
      if (cur >= 0) FLUSH();
    }
#undef CONSUME
#undef LOADP
#undef FLUSH
  }
  __syncthreads();

  // ---- phase 2: pure-bf16 MFMA ----
  int l15 = lane & 15, kg = lane >> 4;
  f32x4 acc = {0.f, 0.f, 0.f, 0.f};

  if constexpr (NCOL == 64) {
    int wm = w >> 2, wn = w & 3;
    int col = wn * 16 + l15;
    for (int ks = 0; ks < 18; ++ks) {
      union { uint4 q; short8v s; } bh, ah;
      bh.q = *(const uint4*)(Bf + (ks * 4 + wn) * 512 + lane * 8);
      if (ks < 16) {
        int rr = ks >> 1;
        int f0 = ((ks & 1) << 5) + (kg << 3);
        int row = ((wm * 16 + l15) << 3) + rr;
        int sw = (row << 6) + (f0 ^ ((l15 & 7) << 3));
        ah.q = *(const uint4*)&agg[sw];
      } else {
        int kb = ((ks - 16) << 5) + (kg << 3);
        ah.q = *(const uint4*)&Xg[(size_t)(d0 + wm * 16 + l15) * 64 + kb];
      }
      acc = __builtin_amdgcn_mfma_f32_16x16x32_bf16(ah.s, bh.s, acc, 0, 0, 0);
    }
    // epilogue: LDS-staged coalesced stores
    __syncthreads();                 // all agg reads done; reuse as stage
#pragma unroll
    for (int i2 = 0; i2 < 4; ++i2) {
      float v = acc[i2] + bias_lds[col];
      if (RELUOUT) v = fmaxf(v, 0.f);
      agg[(wm * 16 + kg * 4 + i2) * 64 + col] = rne_bf16(v);
    }
    __syncthreads();
    {
      int r = t >> 4, c4 = t & 15;
      uint2 v = *(const uint2*)&agg[r * 64 + c4 * 4];
      ((uint2*)OutP)[(size_t)(d0 + r) * 16 + c4] = v;
    }
  } else {
    int wm = w >> 2, wn = (w >> 1) & 1, ksp = w & 1;
    int col = wn * 16 + l15;
    for (int ks = ksp; ks < 18; ks += 2) {
      union { uint4 q; short8v s; } bh, ah;
      bh.q = *(const uint4*)(Bf + (ks * 2 + wn) * 512 + lane * 8);
      if (ks < 16) {
        int rr = ks >> 1;
        int f0 = ((ks & 1) << 5) + (kg << 3);
        int row = ((wm * 16 + l15) << 3) + rr;
        int sw = (row << 6) + (f0 ^ ((l15 & 7) << 3));
        ah.q = *(const uint4*)&agg[sw];
      } else {
        int kb = ((ks - 16) << 5) + (kg << 3);
        ah.q = *(const uint4*)&Xg[(size_t)(d0 + wm * 16 + l15) * 64 + kb];
      }
      acc = __builtin_amdgcn_mfma_f32_16x16x32_bf16(ah.s, bh.s, acc, 0, 0, 0);
    }
    __syncthreads();               // agg reads done before reuse
    float* red = (float*)agg;
    int rbase = wm * 16 + kg * 4;
    if (ksp == 1) {
#pragma unroll
      for (int i2 = 0; i2 < 4; ++i2) red[(rbase + i2) * 36 + col] = acc[i2];
    }
    __syncthreads();
    if (ksp == 0) {
#pragma unroll
      for (int i2 = 0; i2 < 4; ++i2) {
        float v = acc[i2] + red[(rbase + i2) * 36 + col] + bias_lds[col];
        if (RELUOUT) v = fmaxf(v, 0.f);
        ((float*)OutP)[(size_t)(d0 + rbase + i2) * 32 + col] = v;
      }
    }
  }
}

// ---------------- launch ----------------

extern "C" void kernel_launch(void* const* d_in, const int* in_sizes, int n_in,
                              void* d_out, int out_size, void* d_ws, size_t ws_size,
                              hipStream_t stream) {
  const float* x = (const float*)d_in[0];
  const int* ei = (const int*)d_in[1];
  const int* et = (const int*)d_in[2];
  const float* w1 = (const float*)d_in[3];
  const float* r1 = (const float*)d_in[4];
  const float* b1 = (const float*)d_in[5];
  const float* w2 = (const float*)d_in[6];
  const float* r2 = (const float*)d_in[7];
  const float* b2 = (const float*)d_in[8];
  float* out = (float*)d_out;

  int* cnt = (int*)d_ws;                     // NROWS_PAD ints
  int* bsum = cnt + NROWS_PAD;               // 1024
  int* bpre = bsum + 1024;                   // 1024
  int* rowoff = bpre + 1024;                 // NROWS+1 (pad 16)
  int* er = rowoff + NROWS + 16;             // N_EDGES (edge rank)
  int* ep = er + N_EDGES;                    // N_EDGES
  ushort* bf1 = (ushort*)(ep + N_EDGES);     // 36864 (single plane)
  ushort* bf2 = bf1 + 36864;                 // 18432
  ushort* xbf = bf2 + 18432;                 // 12,800,000 (25.6 MB)
  ushort* hbf = xbf + 12800000;              // 12,800,000 (25.6 MB)

  hipMemsetAsync(cnt, 0, (size_t)NROWS_PAD * 4, stream);
  k_setup<<<NB_COUNT + NB_XCAST + NB_PREP1 + NB_PREP2, 256, 0, stream>>>(
      ei, et, cnt, er, x, xbf, w1, r1, bf1, w2, r2, bf2);
  k_bsum<<<NSCAN, 256, 0, stream>>>(cnt, bsum);
  k_scan1<<<1, 1024, 0, stream>>>(bsum, bpre, rowoff);
  k_apply<<<NSCAN, 256, 0, stream>>>(cnt, bpre, rowoff);
  k_scatter<<<(N_EDGES + 255) / 256, 256, 0, stream>>>(ei, et, rowoff, er, ep);

  k_rgcn<64, true, true><<<NBUCK, 512, 0, stream>>>(xbf, bf1, b1, rowoff, ep, hbf);
  k_rgcn<32, false, false><<<NBUCK, 512, 0, stream>>>(hbf, bf2, b2, rowoff, ep, out);
}